// Round 5
// baseline (422.662 us; speedup 1.0000x reference)
//
#include <hip/hip_runtime.h>
#include <cstddef>

#define LSEQ    1024
#define DMODEL  256
#define DINNER  512
#define DSTATE  64
#define NHEADS  8
#define HEADDIM 64
#define CONVDIM 640
#define DINPROJ 1160
#define ROWS    2048   // B * L
#define EPSF    1e-5f
#define NC      16     // chunks per sequence
#define LC      64     // chunk length
#define XBCW    648    // xBC (640) + raw dt (8)

// weight-pair buffer geometry (element counts)
#define WIN  593920    // 2 dirs * 1160 * 256 (one layer of in_w)
#define WOUT 262144    // 2 dirs * 256 * 512  (one layer of out_w)
#define WF   262144    // 512 * 512           (fusion_w)
#define PSI  296960    // 1160*256 per (dir,layer) slice of in_w
#define PSO  131072    // 256*512  per (dir,layer) slice of out_w

typedef _Float16 f16;
typedef f16   v8h __attribute__((ext_vector_type(8)));
typedef float v4f __attribute__((ext_vector_type(4)));
#define MFMA16(a, b, c) __builtin_amdgcn_mfma_f32_16x16x32_f16(a, b, c, 0, 0, 0)

__device__ __forceinline__ float sigmoidf_(float x) { return 1.0f / (1.0f + expf(-x)); }
__device__ __forceinline__ float siluf_(float x)    { return x / (1.0f + expf(-x)); }
__device__ __forceinline__ float softplusf_(float x) {
    return x > 0.0f ? x + log1pf(expf(-x)) : log1pf(expf(x));
}
__device__ __forceinline__ void split16(float v, f16& h, f16& l) {
    h = (f16)v;                          // RN; v - h exact in fp32
    l = (f16)((v - (float)h) * 4096.0f); // residual beyond pair <= 2^-24 |v|
}

// ---------------------------------------------------------------- embedding -> f16 pairs (fwd + time-flipped)
__global__ __launch_bounds__(256) void embed_kernel(
    const int* __restrict__ ids, const float* __restrict__ mask,
    const float* __restrict__ tok, const float* __restrict__ pos,
    f16* __restrict__ uh, f16* __restrict__ ul) {
    int row = blockIdx.x;            // b*1024 + t
    int d = threadIdx.x;
    int b = row >> 10, t = row & 1023;
    int id = ids[row];
    float v = tok[(size_t)id * DMODEL + d] + pos[(size_t)t * DMODEL + d];
    v *= mask[row];
    f16 h, l; split16(v, h, l);
    size_t fwd = (size_t)row * DMODEL + d;
    size_t bwd = (size_t)ROWS * DMODEL + ((size_t)(b << 10) + (1023 - t)) * DMODEL + d;
    uh[fwd] = h; ul[fwd] = l;
    uh[bwd] = h; ul[bwd] = l;
}

// ---------------------------------------------------------------- weight fp32 -> f16 pair conversion (per layer)
__global__ __launch_bounds__(256) void wconv_kernel(
    const float* __restrict__ inw, const float* __restrict__ ow, const float* __restrict__ fw,
    f16* __restrict__ wb, int layer, int total) {
    int idx = (blockIdx.x * 256 + threadIdx.x) * 4;
#pragma unroll
    for (int e = idx; e < idx + 4; ++e) {
        if (e >= total) break;
        float v; f16 *dh, *dl; int off;
        if (e < WIN) {
            int d = e / PSI, r = e - d * PSI;
            v = inw[(size_t)(d * 2 + layer) * PSI + r];
            dh = wb; dl = wb + WIN; off = e;
        } else if (e < WIN + WOUT) {
            int e2 = e - WIN;
            int d = e2 / PSO, r = e2 - d * PSO;
            v = ow[(size_t)(d * 2 + layer) * PSO + r];
            dh = wb + 2 * WIN; dl = dh + WOUT; off = e2;
        } else {
            int e3 = e - WIN - WOUT;
            v = fw[e3];
            dh = wb + 2 * WIN + 2 * WOUT; dl = dh + WF; off = e3;
        }
        f16 h, l; split16(v, h, l);
        dh[off] = h; dl[off] = l;
    }
}

// ---------------------------------------------------------------- f16x3 MFMA GEMM: C[M,N] = A[M,K] * W[N,K]^T
// A,W given as exact f16 (hi, lo*2^12) pairs. 64x64 tile / block, 4 waves of 32x32.
// haspair epilogue: flipcomb=0 -> per-dir pair write at ldP; flipcomb=1 -> write into
// comb layout [row][512]: dir0 at cols 0..255 (row as-is), dir1 at cols 256..511 (time-flipped row).
__global__ __launch_bounds__(256) void gemm_f16x3(
    const f16* __restrict__ Ah, const f16* __restrict__ Al, long sA,
    const f16* __restrict__ Wh, const f16* __restrict__ Wl, long sW,
    int N, int K, int Nsplit,
    float* __restrict__ O0, int ld0, long sO0,
    float* __restrict__ O1, int ld1, long sO1,
    f16* __restrict__ Ph, f16* __restrict__ Pl, int ldP, long sP,
    int has32, int haspair, int flipcomb) {
    int dir = blockIdx.z;
    Ah += (size_t)dir * sA; Al += (size_t)dir * sA;
    Wh += (size_t)dir * sW; Wl += (size_t)dir * sW;
    if (has32)  { O0 += (size_t)dir * sO0; O1 += (size_t)dir * sO1; }
    if (haspair){ Ph += (size_t)dir * sP;  Pl += (size_t)dir * sP; }

    __shared__ f16 sm[4 * 64 * 72];      // Ah | Al | Wh | Wl tiles, 64 rows x 64 k, pitch 72
    f16* As_h = sm;
    f16* As_l = sm + 64 * 72;
    f16* Ws_h = sm + 2 * 64 * 72;
    f16* Ws_l = sm + 3 * 64 * 72;

    int tid = threadIdx.x;
    int m0 = blockIdx.x * 64, n0 = blockIdx.y * 64;
    int srow = tid >> 2, sseg = tid & 3;           // staging: 64 rows x 4 segs of 16 halves
    int lane = tid & 63, w = tid >> 6;
    int wrow = (w >> 1) * 32, wcol = (w & 1) * 32;
    int q = lane >> 4, r16 = lane & 15;
    bool wok = (n0 + srow) < N;

    v4f accM[2][2], accX[2][2];
#pragma unroll
    for (int i = 0; i < 2; ++i)
#pragma unroll
        for (int j = 0; j < 2; ++j) { accM[i][j] = (v4f)0.0f; accX[i][j] = (v4f)0.0f; }

    for (int k0 = 0; k0 < K; k0 += 64) {
        size_t aoff = (size_t)(m0 + srow) * K + k0 + sseg * 16;
        float4 ah0 = *(const float4*)&Ah[aoff];
        float4 ah1 = *(const float4*)&Ah[aoff + 8];
        float4 al0 = *(const float4*)&Al[aoff];
        float4 al1 = *(const float4*)&Al[aoff + 8];
        float4 wh0 = make_float4(0.f,0.f,0.f,0.f), wh1 = wh0, wl0 = wh0, wl1 = wh0;
        if (wok) {
            size_t woff = (size_t)(n0 + srow) * K + k0 + sseg * 16;
            wh0 = *(const float4*)&Wh[woff];
            wh1 = *(const float4*)&Wh[woff + 8];
            wl0 = *(const float4*)&Wl[woff];
            wl1 = *(const float4*)&Wl[woff + 8];
        }
        __syncthreads();                 // previous iteration's reads done
        int d = srow * 72 + sseg * 16;
        *(float4*)&As_h[d] = ah0; *(float4*)&As_h[d + 8] = ah1;
        *(float4*)&As_l[d] = al0; *(float4*)&As_l[d + 8] = al1;
        *(float4*)&Ws_h[d] = wh0; *(float4*)&Ws_h[d + 8] = wh1;
        *(float4*)&Ws_l[d] = wl0; *(float4*)&Ws_l[d + 8] = wl1;
        __syncthreads();

#pragma unroll
        for (int ks = 0; ks < 64; ks += 32) {
            v8h fa_h[2], fa_l[2], fb_h[2], fb_l[2];
#pragma unroll
            for (int i = 0; i < 2; ++i) {
                int ra = (wrow + i * 16 + r16) * 72 + ks + q * 8;
                int rb = (wcol + i * 16 + r16) * 72 + ks + q * 8;
                fa_h[i] = *(const v8h*)&As_h[ra];
                fa_l[i] = *(const v8h*)&As_l[ra];
                fb_h[i] = *(const v8h*)&Ws_h[rb];
                fb_l[i] = *(const v8h*)&Ws_l[rb];
            }
#pragma unroll
            for (int i = 0; i < 2; ++i)
#pragma unroll
                for (int j = 0; j < 2; ++j) {
                    accM[i][j] = MFMA16(fa_h[i], fb_h[j], accM[i][j]);
                    accX[i][j] = MFMA16(fa_h[i], fb_l[j], accX[i][j]);
                    accX[i][j] = MFMA16(fa_l[i], fb_h[j], accX[i][j]);
                }
        }
    }

    const float cs = 1.0f / 4096.0f;
#pragma unroll
    for (int i = 0; i < 2; ++i)
#pragma unroll
        for (int j = 0; j < 2; ++j) {
            int nn = n0 + wcol + j * 16 + r16;
            if (nn < N) {
#pragma unroll
                for (int r = 0; r < 4; ++r) {
                    float v = accM[i][j][r] + accX[i][j][r] * cs;
                    int mm = m0 + wrow + i * 16 + q * 4 + r;
                    if (has32) {
                        if (nn < Nsplit) O0[(size_t)mm * ld0 + nn] = v;
                        else             O1[(size_t)mm * ld1 + (nn - Nsplit)] = v;
                    }
                    if (haspair) {
                        f16 h, l; split16(v, h, l);
                        if (flipcomb) {
                            int bb = mm >> 10, tt_ = mm & 1023;
                            size_t drow = dir == 0 ? (size_t)mm : (size_t)((bb << 10) + (1023 - tt_));
                            size_t dcol = dir == 0 ? (size_t)nn : (size_t)(nn + 256);
                            Ph[drow * 512 + dcol] = h;
                            Pl[drow * 512 + dcol] = l;
                        } else {
                            Ph[(size_t)mm * ldP + nn] = h;
                            Pl[(size_t)mm * ldP + nn] = l;
                        }
                    }
                }
            }
        }
}

// ---------------------------------------------------------------- depthwise causal conv(4) + SiLU, plus softplus(dt)
__global__ __launch_bounds__(256) void conv_dt_kernel(
    const float* __restrict__ xbc, float* __restrict__ xc, float* __restrict__ dts,
    const float* __restrict__ cw, const float* __restrict__ cb,
    const float* __restrict__ dtb, int layer) {
    int row = blockIdx.x;            // b*1024+t
    int dir = blockIdx.y;
    int b = row >> 10, t = row & 1023;
    const float* xd = xbc + (size_t)dir * ROWS * XBCW;
    int pi = dir * 2 + layer;
    const float* cwl = cw + (size_t)pi * CONVDIM * 4;
    const float* cbl = cb + (size_t)pi * CONVDIM;
    const float* dtbl = dtb + pi * NHEADS;
    for (int c = threadIdx.x; c < CONVDIM + NHEADS; c += 256) {
        if (c < CONVDIM) {
            float acc = cbl[c];
#pragma unroll
            for (int k = 0; k < 4; ++k) {
                int tt = t - 3 + k;
                if (tt >= 0)
                    acc = fmaf(xd[(size_t)((b << 10) + tt) * XBCW + c], cwl[c * 4 + k], acc);
            }
            xc[((size_t)dir * ROWS + row) * CONVDIM + c] = siluf_(acc);
        } else {
            int hh = c - CONVDIM;
            dts[((size_t)dir * ROWS + row) * NHEADS + hh] =
                softplusf_(xd[(size_t)row * XBCW + CONVDIM + hh] + dtbl[hh]);
        }
    }
}

// ---------------------------------------------------------------- S1: local chunk scan (from zero state)
// Per-step scalars (dt, dA) via LDS broadcast tables (prefetchable) — no loop-carried shfl.
__global__ __launch_bounds__(64) void scan_chunk_kernel(
    const float* __restrict__ xc, const float* __restrict__ dts,
    float* __restrict__ y, const float* __restrict__ Alog, const float* __restrict__ Dp,
    float* __restrict__ H, float* __restrict__ cumb, int layer) {
    __shared__ float sBC[LC * 128];
    __shared__ float sX[LC * 64];
    __shared__ float sDT[LC];
    __shared__ float sDA[LC];
    int blk = blockIdx.x;
    int u = blk >> 4, c = blk & 15;
    int dir = u >> 4, b = (u >> 3) & 1, h = u & 7;
    int p = threadIdx.x;
    int pi = dir * 2 + layer;
    float Av = -expf(Alog[pi * NHEADS + h]);
    float Dv = Dp[pi * NHEADS + h];
    const float* xcd = xc + (size_t)dir * ROWS * CONVDIM;
    const float* dtd = dts + (size_t)dir * ROWS * NHEADS;
    float* yd = y + (size_t)dir * ROWS * DINNER;
    int t0 = c * LC, base = b << 10;

    // lane t: dt / dA for step t of this chunk
    float dt_l = dtd[(size_t)(base + t0 + p) * NHEADS + h];
    float dA_l = expf(dt_l * Av);
    sDT[p] = dt_l;
    sDA[p] = dA_l;
    float cum_l = dA_l;
#pragma unroll
    for (int off = 1; off < 64; off <<= 1) {
        float o = __shfl_up(cum_l, off);
        if (p >= off) cum_l *= o;
    }
    cumb[(u << 10) + t0 + p] = cum_l;

#pragma unroll
    for (int j = 0; j < 32; ++j) {
        int f4 = j * 64 + p;
        int trow = f4 >> 5, col4 = f4 & 31;
        float4 v = *(const float4*)&xcd[(size_t)(base + t0 + trow) * CONVDIM + DINNER + col4 * 4];
        *(float4*)&sBC[trow * 128 + col4 * 4] = v;
    }
#pragma unroll
    for (int j = 0; j < 16; ++j) {
        int f4 = j * 64 + p;
        int trow = f4 >> 4, col4 = f4 & 15;
        float4 v = *(const float4*)&xcd[(size_t)(base + t0 + trow) * CONVDIM + h * HEADDIM + col4 * 4];
        *(float4*)&sX[trow * 64 + col4 * 4] = v;
    }
    __syncthreads();

    float hreg[DSTATE];
#pragma unroll
    for (int n = 0; n < DSTATE; ++n) hreg[n] = 0.f;

#pragma unroll 2
    for (int tt = 0; tt < LC; ++tt) {
        float dtv = sDT[tt];
        float dA  = sDA[tt];
        float xv = sX[tt * 64 + p];
        float coef = dtv * xv;
        const float* Bsr = &sBC[tt * 128];
        const float* Csr = Bsr + 64;
        float y0 = 0.f, y1 = 0.f, y2 = 0.f, y3 = 0.f;
#pragma unroll
        for (int n = 0; n < DSTATE; n += 4) {
            float4 b4 = *(const float4*)&Bsr[n];
            float4 c4 = *(const float4*)&Csr[n];
            hreg[n]     = fmaf(hreg[n],     dA, coef * b4.x); y0 = fmaf(hreg[n],     c4.x, y0);
            hreg[n + 1] = fmaf(hreg[n + 1], dA, coef * b4.y); y1 = fmaf(hreg[n + 1], c4.y, y1);
            hreg[n + 2] = fmaf(hreg[n + 2], dA, coef * b4.z); y2 = fmaf(hreg[n + 2], c4.z, y2);
            hreg[n + 3] = fmaf(hreg[n + 3], dA, coef * b4.w); y3 = fmaf(hreg[n + 3], c4.w, y3);
        }
        yd[(size_t)(base + t0 + tt) * DINNER + h * HEADDIM + p] = (y0 + y1) + (y2 + y3) + Dv * xv;
    }
    float* Hb = H + (size_t)blk * 4096 + p * 64;
#pragma unroll
    for (int n = 0; n < DSTATE; n += 4)
        *(float4*)&Hb[n] = make_float4(hreg[n], hreg[n + 1], hreg[n + 2], hreg[n + 3]);
}

// ---------------------------------------------------------------- S2: carry chain over chunks
__global__ __launch_bounds__(256) void carry_kernel(
    float* __restrict__ H, const float* __restrict__ cumb) {
    int u = blockIdx.x;
    int tid = threadIdx.x;
    float P[NC];
#pragma unroll
    for (int c = 0; c < NC; ++c) P[c] = cumb[(u << 10) + c * LC + (LC - 1)];
    float carry[16];
#pragma unroll
    for (int j = 0; j < 16; ++j) carry[j] = 0.f;
    for (int c = 0; c < NC; ++c) {
        float* Hb = H + (size_t)(u * NC + c) * 4096 + tid * 16;
        float Pc = P[c];
#pragma unroll
        for (int j = 0; j < 4; ++j) {
            float4 e = *(const float4*)&Hb[j * 4];
            *(float4*)&Hb[j * 4] = make_float4(carry[j*4], carry[j*4+1], carry[j*4+2], carry[j*4+3]);
            carry[j*4]     = fmaf(Pc, carry[j*4],     e.x);
            carry[j*4 + 1] = fmaf(Pc, carry[j*4 + 1], e.y);
            carry[j*4 + 2] = fmaf(Pc, carry[j*4 + 2], e.z);
            carry[j*4 + 3] = fmaf(Pc, carry[j*4 + 3], e.w);
        }
    }
}

// ---------------------------------------------------------------- S3: y[t] += cum[t] * (C_t . h_in)
__global__ __launch_bounds__(64) void fix_kernel(
    const float* __restrict__ xc, float* __restrict__ y,
    const float* __restrict__ H, const float* __restrict__ cumb) {
    __shared__ float sC[LC * 64];
    __shared__ float sCum[LC];
    int blk = blockIdx.x;
    int u = blk / (NC - 1);
    int c = blk % (NC - 1) + 1;
    int dir = u >> 4, b = (u >> 3) & 1, h = u & 7;
    int p = threadIdx.x;
    const float* xcd = xc + (size_t)dir * ROWS * CONVDIM;
    float* yd = y + (size_t)dir * ROWS * DINNER;
    int t0 = c * LC, base = b << 10;
    sCum[p] = cumb[(u << 10) + t0 + p];
#pragma unroll
    for (int j = 0; j < 16; ++j) {
        int f4 = j * 64 + p;
        int trow = f4 >> 4, col4 = f4 & 15;
        float4 v = *(const float4*)&xcd[(size_t)(base + t0 + trow) * CONVDIM + DINNER + DSTATE + col4 * 4];
        *(float4*)&sC[trow * 64 + col4 * 4] = v;
    }
    const float* Hb = H + (size_t)(u * NC + c) * 4096 + p * 64;
    float hin[DSTATE];
#pragma unroll
    for (int n = 0; n < DSTATE; n += 4) {
        float4 v = *(const float4*)&Hb[n];
        hin[n] = v.x; hin[n + 1] = v.y; hin[n + 2] = v.z; hin[n + 3] = v.w;
    }
    __syncthreads();
#pragma unroll 2
    for (int tt = 0; tt < LC; ++tt) {
        float cumt = sCum[tt];
        const float* Cs = &sC[tt * 64];
        float y0 = 0.f, y1 = 0.f, y2 = 0.f, y3 = 0.f;
#pragma unroll
        for (int n = 0; n < DSTATE; n += 4) {
            y0 = fmaf(hin[n],     Cs[n],     y0);
            y1 = fmaf(hin[n + 1], Cs[n + 1], y1);
            y2 = fmaf(hin[n + 2], Cs[n + 2], y2);
            y3 = fmaf(hin[n + 3], Cs[n + 3], y3);
        }
        size_t yi = (size_t)(base + t0 + tt) * DINNER + h * HEADDIM + p;
        yd[yi] += cumt * ((y0 + y1) + (y2 + y3));
    }
}

// ---------------------------------------------------------------- y*silu(z), RMSNorm*nw -> f16 pairs
__global__ __launch_bounds__(256) void gate_rms_kernel(
    const float* __restrict__ y, const float* __restrict__ zbuf,
    const float* __restrict__ nw, f16* __restrict__ yh, f16* __restrict__ yl, int layer) {
    int row = blockIdx.x;
    int dir = blockIdx.y;
    const float* zrow = zbuf + ((size_t)dir * ROWS + row) * DINNER;
    const float* yrow = y + ((size_t)dir * ROWS + row) * DINNER;
    f16* yhr = yh + ((size_t)dir * ROWS + row) * DINNER;
    f16* ylr = yl + ((size_t)dir * ROWS + row) * DINNER;
    const float* nwl = nw + (dir * 2 + layer) * DINNER;
    int tid = threadIdx.x;
    int i0 = tid, i1 = tid + 256;
    float g0 = yrow[i0] * siluf_(zrow[i0]);
    float g1 = yrow[i1] * siluf_(zrow[i1]);
    __shared__ float red[256];
    red[tid] = fmaf(g0, g0, g1 * g1);
    __syncthreads();
    for (int s = 128; s > 0; s >>= 1) {
        if (tid < s) red[tid] += red[tid + s];
        __syncthreads();
    }
    float scale = 1.0f / sqrtf(red[0] / (float)DINNER + EPSF);
    float v0 = g0 * scale * nwl[i0];
    float v1 = g1 * scale * nwl[i1];
    f16 h, l;
    split16(v0, h, l); yhr[i0] = h; ylr[i0] = l;
    split16(v1, h, l); yhr[i1] = h; ylr[i1] = l;
}

// ---------------------------------------------------------------- fusion gates + LayerNorm
__global__ __launch_bounds__(256) void fusion_ln2_kernel(
    const float* __restrict__ u32, const float* __restrict__ gate,
    const float* __restrict__ fb, const float* __restrict__ lnw,
    const float* __restrict__ lnb, float* __restrict__ out) {
    int row = blockIdx.x;
    int b = row >> 10, t = row & 1023;
    int tid = threadIdx.x;
    float f  = u32[(size_t)row * DMODEL + tid];
    float bw = u32[(size_t)ROWS * DMODEL + ((size_t)(b << 10) + (1023 - t)) * DMODEL + tid];
    float g0 = sigmoidf_(gate[(size_t)row * 512 + tid] + fb[tid]);
    float g1 = sigmoidf_(gate[(size_t)row * 512 + 256 + tid] + fb[256 + tid]);
    float fused = g0 * f + g1 * bw;
    __shared__ float red[256];
    red[tid] = fused;
    __syncthreads();
    for (int s = 128; s > 0; s >>= 1) {
        if (tid < s) red[tid] += red[tid + s];
        __syncthreads();
    }
    float mu = red[0] / (float)DMODEL;
    __syncthreads();
    float d = fused - mu;
    red[tid] = d * d;
    __syncthreads();
    for (int s = 128; s > 0; s >>= 1) {
        if (tid < s) red[tid] += red[tid + s];
        __syncthreads();
    }
    float var = red[0] / (float)DMODEL;
    out[(size_t)row * DMODEL + tid] = d * (1.0f / sqrtf(var + EPSF)) * lnw[tid] + lnb[tid];
}

// ---------------------------------------------------------------- launch
extern "C" void kernel_launch(void* const* d_in, const int* in_sizes, int n_in,
                              void* d_out, int out_size, void* d_ws, size_t ws_size,
                              hipStream_t stream) {
    const int*   ids  = (const int*)d_in[0];
    const float* mask = (const float*)d_in[1];
    const float* tok  = (const float*)d_in[2];
    const float* pos  = (const float*)d_in[3];
    const float* inw  = (const float*)d_in[4];
    const float* cw   = (const float*)d_in[5];
    const float* cb   = (const float*)d_in[6];
    const float* dtb  = (const float*)d_in[7];
    const float* alog = (const float*)d_in[8];
    const float* dpar = (const float*)d_in[9];
    const float* nw   = (const float*)d_in[10];
    const float* ow   = (const float*)d_in[11];
    const float* fw   = (const float*)d_in[12];
    const float* fb   = (const float*)d_in[13];
    const float* lnw  = (const float*)d_in[14];
    const float* lnb  = (const float*)d_in[15];

    float* ws = (float*)d_ws;
    // float-unit offsets
    float* zbuf = ws;                      // 2,097,152 f  (z, fp32)
    float* xbc  = ws + 2097152;            // 2,654,208 f  (in_proj xBC+dtraw fp32; later H + cumb overlay)
    float* xc   = ws + 4751360;            // 2,621,440 f  (conv out fp32; later yh/yl pairs, then gate)
    float* dts  = ws + 7372800;            //    32,768 f
    float* ybuf = ws + 7405568;            // 2,097,152 f  (scan y fp32; later u_fp32 + comb pairs)
    f16*   uh   = (f16*)(ws + 9502720);    // 1,048,576 h
    f16*   ul   = (f16*)(ws + 10027008);   // 1,048,576 h
    f16*   wb   = (f16*)(ws + 10551296);   // 2,236,416 h (weight pairs)
    // overlays
    float* H    = xbc;                     // 512 * 4096 f
    float* cumb = xbc + 2097152;           // 32,768 f
    f16*   yh   = (f16*)xc;                // 2,097,152 h
    f16*   yl   = (f16*)(xc + 1048576);    // 2,097,152 h
    float* gate = xc;                      // 1,048,576 f (fusion time; yh/yl dead)
    float* u32  = ybuf;                    // 1,048,576 f (out_proj fp32)
    f16*   combh = (f16*)(ybuf + 1048576); // 1,048,576 h
    f16*   combl = (f16*)(ybuf + 1572864); // 1,048,576 h
    // weight-pair sub-pointers
    f16* wih = wb;               f16* wil = wb + WIN;
    f16* woh = wb + 2 * WIN;     f16* wol = wb + 2 * WIN + WOUT;
    f16* wfh = wb + 2 * WIN + 2 * WOUT;
    f16* wfl = wfh + WF;

    embed_kernel<<<ROWS, DMODEL, 0, stream>>>(ids, mask, tok, pos, uh, ul);

    for (int layer = 0; layer < 2; ++layer) {
        int wtot = WIN + WOUT + (layer == 1 ? WF : 0);
        wconv_kernel<<<(wtot + 1023) / 1024, 256, 0, stream>>>(inw, ow, fw, wb, layer, wtot);

        // in_proj: A=(uh,ul) [dir][2048][256], W pairs, N=1160 -> zbuf(512) + xbc(648)
        dim3 g1(ROWS / 64, (DINPROJ + 63) / 64, 2);
        gemm_f16x3<<<g1, 256, 0, stream>>>(
            uh, ul, (long)ROWS * DMODEL,
            wih, wil, (long)PSI,
            DINPROJ, DMODEL, DINNER,
            zbuf, DINNER, (long)ROWS * DINNER,
            xbc, XBCW, (long)ROWS * XBCW,
            (f16*)nullptr, (f16*)nullptr, 0, 0L,
            1, 0, 0);

        conv_dt_kernel<<<dim3(ROWS, 2), 256, 0, stream>>>(xbc, xc, dts, cw, cb, dtb, layer);
        scan_chunk_kernel<<<32 * NC, 64, 0, stream>>>(xc, dts, ybuf, alog, dpar, H, cumb, layer);
        carry_kernel<<<32, 256, 0, stream>>>(H, cumb);
        fix_kernel<<<32 * (NC - 1), 64, 0, stream>>>(xc, ybuf, H, cumb);
        gate_rms_kernel<<<dim3(ROWS, 2), 256, 0, stream>>>(ybuf, zbuf, nw, yh, yl, layer);

        // out_proj: A=(yh,yl) [dir][2048][512], N=256 -> u32 fp32 + pairs
        // layer 0: pairs -> uh/ul (per-dir, ldP=256); layer 1: pairs -> comb layout with flip
        dim3 g2(ROWS / 64, DMODEL / 64, 2);
        if (layer == 0) {
            gemm_f16x3<<<g2, 256, 0, stream>>>(
                yh, yl, (long)ROWS * DINNER,
                woh, wol, (long)PSO,
                DMODEL, DINNER, DMODEL,
                u32, DMODEL, (long)ROWS * DMODEL,
                u32, DMODEL, (long)ROWS * DMODEL,
                uh, ul, DMODEL, (long)ROWS * DMODEL,
                1, 1, 0);
        } else {
            gemm_f16x3<<<g2, 256, 0, stream>>>(
                yh, yl, (long)ROWS * DINNER,
                woh, wol, (long)PSO,
                DMODEL, DINNER, DMODEL,
                u32, DMODEL, (long)ROWS * DMODEL,
                u32, DMODEL, (long)ROWS * DMODEL,
                combh, combl, 512, 0L,
                1, 1, 1);
        }
    }

    // fusion: A=(combh,combl) [2048][512], N=512 -> gate fp32
    dim3 g3(ROWS / 64, 512 / 64, 1);
    gemm_f16x3<<<g3, 256, 0, stream>>>(
        combh, combl, 0L,
        wfh, wfl, 0L,
        512, 512, 512,
        gate, 512, 0L,
        gate, 512, 0L,
        (f16*)nullptr, (f16*)nullptr, 0, 0L,
        1, 0, 0);

    fusion_ln2_kernel<<<ROWS, 256, 0, stream>>>(u32, gate, fb, lnw, lnb, (float*)d_out);
}

// Round 6
// 415.040 us; speedup vs baseline: 1.0184x; 1.0184x over previous
//
#include <hip/hip_runtime.h>
#include <cstddef>

#define LSEQ    1024
#define DMODEL  256
#define DINNER  512
#define DSTATE  64
#define NHEADS  8
#define HEADDIM 64
#define CONVDIM 640
#define DINPROJ 1160
#define ROWS    2048   // B * L
#define EPSF    1e-5f
#define NC      32     // chunks per sequence
#define LC      32     // chunk length
#define XBCW    648    // xBC (640) + raw dt (8)
#define HROW    131072 // 32 units * 4096 floats per chunk-row (c-major H)

// weight-pair buffer geometry (element counts)
#define WIN  593920    // 2 dirs * 1160 * 256 (one layer of in_w)
#define WOUT 262144    // 2 dirs * 256 * 512  (one layer of out_w)
#define WF   262144    // 512 * 512           (fusion_w)
#define PSI  296960    // 1160*256 per (dir,layer) slice of in_w
#define PSO  131072    // 256*512  per (dir,layer) slice of out_w

typedef _Float16 f16;
typedef f16   v8h __attribute__((ext_vector_type(8)));
typedef float v4f __attribute__((ext_vector_type(4)));
#define MFMA16(a, b, c) __builtin_amdgcn_mfma_f32_16x16x32_f16(a, b, c, 0, 0, 0)

__device__ __forceinline__ float sigmoidf_(float x) { return 1.0f / (1.0f + expf(-x)); }
__device__ __forceinline__ float siluf_(float x)    { return x / (1.0f + expf(-x)); }
__device__ __forceinline__ float softplusf_(float x) {
    return x > 0.0f ? x + log1pf(expf(-x)) : log1pf(expf(x));
}
__device__ __forceinline__ void split16(float v, f16& h, f16& l) {
    h = (f16)v;                          // RN; v - h exact in fp32
    l = (f16)((v - (float)h) * 4096.0f); // residual beyond pair <= 2^-24 |v|
}
// H is stored c-major, split across two regions (xbc overlay holds chunk-rows 0..19)
__device__ __forceinline__ float* hrow_(float* HA, float* HB, int c) {
    return c < 20 ? HA + (size_t)c * HROW : HB + (size_t)(c - 20) * HROW;
}
__device__ __forceinline__ const float* hrow_c(const float* HA, const float* HB, int c) {
    return c < 20 ? HA + (size_t)c * HROW : HB + (size_t)(c - 20) * HROW;
}

// ---------------------------------------------------------------- embedding -> f16 pairs (fwd + time-flipped)
__global__ __launch_bounds__(256) void embed_kernel(
    const int* __restrict__ ids, const float* __restrict__ mask,
    const float* __restrict__ tok, const float* __restrict__ pos,
    f16* __restrict__ uh, f16* __restrict__ ul) {
    int row = blockIdx.x;            // b*1024 + t
    int d = threadIdx.x;
    int b = row >> 10, t = row & 1023;
    int id = ids[row];
    float v = tok[(size_t)id * DMODEL + d] + pos[(size_t)t * DMODEL + d];
    v *= mask[row];
    f16 h, l; split16(v, h, l);
    size_t fwd = (size_t)row * DMODEL + d;
    size_t bwd = (size_t)ROWS * DMODEL + ((size_t)(b << 10) + (1023 - t)) * DMODEL + d;
    uh[fwd] = h; ul[fwd] = l;
    uh[bwd] = h; ul[bwd] = l;
}

// ---------------------------------------------------------------- weight fp32 -> f16 pair conversion (per layer)
__global__ __launch_bounds__(256) void wconv_kernel(
    const float* __restrict__ inw, const float* __restrict__ ow, const float* __restrict__ fw,
    f16* __restrict__ wb, int layer, int total) {
    int idx = (blockIdx.x * 256 + threadIdx.x) * 4;
#pragma unroll
    for (int e = idx; e < idx + 4; ++e) {
        if (e >= total) break;
        float v; f16 *dh, *dl; int off;
        if (e < WIN) {
            int d = e / PSI, r = e - d * PSI;
            v = inw[(size_t)(d * 2 + layer) * PSI + r];
            dh = wb; dl = wb + WIN; off = e;
        } else if (e < WIN + WOUT) {
            int e2 = e - WIN;
            int d = e2 / PSO, r = e2 - d * PSO;
            v = ow[(size_t)(d * 2 + layer) * PSO + r];
            dh = wb + 2 * WIN; dl = dh + WOUT; off = e2;
        } else {
            int e3 = e - WIN - WOUT;
            v = fw[e3];
            dh = wb + 2 * WIN + 2 * WOUT; dl = dh + WF; off = e3;
        }
        f16 h, l; split16(v, h, l);
        dh[off] = h; dl[off] = l;
    }
}

// ---------------------------------------------------------------- f16x3 MFMA GEMM: C[M,N] = A[M,K] * W[N,K]^T
__global__ __launch_bounds__(256) void gemm_f16x3(
    const f16* __restrict__ Ah, const f16* __restrict__ Al, long sA,
    const f16* __restrict__ Wh, const f16* __restrict__ Wl, long sW,
    int N, int K, int Nsplit,
    float* __restrict__ O0, int ld0, long sO0,
    float* __restrict__ O1, int ld1, long sO1,
    f16* __restrict__ Ph, f16* __restrict__ Pl, int ldP, long sP,
    int has32, int haspair, int flipcomb) {
    int dir = blockIdx.z;
    Ah += (size_t)dir * sA; Al += (size_t)dir * sA;
    Wh += (size_t)dir * sW; Wl += (size_t)dir * sW;
    if (has32)  { O0 += (size_t)dir * sO0; O1 += (size_t)dir * sO1; }
    if (haspair){ Ph += (size_t)dir * sP;  Pl += (size_t)dir * sP; }

    __shared__ f16 sm[4 * 64 * 72];      // Ah | Al | Wh | Wl tiles, 64 rows x 64 k, pitch 72
    f16* As_h = sm;
    f16* As_l = sm + 64 * 72;
    f16* Ws_h = sm + 2 * 64 * 72;
    f16* Ws_l = sm + 3 * 64 * 72;

    int tid = threadIdx.x;
    int m0 = blockIdx.x * 64, n0 = blockIdx.y * 64;
    int srow = tid >> 2, sseg = tid & 3;           // staging: 64 rows x 4 segs of 16 halves
    int lane = tid & 63, w = tid >> 6;
    int wrow = (w >> 1) * 32, wcol = (w & 1) * 32;
    int q = lane >> 4, r16 = lane & 15;
    bool wok = (n0 + srow) < N;

    v4f accM[2][2], accX[2][2];
#pragma unroll
    for (int i = 0; i < 2; ++i)
#pragma unroll
        for (int j = 0; j < 2; ++j) { accM[i][j] = (v4f)0.0f; accX[i][j] = (v4f)0.0f; }

    for (int k0 = 0; k0 < K; k0 += 64) {
        size_t aoff = (size_t)(m0 + srow) * K + k0 + sseg * 16;
        float4 ah0 = *(const float4*)&Ah[aoff];
        float4 ah1 = *(const float4*)&Ah[aoff + 8];
        float4 al0 = *(const float4*)&Al[aoff];
        float4 al1 = *(const float4*)&Al[aoff + 8];
        float4 wh0 = make_float4(0.f,0.f,0.f,0.f), wh1 = wh0, wl0 = wh0, wl1 = wh0;
        if (wok) {
            size_t woff = (size_t)(n0 + srow) * K + k0 + sseg * 16;
            wh0 = *(const float4*)&Wh[woff];
            wh1 = *(const float4*)&Wh[woff + 8];
            wl0 = *(const float4*)&Wl[woff];
            wl1 = *(const float4*)&Wl[woff + 8];
        }
        __syncthreads();                 // previous iteration's reads done
        int d = srow * 72 + sseg * 16;
        *(float4*)&As_h[d] = ah0; *(float4*)&As_h[d + 8] = ah1;
        *(float4*)&As_l[d] = al0; *(float4*)&As_l[d + 8] = al1;
        *(float4*)&Ws_h[d] = wh0; *(float4*)&Ws_h[d + 8] = wh1;
        *(float4*)&Ws_l[d] = wl0; *(float4*)&Ws_l[d + 8] = wl1;
        __syncthreads();

#pragma unroll
        for (int ks = 0; ks < 64; ks += 32) {
            v8h fa_h[2], fa_l[2], fb_h[2], fb_l[2];
#pragma unroll
            for (int i = 0; i < 2; ++i) {
                int ra = (wrow + i * 16 + r16) * 72 + ks + q * 8;
                int rb = (wcol + i * 16 + r16) * 72 + ks + q * 8;
                fa_h[i] = *(const v8h*)&As_h[ra];
                fa_l[i] = *(const v8h*)&As_l[ra];
                fb_h[i] = *(const v8h*)&Ws_h[rb];
                fb_l[i] = *(const v8h*)&Ws_l[rb];
            }
#pragma unroll
            for (int i = 0; i < 2; ++i)
#pragma unroll
                for (int j = 0; j < 2; ++j) {
                    accM[i][j] = MFMA16(fa_h[i], fb_h[j], accM[i][j]);
                    accX[i][j] = MFMA16(fa_h[i], fb_l[j], accX[i][j]);
                    accX[i][j] = MFMA16(fa_l[i], fb_h[j], accX[i][j]);
                }
        }
    }

    const float cs = 1.0f / 4096.0f;
#pragma unroll
    for (int i = 0; i < 2; ++i)
#pragma unroll
        for (int j = 0; j < 2; ++j) {
            int nn = n0 + wcol + j * 16 + r16;
            if (nn < N) {
#pragma unroll
                for (int r = 0; r < 4; ++r) {
                    float v = accM[i][j][r] + accX[i][j][r] * cs;
                    int mm = m0 + wrow + i * 16 + q * 4 + r;
                    if (has32) {
                        if (nn < Nsplit) O0[(size_t)mm * ld0 + nn] = v;
                        else             O1[(size_t)mm * ld1 + (nn - Nsplit)] = v;
                    }
                    if (haspair) {
                        f16 h, l; split16(v, h, l);
                        if (flipcomb) {
                            int bb = mm >> 10, tt_ = mm & 1023;
                            size_t drow = dir == 0 ? (size_t)mm : (size_t)((bb << 10) + (1023 - tt_));
                            size_t dcol = dir == 0 ? (size_t)nn : (size_t)(nn + 256);
                            Ph[drow * 512 + dcol] = h;
                            Pl[drow * 512 + dcol] = l;
                        } else {
                            Ph[(size_t)mm * ldP + nn] = h;
                            Pl[(size_t)mm * ldP + nn] = l;
                        }
                    }
                }
            }
        }
}

// ---------------------------------------------------------------- depthwise causal conv(4) + SiLU, plus softplus(dt)
__global__ __launch_bounds__(256) void conv_dt_kernel(
    const float* __restrict__ xbc, float* __restrict__ xc, float* __restrict__ dts,
    const float* __restrict__ cw, const float* __restrict__ cb,
    const float* __restrict__ dtb, int layer) {
    int row = blockIdx.x;            // b*1024+t
    int dir = blockIdx.y;
    int b = row >> 10, t = row & 1023;
    const float* xd = xbc + (size_t)dir * ROWS * XBCW;
    int pi = dir * 2 + layer;
    const float* cwl = cw + (size_t)pi * CONVDIM * 4;
    const float* cbl = cb + (size_t)pi * CONVDIM;
    const float* dtbl = dtb + pi * NHEADS;
    for (int c = threadIdx.x; c < CONVDIM + NHEADS; c += 256) {
        if (c < CONVDIM) {
            float acc = cbl[c];
#pragma unroll
            for (int k = 0; k < 4; ++k) {
                int tt = t - 3 + k;
                if (tt >= 0)
                    acc = fmaf(xd[(size_t)((b << 10) + tt) * XBCW + c], cwl[c * 4 + k], acc);
            }
            xc[((size_t)dir * ROWS + row) * CONVDIM + c] = siluf_(acc);
        } else {
            int hh = c - CONVDIM;
            dts[((size_t)dir * ROWS + row) * NHEADS + hh] =
                softplusf_(xd[(size_t)row * XBCW + CONVDIM + hh] + dtbl[hh]);
        }
    }
}

// ---------------------------------------------------------------- S1: local chunk scan (LC=32), shfl scalars
__global__ __launch_bounds__(64) void scan_chunk_kernel(
    const float* __restrict__ xc, const float* __restrict__ dts,
    float* __restrict__ y, const float* __restrict__ Alog, const float* __restrict__ Dp,
    float* __restrict__ HA, float* __restrict__ HB, float* __restrict__ cumb, int layer) {
    __shared__ float sBC[LC * 128];   // 16 KB
    __shared__ float sX[LC * 64];     // 8 KB
    int blk = blockIdx.x;
    int u = blk >> 5, c = blk & 31;
    int dir = u >> 4, b = (u >> 3) & 1, h = u & 7;
    int p = threadIdx.x;
    int pi = dir * 2 + layer;
    float Av = -expf(Alog[pi * NHEADS + h]);
    float Dv = Dp[pi * NHEADS + h];
    const float* xcd = xc + (size_t)dir * ROWS * CONVDIM;
    const float* dtd = dts + (size_t)dir * ROWS * NHEADS;
    float* yd = y + (size_t)dir * ROWS * DINNER;
    int t0 = c * LC, base = b << 10;

    // lane t (t = p & 31): dt / dA for step t of this chunk
    int tp = p & (LC - 1);
    float dt_l = dtd[(size_t)(base + t0 + tp) * NHEADS + h];
    float dA_l = expf(dt_l * Av);
    float cum_l = dA_l;
#pragma unroll
    for (int off = 1; off < LC; off <<= 1) {
        float o = __shfl_up(cum_l, off);
        if ((p & (LC - 1)) >= off) cum_l *= o;
    }
    if (p < LC) cumb[(u << 10) + t0 + p] = cum_l;

    // stage B/C (xc cols 512..639): 32 rows x 128 floats
#pragma unroll
    for (int j = 0; j < 16; ++j) {
        int f4 = j * 64 + p;
        int trow = f4 >> 5, col4 = f4 & 31;
        float4 v = *(const float4*)&xcd[(size_t)(base + t0 + trow) * CONVDIM + DINNER + col4 * 4];
        *(float4*)&sBC[trow * 128 + col4 * 4] = v;
    }
    // stage x head-slice: 32 rows x 64 floats
#pragma unroll
    for (int j = 0; j < 8; ++j) {
        int f4 = j * 64 + p;
        int trow = f4 >> 4, col4 = f4 & 15;
        float4 v = *(const float4*)&xcd[(size_t)(base + t0 + trow) * CONVDIM + h * HEADDIM + col4 * 4];
        *(float4*)&sX[trow * 64 + col4 * 4] = v;
    }
    __syncthreads();

    float hreg[DSTATE];
#pragma unroll
    for (int n = 0; n < DSTATE; ++n) hreg[n] = 0.f;

#pragma unroll 2
    for (int tt = 0; tt < LC; ++tt) {
        float dtv = __shfl(dt_l, tt);
        float dA  = __shfl(dA_l, tt);
        float xv = sX[tt * 64 + p];
        float coef = dtv * xv;
        const float* Bsr = &sBC[tt * 128];
        const float* Csr = Bsr + 64;
        float y0 = 0.f, y1 = 0.f, y2 = 0.f, y3 = 0.f;
#pragma unroll
        for (int n = 0; n < DSTATE; n += 4) {
            float4 b4 = *(const float4*)&Bsr[n];
            float4 c4 = *(const float4*)&Csr[n];
            hreg[n]     = fmaf(hreg[n],     dA, coef * b4.x); y0 = fmaf(hreg[n],     c4.x, y0);
            hreg[n + 1] = fmaf(hreg[n + 1], dA, coef * b4.y); y1 = fmaf(hreg[n + 1], c4.y, y1);
            hreg[n + 2] = fmaf(hreg[n + 2], dA, coef * b4.z); y2 = fmaf(hreg[n + 2], c4.z, y2);
            hreg[n + 3] = fmaf(hreg[n + 3], dA, coef * b4.w); y3 = fmaf(hreg[n + 3], c4.w, y3);
        }
        yd[(size_t)(base + t0 + tt) * DINNER + h * HEADDIM + p] = (y0 + y1) + (y2 + y3) + Dv * xv;
    }
    float* Hb = hrow_(HA, HB, c) + (size_t)u * 4096 + p * 64;
#pragma unroll
    for (int n = 0; n < DSTATE; n += 4)
        *(float4*)&Hb[n] = make_float4(hreg[n], hreg[n + 1], hreg[n + 2], hreg[n + 3]);
}

// ---------------------------------------------------------------- S2: carry chain over chunks (in place: h_end -> h_in)
__global__ __launch_bounds__(256) void carry_kernel(
    float* __restrict__ HA, float* __restrict__ HB, const float* __restrict__ cumb) {
    int u = blockIdx.x;
    int tid = threadIdx.x;
    float carry[16];
#pragma unroll
    for (int j = 0; j < 16; ++j) carry[j] = 0.f;
    for (int c = 0; c < NC; ++c) {
        float Pc = cumb[(u << 10) + c * LC + (LC - 1)];
        float* Hb = hrow_(HA, HB, c) + (size_t)u * 4096 + tid * 16;
#pragma unroll
        for (int j = 0; j < 4; ++j) {
            float4 e = *(const float4*)&Hb[j * 4];
            *(float4*)&Hb[j * 4] = make_float4(carry[j*4], carry[j*4+1], carry[j*4+2], carry[j*4+3]);
            carry[j*4]     = fmaf(Pc, carry[j*4],     e.x);
            carry[j*4 + 1] = fmaf(Pc, carry[j*4 + 1], e.y);
            carry[j*4 + 2] = fmaf(Pc, carry[j*4 + 2], e.z);
            carry[j*4 + 3] = fmaf(Pc, carry[j*4 + 3], e.w);
        }
    }
}

// ---------------------------------------------------------------- S3: y[t] += cum[t] * (C_t . h_in), chunks 1..NC-1
__global__ __launch_bounds__(64) void fix_kernel(
    const float* __restrict__ xc, float* __restrict__ y,
    const float* __restrict__ HA, const float* __restrict__ HB,
    const float* __restrict__ cumb) {
    __shared__ float sC[LC * 64];
    int blk = blockIdx.x;
    int u = blk / (NC - 1);
    int c = blk % (NC - 1) + 1;
    int dir = u >> 4, b = (u >> 3) & 1, h = u & 7;
    int p = threadIdx.x;
    const float* xcd = xc + (size_t)dir * ROWS * CONVDIM;
    float* yd = y + (size_t)dir * ROWS * DINNER;
    int t0 = c * LC, base = b << 10;
    float cum_l = cumb[(u << 10) + t0 + (p & (LC - 1))];   // lane t holds cum[t]
#pragma unroll
    for (int j = 0; j < 8; ++j) {
        int f4 = j * 64 + p;
        int trow = f4 >> 4, col4 = f4 & 15;
        float4 v = *(const float4*)&xcd[(size_t)(base + t0 + trow) * CONVDIM + DINNER + DSTATE + col4 * 4];
        *(float4*)&sC[trow * 64 + col4 * 4] = v;
    }
    const float* Hb = hrow_c(HA, HB, c) + (size_t)u * 4096 + p * 64;
    float hin[DSTATE];
#pragma unroll
    for (int n = 0; n < DSTATE; n += 4) {
        float4 v = *(const float4*)&Hb[n];
        hin[n] = v.x; hin[n + 1] = v.y; hin[n + 2] = v.z; hin[n + 3] = v.w;
    }
    __syncthreads();
#pragma unroll 2
    for (int tt = 0; tt < LC; ++tt) {
        float cumt = __shfl(cum_l, tt);
        const float* Cs = &sC[tt * 64];
        float y0 = 0.f, y1 = 0.f, y2 = 0.f, y3 = 0.f;
#pragma unroll
        for (int n = 0; n < DSTATE; n += 4) {
            y0 = fmaf(hin[n],     Cs[n],     y0);
            y1 = fmaf(hin[n + 1], Cs[n + 1], y1);
            y2 = fmaf(hin[n + 2], Cs[n + 2], y2);
            y3 = fmaf(hin[n + 3], Cs[n + 3], y3);
        }
        size_t yi = (size_t)(base + t0 + tt) * DINNER + h * HEADDIM + p;
        yd[yi] += cumt * ((y0 + y1) + (y2 + y3));
    }
}

// ---------------------------------------------------------------- y*silu(z), RMSNorm*nw -> f16 pairs
__global__ __launch_bounds__(256) void gate_rms_kernel(
    const float* __restrict__ y, const float* __restrict__ zbuf,
    const float* __restrict__ nw, f16* __restrict__ yh, f16* __restrict__ yl, int layer) {
    int row = blockIdx.x;
    int dir = blockIdx.y;
    const float* zrow = zbuf + ((size_t)dir * ROWS + row) * DINNER;
    const float* yrow = y + ((size_t)dir * ROWS + row) * DINNER;
    f16* yhr = yh + ((size_t)dir * ROWS + row) * DINNER;
    f16* ylr = yl + ((size_t)dir * ROWS + row) * DINNER;
    const float* nwl = nw + (dir * 2 + layer) * DINNER;
    int tid = threadIdx.x;
    int i0 = tid, i1 = tid + 256;
    float g0 = yrow[i0] * siluf_(zrow[i0]);
    float g1 = yrow[i1] * siluf_(zrow[i1]);
    __shared__ float red[256];
    red[tid] = fmaf(g0, g0, g1 * g1);
    __syncthreads();
    for (int s = 128; s > 0; s >>= 1) {
        if (tid < s) red[tid] += red[tid + s];
        __syncthreads();
    }
    float scale = 1.0f / sqrtf(red[0] / (float)DINNER + EPSF);
    float v0 = g0 * scale * nwl[i0];
    float v1 = g1 * scale * nwl[i1];
    f16 h, l;
    split16(v0, h, l); yhr[i0] = h; ylr[i0] = l;
    split16(v1, h, l); yhr[i1] = h; ylr[i1] = l;
}

// ---------------------------------------------------------------- fusion gates + LayerNorm
__global__ __launch_bounds__(256) void fusion_ln2_kernel(
    const float* __restrict__ u32, const float* __restrict__ gate,
    const float* __restrict__ fb, const float* __restrict__ lnw,
    const float* __restrict__ lnb, float* __restrict__ out) {
    int row = blockIdx.x;
    int b = row >> 10, t = row & 1023;
    int tid = threadIdx.x;
    float f  = u32[(size_t)row * DMODEL + tid];
    float bw = u32[(size_t)ROWS * DMODEL + ((size_t)(b << 10) + (1023 - t)) * DMODEL + tid];
    float g0 = sigmoidf_(gate[(size_t)row * 512 + tid] + fb[tid]);
    float g1 = sigmoidf_(gate[(size_t)row * 512 + 256 + tid] + fb[256 + tid]);
    float fused = g0 * f + g1 * bw;
    __shared__ float red[256];
    red[tid] = fused;
    __syncthreads();
    for (int s = 128; s > 0; s >>= 1) {
        if (tid < s) red[tid] += red[tid + s];
        __syncthreads();
    }
    float mu = red[0] / (float)DMODEL;
    __syncthreads();
    float d = fused - mu;
    red[tid] = d * d;
    __syncthreads();
    for (int s = 128; s > 0; s >>= 1) {
        if (tid < s) red[tid] += red[tid + s];
        __syncthreads();
    }
    float var = red[0] / (float)DMODEL;
    out[(size_t)row * DMODEL + tid] = d * (1.0f / sqrtf(var + EPSF)) * lnw[tid] + lnb[tid];
}

// ---------------------------------------------------------------- launch
extern "C" void kernel_launch(void* const* d_in, const int* in_sizes, int n_in,
                              void* d_out, int out_size, void* d_ws, size_t ws_size,
                              hipStream_t stream) {
    const int*   ids  = (const int*)d_in[0];
    const float* mask = (const float*)d_in[1];
    const float* tok  = (const float*)d_in[2];
    const float* pos  = (const float*)d_in[3];
    const float* inw  = (const float*)d_in[4];
    const float* cw   = (const float*)d_in[5];
    const float* cb   = (const float*)d_in[6];
    const float* dtb  = (const float*)d_in[7];
    const float* alog = (const float*)d_in[8];
    const float* dpar = (const float*)d_in[9];
    const float* nw   = (const float*)d_in[10];
    const float* ow   = (const float*)d_in[11];
    const float* fw   = (const float*)d_in[12];
    const float* fb   = (const float*)d_in[13];
    const float* lnw  = (const float*)d_in[14];
    const float* lnb  = (const float*)d_in[15];

    float* ws = (float*)d_ws;
    // float-unit offsets (total 13,275,136 f = 53.1 MB)
    float* zbuf = ws;                      // 2,097,152 f
    float* xbc  = ws + 2097152;            // 2,654,208 f (in_proj xBC+dtraw; later H chunk-rows 0..19)
    float* xc   = ws + 4751360;            // 2,621,440 f (conv out; later yh/yl pairs, then gate)
    float* dts  = ws + 7372800;            //    32,768 f
    float* ybuf = ws + 7405568;            // 2,097,152 f (scan y; later u_fp32 + comb pairs)
    f16*   uh   = (f16*)(ws + 9502720);    // 1,048,576 h
    f16*   ul   = (f16*)(ws + 10027008);   // 1,048,576 h
    f16*   wb   = (f16*)(ws + 10551296);   // 2,236,416 h (weight pairs)
    float* tailH= ws + 11669504;           // 1,572,864 f (H chunk-rows 20..31)
    float* cumb = ws + 13242368;           //    32,768 f
    // overlays
    float* HA   = xbc;                     // 20 * HROW
    float* HB   = tailH;                   // 12 * HROW
    f16*   yh   = (f16*)xc;                // 2,097,152 h
    f16*   yl   = (f16*)(xc + 1048576);    // 2,097,152 h
    float* gate = xc;                      // 1,048,576 f (fusion time; yh/yl dead)
    float* u32  = ybuf;                    // 1,048,576 f (out_proj fp32)
    f16*   combh = (f16*)(ybuf + 1048576); // 1,048,576 h
    f16*   combl = (f16*)(ybuf + 1572864); // 1,048,576 h
    // weight-pair sub-pointers
    f16* wih = wb;               f16* wil = wb + WIN;
    f16* woh = wb + 2 * WIN;     f16* wol = wb + 2 * WIN + WOUT;
    f16* wfh = wb + 2 * WIN + 2 * WOUT;
    f16* wfl = wfh + WF;

    embed_kernel<<<ROWS, DMODEL, 0, stream>>>(ids, mask, tok, pos, uh, ul);

    for (int layer = 0; layer < 2; ++layer) {
        int wtot = WIN + WOUT + (layer == 1 ? WF : 0);
        wconv_kernel<<<(wtot + 1023) / 1024, 256, 0, stream>>>(inw, ow, fw, wb, layer, wtot);

        // in_proj: A=(uh,ul) [dir][2048][256], W pairs, N=1160 -> zbuf(512) + xbc(648)
        dim3 g1(ROWS / 64, (DINPROJ + 63) / 64, 2);
        gemm_f16x3<<<g1, 256, 0, stream>>>(
            uh, ul, (long)ROWS * DMODEL,
            wih, wil, (long)PSI,
            DINPROJ, DMODEL, DINNER,
            zbuf, DINNER, (long)ROWS * DINNER,
            xbc, XBCW, (long)ROWS * XBCW,
            (f16*)nullptr, (f16*)nullptr, 0, 0L,
            1, 0, 0);

        conv_dt_kernel<<<dim3(ROWS, 2), 256, 0, stream>>>(xbc, xc, dts, cw, cb, dtb, layer);
        scan_chunk_kernel<<<32 * NC, 64, 0, stream>>>(xc, dts, ybuf, alog, dpar, HA, HB, cumb, layer);
        carry_kernel<<<32, 256, 0, stream>>>(HA, HB, cumb);
        fix_kernel<<<32 * (NC - 1), 64, 0, stream>>>(xc, ybuf, HA, HB, cumb);
        gate_rms_kernel<<<dim3(ROWS, 2), 256, 0, stream>>>(ybuf, zbuf, nw, yh, yl, layer);

        // out_proj: A=(yh,yl) [dir][2048][512], N=256 -> u32 fp32 + pairs
        dim3 g2(ROWS / 64, DMODEL / 64, 2);
        if (layer == 0) {
            gemm_f16x3<<<g2, 256, 0, stream>>>(
                yh, yl, (long)ROWS * DINNER,
                woh, wol, (long)PSO,
                DMODEL, DINNER, DMODEL,
                u32, DMODEL, (long)ROWS * DMODEL,
                u32, DMODEL, (long)ROWS * DMODEL,
                uh, ul, DMODEL, (long)ROWS * DMODEL,
                1, 1, 0);
        } else {
            gemm_f16x3<<<g2, 256, 0, stream>>>(
                yh, yl, (long)ROWS * DINNER,
                woh, wol, (long)PSO,
                DMODEL, DINNER, DMODEL,
                u32, DMODEL, (long)ROWS * DMODEL,
                u32, DMODEL, (long)ROWS * DMODEL,
                combh, combl, 512, 0L,
                1, 1, 1);
        }
    }

    // fusion: A=(combh,combl) [2048][512], N=512 -> gate fp32
    dim3 g3(ROWS / 64, 512 / 64, 1);
    gemm_f16x3<<<g3, 256, 0, stream>>>(
        combh, combl, 0L,
        wfh, wfl, 0L,
        512, 512, 512,
        gate, 512, 0L,
        gate, 512, 0L,
        (f16*)nullptr, (f16*)nullptr, 0, 0L,
        1, 0, 0);

    fusion_ln2_kernel<<<ROWS, 256, 0, stream>>>(u32, gate, fb, lnw, lnb, (float*)d_out);
}

// Round 7
// 409.205 us; speedup vs baseline: 1.0329x; 1.0143x over previous
//
#include <hip/hip_runtime.h>
#include <cstddef>

#define LSEQ    1024
#define DMODEL  256
#define DINNER  512
#define DSTATE  64
#define NHEADS  8
#define HEADDIM 64
#define CONVDIM 640
#define DINPROJ 1160
#define ROWS    2048   // B * L
#define EPSF    1e-5f
#define NC      32     // chunks per sequence
#define LC      32     // chunk length
#define XBCW    648    // xBC (640) + raw dt (8)
#define HROW    131072 // 32 units * 4096 floats per chunk-row (c-major H)

// weight-pair buffer geometry (element counts)
#define WIN  593920
#define WOUT 262144
#define WF   262144
#define PSI  296960
#define PSO  131072

typedef _Float16 f16;
typedef f16   v8h __attribute__((ext_vector_type(8)));
typedef f16   v4h __attribute__((ext_vector_type(4)));
typedef float v4f __attribute__((ext_vector_type(4)));
#define MFMA16(a, b, c) __builtin_amdgcn_mfma_f32_16x16x32_f16(a, b, c, 0, 0, 0)

__device__ __forceinline__ float sigmoidf_(float x) { return 1.0f / (1.0f + expf(-x)); }
__device__ __forceinline__ float siluf_(float x)    { return x / (1.0f + expf(-x)); }
__device__ __forceinline__ float softplusf_(float x) {
    return x > 0.0f ? x + log1pf(expf(-x)) : log1pf(expf(x));
}
__device__ __forceinline__ void split16(float v, f16& h, f16& l) {
    h = (f16)v;
    l = (f16)((v - (float)h) * 4096.0f);
}
__device__ __forceinline__ float* hrow_(float* HA, float* HB, int c) {
    return c < 20 ? HA + (size_t)c * HROW : HB + (size_t)(c - 20) * HROW;
}
__device__ __forceinline__ const float* hrow_c(const float* HA, const float* HB, int c) {
    return c < 20 ? HA + (size_t)c * HROW : HB + (size_t)(c - 20) * HROW;
}

// ---------------------------------------------------------------- embedding -> f16 pairs
__global__ __launch_bounds__(256) void embed_kernel(
    const int* __restrict__ ids, const float* __restrict__ mask,
    const float* __restrict__ tok, const float* __restrict__ pos,
    f16* __restrict__ uh, f16* __restrict__ ul) {
    int row = blockIdx.x;
    int d = threadIdx.x;
    int b = row >> 10, t = row & 1023;
    int id = ids[row];
    float v = tok[(size_t)id * DMODEL + d] + pos[(size_t)t * DMODEL + d];
    v *= mask[row];
    f16 h, l; split16(v, h, l);
    size_t fwd = (size_t)row * DMODEL + d;
    size_t bwd = (size_t)ROWS * DMODEL + ((size_t)(b << 10) + (1023 - t)) * DMODEL + d;
    uh[fwd] = h; ul[fwd] = l;
    uh[bwd] = h; ul[bwd] = l;
}

// ---------------------------------------------------------------- weight fp32 -> f16 pairs (per layer)
__global__ __launch_bounds__(256) void wconv_kernel(
    const float* __restrict__ inw, const float* __restrict__ ow, const float* __restrict__ fw,
    f16* __restrict__ wb, int layer, int total) {
    int idx = (blockIdx.x * 256 + threadIdx.x) * 4;
#pragma unroll
    for (int e = idx; e < idx + 4; ++e) {
        if (e >= total) break;
        float v; f16 *dh, *dl; int off;
        if (e < WIN) {
            int d = e / PSI, r = e - d * PSI;
            v = inw[(size_t)(d * 2 + layer) * PSI + r];
            dh = wb; dl = wb + WIN; off = e;
        } else if (e < WIN + WOUT) {
            int e2 = e - WIN;
            int d = e2 / PSO, r = e2 - d * PSO;
            v = ow[(size_t)(d * 2 + layer) * PSO + r];
            dh = wb + 2 * WIN; dl = dh + WOUT; off = e2;
        } else {
            int e3 = e - WIN - WOUT;
            v = fw[e3];
            dh = wb + 2 * WIN + 2 * WOUT; dl = dh + WF; off = e3;
        }
        f16 h, l; split16(v, h, l);
        dh[off] = h; dl[off] = l;
    }
}

// ---------------------------------------------------------------- f16x3 MFMA GEMM (unchanged, verified)
__global__ __launch_bounds__(256) void gemm_f16x3(
    const f16* __restrict__ Ah, const f16* __restrict__ Al, long sA,
    const f16* __restrict__ Wh, const f16* __restrict__ Wl, long sW,
    int N, int K, int Nsplit,
    float* __restrict__ O0, int ld0, long sO0,
    float* __restrict__ O1, int ld1, long sO1,
    f16* __restrict__ Ph, f16* __restrict__ Pl, int ldP, long sP,
    int has32, int haspair, int flipcomb) {
    int dir = blockIdx.z;
    Ah += (size_t)dir * sA; Al += (size_t)dir * sA;
    Wh += (size_t)dir * sW; Wl += (size_t)dir * sW;
    if (has32)  { O0 += (size_t)dir * sO0; O1 += (size_t)dir * sO1; }
    if (haspair){ Ph += (size_t)dir * sP;  Pl += (size_t)dir * sP; }

    __shared__ f16 sm[4 * 64 * 72];
    f16* As_h = sm;
    f16* As_l = sm + 64 * 72;
    f16* Ws_h = sm + 2 * 64 * 72;
    f16* Ws_l = sm + 3 * 64 * 72;

    int tid = threadIdx.x;
    int m0 = blockIdx.x * 64, n0 = blockIdx.y * 64;
    int srow = tid >> 2, sseg = tid & 3;
    int lane = tid & 63, w = tid >> 6;
    int wrow = (w >> 1) * 32, wcol = (w & 1) * 32;
    int q = lane >> 4, r16 = lane & 15;
    bool wok = (n0 + srow) < N;

    v4f accM[2][2], accX[2][2];
#pragma unroll
    for (int i = 0; i < 2; ++i)
#pragma unroll
        for (int j = 0; j < 2; ++j) { accM[i][j] = (v4f)0.0f; accX[i][j] = (v4f)0.0f; }

    for (int k0 = 0; k0 < K; k0 += 64) {
        size_t aoff = (size_t)(m0 + srow) * K + k0 + sseg * 16;
        float4 ah0 = *(const float4*)&Ah[aoff];
        float4 ah1 = *(const float4*)&Ah[aoff + 8];
        float4 al0 = *(const float4*)&Al[aoff];
        float4 al1 = *(const float4*)&Al[aoff + 8];
        float4 wh0 = make_float4(0.f,0.f,0.f,0.f), wh1 = wh0, wl0 = wh0, wl1 = wh0;
        if (wok) {
            size_t woff = (size_t)(n0 + srow) * K + k0 + sseg * 16;
            wh0 = *(const float4*)&Wh[woff];
            wh1 = *(const float4*)&Wh[woff + 8];
            wl0 = *(const float4*)&Wl[woff];
            wl1 = *(const float4*)&Wl[woff + 8];
        }
        __syncthreads();
        int d = srow * 72 + sseg * 16;
        *(float4*)&As_h[d] = ah0; *(float4*)&As_h[d + 8] = ah1;
        *(float4*)&As_l[d] = al0; *(float4*)&As_l[d + 8] = al1;
        *(float4*)&Ws_h[d] = wh0; *(float4*)&Ws_h[d + 8] = wh1;
        *(float4*)&Ws_l[d] = wl0; *(float4*)&Ws_l[d + 8] = wl1;
        __syncthreads();

#pragma unroll
        for (int ks = 0; ks < 64; ks += 32) {
            v8h fa_h[2], fa_l[2], fb_h[2], fb_l[2];
#pragma unroll
            for (int i = 0; i < 2; ++i) {
                int ra = (wrow + i * 16 + r16) * 72 + ks + q * 8;
                int rb = (wcol + i * 16 + r16) * 72 + ks + q * 8;
                fa_h[i] = *(const v8h*)&As_h[ra];
                fa_l[i] = *(const v8h*)&As_l[ra];
                fb_h[i] = *(const v8h*)&Ws_h[rb];
                fb_l[i] = *(const v8h*)&Ws_l[rb];
            }
#pragma unroll
            for (int i = 0; i < 2; ++i)
#pragma unroll
                for (int j = 0; j < 2; ++j) {
                    accM[i][j] = MFMA16(fa_h[i], fb_h[j], accM[i][j]);
                    accX[i][j] = MFMA16(fa_h[i], fb_l[j], accX[i][j]);
                    accX[i][j] = MFMA16(fa_l[i], fb_h[j], accX[i][j]);
                }
        }
    }

    const float cs = 1.0f / 4096.0f;
#pragma unroll
    for (int i = 0; i < 2; ++i)
#pragma unroll
        for (int j = 0; j < 2; ++j) {
            int nn = n0 + wcol + j * 16 + r16;
            if (nn < N) {
#pragma unroll
                for (int r = 0; r < 4; ++r) {
                    float v = accM[i][j][r] + accX[i][j][r] * cs;
                    int mm = m0 + wrow + i * 16 + q * 4 + r;
                    if (has32) {
                        if (nn < Nsplit) O0[(size_t)mm * ld0 + nn] = v;
                        else             O1[(size_t)mm * ld1 + (nn - Nsplit)] = v;
                    }
                    if (haspair) {
                        f16 h, l; split16(v, h, l);
                        if (flipcomb) {
                            int bb = mm >> 10, tt_ = mm & 1023;
                            size_t drow = dir == 0 ? (size_t)mm : (size_t)((bb << 10) + (1023 - tt_));
                            size_t dcol = dir == 0 ? (size_t)nn : (size_t)(nn + 256);
                            Ph[drow * 512 + dcol] = h;
                            Pl[drow * 512 + dcol] = l;
                        } else {
                            Ph[(size_t)mm * ldP + nn] = h;
                            Pl[(size_t)mm * ldP + nn] = l;
                        }
                    }
                }
            }
        }
}

// ---------------------------------------------------------------- depthwise causal conv(4) + SiLU + softplus(dt)
__global__ __launch_bounds__(256) void conv_dt_kernel(
    const float* __restrict__ xbc, float* __restrict__ xc, float* __restrict__ dts,
    const float* __restrict__ cw, const float* __restrict__ cb,
    const float* __restrict__ dtb, int layer) {
    int row = blockIdx.x;
    int dir = blockIdx.y;
    int b = row >> 10, t = row & 1023;
    const float* xd = xbc + (size_t)dir * ROWS * XBCW;
    int pi = dir * 2 + layer;
    const float* cwl = cw + (size_t)pi * CONVDIM * 4;
    const float* cbl = cb + (size_t)pi * CONVDIM;
    const float* dtbl = dtb + pi * NHEADS;
    for (int c = threadIdx.x; c < CONVDIM + NHEADS; c += 256) {
        if (c < CONVDIM) {
            float acc = cbl[c];
#pragma unroll
            for (int k = 0; k < 4; ++k) {
                int tt = t - 3 + k;
                if (tt >= 0)
                    acc = fmaf(xd[(size_t)((b << 10) + tt) * XBCW + c], cwl[c * 4 + k], acc);
            }
            xc[((size_t)dir * ROWS + row) * CONVDIM + c] = siluf_(acc);
        } else {
            int hh = c - CONVDIM;
            dts[((size_t)dir * ROWS + row) * NHEADS + hh] =
                softplusf_(xd[(size_t)row * XBCW + CONVDIM + hh] + dtbl[hh]);
        }
    }
}

// ---------------------------------------------------------------- S1: MFMA-SSD chunk scan. One wave per (unit,chunk).
// Y_loc[t,p] = lc[t] * Sum_s mask(s<=t) G[t,s]*(dt_s/lc[s]) * x[s,p]  (G = C.B^T)
// h_end[p,n] = Sum_s (lc_last/lc[s])*dt_s * x[s,p]*B[s,n]
__global__ __launch_bounds__(64) void scan_chunk_kernel(
    const float* __restrict__ xc, const float* __restrict__ dts,
    float* __restrict__ y, const float* __restrict__ Alog, const float* __restrict__ Dp,
    float* __restrict__ HA, float* __restrict__ HB, float* __restrict__ cumb, int layer) {
    __shared__ f16 Chs[32 * 72], Cls[32 * 72], Bhs[32 * 72], Bls[32 * 72];   // C,B row-major (t/s, n)
    __shared__ f16 Xth[64 * 40], Xtl[64 * 40];                                // X^T (p, s)
    __shared__ f16 Bvh[64 * 40], Bvl[64 * 40];                                // (B*v*4096)^T (n, s)
    __shared__ f16 Gph[32 * 40], Gpl[32 * 40];                                // G' (t, s)
    __shared__ float sLC[32], sRD[32], sV[32];

    int blk = blockIdx.x;
    int u = blk >> 5, c = blk & 31;
    int dir = u >> 4, b = (u >> 3) & 1, h = u & 7;
    int p = threadIdx.x;
    int pi = dir * 2 + layer;
    float Av = -expf(Alog[pi * NHEADS + h]);
    float Dv = Dp[pi * NHEADS + h];
    const float* xcd = xc + (size_t)dir * ROWS * CONVDIM;
    const float* dtd = dts + (size_t)dir * ROWS * NHEADS;
    float* yd = y + (size_t)dir * ROWS * DINNER;
    int t0 = c * LC, base = b << 10;
    const float cs = 1.0f / 4096.0f;

    // per-step scalars: dt, dA, chunk-local prefix product lc
    int tp = p & 31;
    float dt_l = dtd[(size_t)(base + t0 + tp) * NHEADS + h];
    float dA_l = expf(dt_l * Av);
    float cum_l = dA_l;
#pragma unroll
    for (int off = 1; off < 32; off <<= 1) {
        float o = __shfl_up(cum_l, off);
        if (tp >= off) cum_l *= o;
    }
    float lclast = __shfl(cum_l, 31);
    if (p < 32) {
        cumb[(u << 10) + t0 + p] = cum_l;
        float rl = 1.0f / cum_l;
        sLC[p] = cum_l;
        sRD[p] = rl * dt_l;                    // dt_s / lc[s]
        sV[p]  = lclast * rl * dt_l * 4096.0f; // carry weight, pre-scaled
    }
    __syncthreads();

    // stage B (xc cols 512..575) + C (576..639), row-major pairs; Bv transposed-scaled
#pragma unroll
    for (int j = 0; j < 16; ++j) {
        int idx = j * 64 + p;
        int tr = idx >> 5, c4 = idx & 31;
        float4 v = *(const float4*)&xcd[(size_t)(base + t0 + tr) * CONVDIM + DINNER + c4 * 4];
        float vs = sV[tr];
        float e[4] = {v.x, v.y, v.z, v.w};
        f16 hq[4], lq[4];
#pragma unroll
        for (int k = 0; k < 4; ++k) split16(e[k], hq[k], lq[k]);
        int col0 = c4 * 4;
        if (col0 < 64) {
            *(v4h*)&Bhs[tr * 72 + col0] = *(v4h*)hq;
            *(v4h*)&Bls[tr * 72 + col0] = *(v4h*)lq;
#pragma unroll
            for (int k = 0; k < 4; ++k) {
                f16 h2, l2; split16(e[k] * vs, h2, l2);
                Bvh[(col0 + k) * 40 + tr] = h2;
                Bvl[(col0 + k) * 40 + tr] = l2;
            }
        } else {
            *(v4h*)&Chs[tr * 72 + col0 - 64] = *(v4h*)hq;
            *(v4h*)&Cls[tr * 72 + col0 - 64] = *(v4h*)lq;
        }
    }
    // stage X^T (head slice)
#pragma unroll
    for (int j = 0; j < 8; ++j) {
        int idx = j * 64 + p;
        int sr = idx >> 4, c4 = idx & 15;
        float4 v = *(const float4*)&xcd[(size_t)(base + t0 + sr) * CONVDIM + h * HEADDIM + c4 * 4];
        float e[4] = {v.x, v.y, v.z, v.w};
#pragma unroll
        for (int k = 0; k < 4; ++k) {
            f16 hh, ll; split16(e[k], hh, ll);
            Xth[(c4 * 4 + k) * 40 + sr] = hh;
            Xtl[(c4 * 4 + k) * 40 + sr] = ll;
        }
    }
    __syncthreads();

    int q = p >> 4, r16 = p & 15;

    // ---- G = C.B^T (32x32, k=64), mask+scale -> G' in LDS
    {
        v4f gM[2][2], gX[2][2];
#pragma unroll
        for (int i = 0; i < 2; ++i)
#pragma unroll
            for (int j = 0; j < 2; ++j) { gM[i][j] = (v4f)0.0f; gX[i][j] = (v4f)0.0f; }
#pragma unroll
        for (int ks = 0; ks < 64; ks += 32) {
            v8h ca[2], cl2[2], ba[2], bl2[2];
#pragma unroll
            for (int i = 0; i < 2; ++i) {
                int ra = (i * 16 + r16) * 72 + ks + q * 8;
                ca[i]  = *(const v8h*)&Chs[ra];
                cl2[i] = *(const v8h*)&Cls[ra];
                ba[i]  = *(const v8h*)&Bhs[ra];
                bl2[i] = *(const v8h*)&Bls[ra];
            }
#pragma unroll
            for (int i = 0; i < 2; ++i)
#pragma unroll
                for (int j = 0; j < 2; ++j) {
                    gM[i][j] = MFMA16(ca[i], ba[j], gM[i][j]);
                    gX[i][j] = MFMA16(ca[i], bl2[j], gX[i][j]);
                    gX[i][j] = MFMA16(cl2[i], ba[j], gX[i][j]);
                }
        }
#pragma unroll
        for (int ti = 0; ti < 2; ++ti)
#pragma unroll
            for (int si = 0; si < 2; ++si)
#pragma unroll
                for (int r = 0; r < 4; ++r) {
                    int t = ti * 16 + q * 4 + r;
                    int s = si * 16 + r16;
                    float g = gM[ti][si][r] + gX[ti][si][r] * cs;
                    float w = (s <= t) ? sLC[t] * sRD[s] * 4096.0f : 0.0f;
                    f16 hh, ll; split16(g * w, hh, ll);
                    Gph[t * 40 + s] = hh;
                    Gpl[t * 40 + s] = ll;
                }
    }
    __syncthreads();

    // ---- Y = G'.X /4096 + Dv*x  (32t x 64p, k=32)
#pragma unroll
    for (int ti = 0; ti < 2; ++ti) {
        int ra = (ti * 16 + r16) * 40 + q * 8;
        v8h ga = *(const v8h*)&Gph[ra];
        v8h gl = *(const v8h*)&Gpl[ra];
#pragma unroll
        for (int pj = 0; pj < 4; ++pj) {
            int rb = (pj * 16 + r16) * 40 + q * 8;
            v8h xa = *(const v8h*)&Xth[rb];
            v8h xl = *(const v8h*)&Xtl[rb];
            v4f m = (v4f)0.0f, x2 = (v4f)0.0f;
            m  = MFMA16(ga, xa, m);
            x2 = MFMA16(ga, xl, x2);
            x2 = MFMA16(gl, xa, x2);
#pragma unroll
            for (int r = 0; r < 4; ++r) {
                int t = ti * 16 + q * 4 + r;
                int pp = pj * 16 + r16;
                float xv = (float)Xth[pp * 40 + t] + cs * (float)Xtl[pp * 40 + t];
                float val = (m[r] + x2[r] * cs) * cs + Dv * xv;
                yd[(size_t)(base + t0 + t) * DINNER + h * HEADDIM + pp] = val;
            }
        }
    }

    // ---- h_end^T = Bv.X /4096 -> H[p*64+n]  (64n x 64p, k=32)
    float* Hb = hrow_(HA, HB, c) + (size_t)u * 4096;
#pragma unroll
    for (int ni = 0; ni < 4; ++ni) {
        int ra = (ni * 16 + r16) * 40 + q * 8;
        v8h ba = *(const v8h*)&Bvh[ra];
        v8h bl2 = *(const v8h*)&Bvl[ra];
#pragma unroll
        for (int pj = 0; pj < 4; ++pj) {
            int rb = (pj * 16 + r16) * 40 + q * 8;
            v8h xa = *(const v8h*)&Xth[rb];
            v8h xl = *(const v8h*)&Xtl[rb];
            v4f m = (v4f)0.0f, x2 = (v4f)0.0f;
            m  = MFMA16(ba, xa, m);
            x2 = MFMA16(ba, xl, x2);
            x2 = MFMA16(bl2, xa, x2);
#pragma unroll
            for (int r = 0; r < 4; ++r) {
                int n = ni * 16 + q * 4 + r;
                int pp = pj * 16 + r16;
                Hb[pp * 64 + n] = (m[r] + x2[r] * cs) * cs;
            }
        }
    }
}

// ---------------------------------------------------------------- S2: carry chain over chunks (in place)
__global__ __launch_bounds__(256) void carry_kernel(
    float* __restrict__ HA, float* __restrict__ HB, const float* __restrict__ cumb) {
    int u = blockIdx.x;
    int tid = threadIdx.x;
    float carry[16];
#pragma unroll
    for (int j = 0; j < 16; ++j) carry[j] = 0.f;
    for (int c = 0; c < NC; ++c) {
        float Pc = cumb[(u << 10) + c * LC + (LC - 1)];
        float* Hb = hrow_(HA, HB, c) + (size_t)u * 4096 + tid * 16;
#pragma unroll
        for (int j = 0; j < 4; ++j) {
            float4 e = *(const float4*)&Hb[j * 4];
            *(float4*)&Hb[j * 4] = make_float4(carry[j*4], carry[j*4+1], carry[j*4+2], carry[j*4+3]);
            carry[j*4]     = fmaf(Pc, carry[j*4],     e.x);
            carry[j*4 + 1] = fmaf(Pc, carry[j*4 + 1], e.y);
            carry[j*4 + 2] = fmaf(Pc, carry[j*4 + 2], e.z);
            carry[j*4 + 3] = fmaf(Pc, carry[j*4 + 3], e.w);
        }
    }
}

// ---------------------------------------------------------------- S3: y[t] += cum[t] * (C_t . h_in)
__global__ __launch_bounds__(64) void fix_kernel(
    const float* __restrict__ xc, float* __restrict__ y,
    const float* __restrict__ HA, const float* __restrict__ HB,
    const float* __restrict__ cumb) {
    __shared__ float sC[LC * 64];
    int blk = blockIdx.x;
    int u = blk / (NC - 1);
    int c = blk % (NC - 1) + 1;
    int dir = u >> 4, b = (u >> 3) & 1, h = u & 7;
    int p = threadIdx.x;
    const float* xcd = xc + (size_t)dir * ROWS * CONVDIM;
    float* yd = y + (size_t)dir * ROWS * DINNER;
    int t0 = c * LC, base = b << 10;
    float cum_l = cumb[(u << 10) + t0 + (p & (LC - 1))];
#pragma unroll
    for (int j = 0; j < 8; ++j) {
        int f4 = j * 64 + p;
        int trow = f4 >> 4, col4 = f4 & 15;
        float4 v = *(const float4*)&xcd[(size_t)(base + t0 + trow) * CONVDIM + DINNER + DSTATE + col4 * 4];
        *(float4*)&sC[trow * 64 + col4 * 4] = v;
    }
    const float* Hb = hrow_c(HA, HB, c) + (size_t)u * 4096 + p * 64;
    float hin[DSTATE];
#pragma unroll
    for (int n = 0; n < DSTATE; n += 4) {
        float4 v = *(const float4*)&Hb[n];
        hin[n] = v.x; hin[n + 1] = v.y; hin[n + 2] = v.z; hin[n + 3] = v.w;
    }
    __syncthreads();
#pragma unroll 2
    for (int tt = 0; tt < LC; ++tt) {
        float cumt = __shfl(cum_l, tt);
        const float* Cs = &sC[tt * 64];
        float y0 = 0.f, y1 = 0.f, y2 = 0.f, y3 = 0.f;
#pragma unroll
        for (int n = 0; n < DSTATE; n += 4) {
            y0 = fmaf(hin[n],     Cs[n],     y0);
            y1 = fmaf(hin[n + 1], Cs[n + 1], y1);
            y2 = fmaf(hin[n + 2], Cs[n + 2], y2);
            y3 = fmaf(hin[n + 3], Cs[n + 3], y3);
        }
        size_t yi = (size_t)(base + t0 + tt) * DINNER + h * HEADDIM + p;
        yd[yi] += cumt * ((y0 + y1) + (y2 + y3));
    }
}

// ---------------------------------------------------------------- y*silu(z), RMSNorm*nw -> f16 pairs
__global__ __launch_bounds__(256) void gate_rms_kernel(
    const float* __restrict__ y, const float* __restrict__ zbuf,
    const float* __restrict__ nw, f16* __restrict__ yh, f16* __restrict__ yl, int layer) {
    int row = blockIdx.x;
    int dir = blockIdx.y;
    const float* zrow = zbuf + ((size_t)dir * ROWS + row) * DINNER;
    const float* yrow = y + ((size_t)dir * ROWS + row) * DINNER;
    f16* yhr = yh + ((size_t)dir * ROWS + row) * DINNER;
    f16* ylr = yl + ((size_t)dir * ROWS + row) * DINNER;
    const float* nwl = nw + (dir * 2 + layer) * DINNER;
    int tid = threadIdx.x;
    int i0 = tid, i1 = tid + 256;
    float g0 = yrow[i0] * siluf_(zrow[i0]);
    float g1 = yrow[i1] * siluf_(zrow[i1]);
    __shared__ float red[256];
    red[tid] = fmaf(g0, g0, g1 * g1);
    __syncthreads();
    for (int s = 128; s > 0; s >>= 1) {
        if (tid < s) red[tid] += red[tid + s];
        __syncthreads();
    }
    float scale = 1.0f / sqrtf(red[0] / (float)DINNER + EPSF);
    float v0 = g0 * scale * nwl[i0];
    float v1 = g1 * scale * nwl[i1];
    f16 h, l;
    split16(v0, h, l); yhr[i0] = h; ylr[i0] = l;
    split16(v1, h, l); yhr[i1] = h; ylr[i1] = l;
}

// ---------------------------------------------------------------- fusion gates + LayerNorm
__global__ __launch_bounds__(256) void fusion_ln2_kernel(
    const float* __restrict__ u32, const float* __restrict__ gate,
    const float* __restrict__ fb, const float* __restrict__ lnw,
    const float* __restrict__ lnb, float* __restrict__ out) {
    int row = blockIdx.x;
    int b = row >> 10, t = row & 1023;
    int tid = threadIdx.x;
    float f  = u32[(size_t)row * DMODEL + tid];
    float bw = u32[(size_t)ROWS * DMODEL + ((size_t)(b << 10) + (1023 - t)) * DMODEL + tid];
    float g0 = sigmoidf_(gate[(size_t)row * 512 + tid] + fb[tid]);
    float g1 = sigmoidf_(gate[(size_t)row * 512 + 256 + tid] + fb[256 + tid]);
    float fused = g0 * f + g1 * bw;
    __shared__ float red[256];
    red[tid] = fused;
    __syncthreads();
    for (int s = 128; s > 0; s >>= 1) {
        if (tid < s) red[tid] += red[tid + s];
        __syncthreads();
    }
    float mu = red[0] / (float)DMODEL;
    __syncthreads();
    float d = fused - mu;
    red[tid] = d * d;
    __syncthreads();
    for (int s = 128; s > 0; s >>= 1) {
        if (tid < s) red[tid] += red[tid + s];
        __syncthreads();
    }
    float var = red[0] / (float)DMODEL;
    out[(size_t)row * DMODEL + tid] = d * (1.0f / sqrtf(var + EPSF)) * lnw[tid] + lnb[tid];
}

// ---------------------------------------------------------------- launch
extern "C" void kernel_launch(void* const* d_in, const int* in_sizes, int n_in,
                              void* d_out, int out_size, void* d_ws, size_t ws_size,
                              hipStream_t stream) {
    const int*   ids  = (const int*)d_in[0];
    const float* mask = (const float*)d_in[1];
    const float* tok  = (const float*)d_in[2];
    const float* pos  = (const float*)d_in[3];
    const float* inw  = (const float*)d_in[4];
    const float* cw   = (const float*)d_in[5];
    const float* cb   = (const float*)d_in[6];
    const float* dtb  = (const float*)d_in[7];
    const float* alog = (const float*)d_in[8];
    const float* dpar = (const float*)d_in[9];
    const float* nw   = (const float*)d_in[10];
    const float* ow   = (const float*)d_in[11];
    const float* fw   = (const float*)d_in[12];
    const float* fb   = (const float*)d_in[13];
    const float* lnw  = (const float*)d_in[14];
    const float* lnb  = (const float*)d_in[15];

    float* ws = (float*)d_ws;
    float* zbuf = ws;                      // 2,097,152 f
    float* xbc  = ws + 2097152;            // 2,654,208 f (in_proj xBC+dtraw; later H rows 0..19)
    float* xc   = ws + 4751360;            // 2,621,440 f (conv out; later yh/yl pairs, then gate)
    float* dts  = ws + 7372800;            //    32,768 f
    float* ybuf = ws + 7405568;            // 2,097,152 f (scan y; later u_fp32 + comb pairs)
    f16*   uh   = (f16*)(ws + 9502720);    // 1,048,576 h
    f16*   ul   = (f16*)(ws + 10027008);   // 1,048,576 h
    f16*   wb   = (f16*)(ws + 10551296);   // 2,236,416 h
    float* tailH= ws + 11669504;           // 1,572,864 f (H rows 20..31)
    float* cumb = ws + 13242368;           //    32,768 f
    float* HA   = xbc;
    float* HB   = tailH;
    f16*   yh   = (f16*)xc;
    f16*   yl   = (f16*)(xc + 1048576);
    float* gate = xc;
    float* u32  = ybuf;
    f16*   combh = (f16*)(ybuf + 1048576);
    f16*   combl = (f16*)(ybuf + 1572864);
    f16* wih = wb;               f16* wil = wb + WIN;
    f16* woh = wb + 2 * WIN;     f16* wol = wb + 2 * WIN + WOUT;
    f16* wfh = wb + 2 * WIN + 2 * WOUT;
    f16* wfl = wfh + WF;

    embed_kernel<<<ROWS, DMODEL, 0, stream>>>(ids, mask, tok, pos, uh, ul);

    for (int layer = 0; layer < 2; ++layer) {
        int wtot = WIN + WOUT + (layer == 1 ? WF : 0);
        wconv_kernel<<<(wtot + 1023) / 1024, 256, 0, stream>>>(inw, ow, fw, wb, layer, wtot);

        dim3 g1(ROWS / 64, (DINPROJ + 63) / 64, 2);
        gemm_f16x3<<<g1, 256, 0, stream>>>(
            uh, ul, (long)ROWS * DMODEL,
            wih, wil, (long)PSI,
            DINPROJ, DMODEL, DINNER,
            zbuf, DINNER, (long)ROWS * DINNER,
            xbc, XBCW, (long)ROWS * XBCW,
            (f16*)nullptr, (f16*)nullptr, 0, 0L,
            1, 0, 0);

        conv_dt_kernel<<<dim3(ROWS, 2), 256, 0, stream>>>(xbc, xc, dts, cw, cb, dtb, layer);
        scan_chunk_kernel<<<32 * NC, 64, 0, stream>>>(xc, dts, ybuf, alog, dpar, HA, HB, cumb, layer);
        carry_kernel<<<32, 256, 0, stream>>>(HA, HB, cumb);
        fix_kernel<<<32 * (NC - 1), 64, 0, stream>>>(xc, ybuf, HA, HB, cumb);
        gate_rms_kernel<<<dim3(ROWS, 2), 256, 0, stream>>>(ybuf, zbuf, nw, yh, yl, layer);

        dim3 g2(ROWS / 64, DMODEL / 64, 2);
        if (layer == 0) {
            gemm_f16x3<<<g2, 256, 0, stream>>>(
                yh, yl, (long)ROWS * DINNER,
                woh, wol, (long)PSO,
                DMODEL, DINNER, DMODEL,
                u32, DMODEL, (long)ROWS * DMODEL,
                u32, DMODEL, (long)ROWS * DMODEL,
                uh, ul, DMODEL, (long)ROWS * DMODEL,
                1, 1, 0);
        } else {
            gemm_f16x3<<<g2, 256, 0, stream>>>(
                yh, yl, (long)ROWS * DINNER,
                woh, wol, (long)PSO,
                DMODEL, DINNER, DMODEL,
                u32, DMODEL, (long)ROWS * DMODEL,
                u32, DMODEL, (long)ROWS * DMODEL,
                combh, combl, 512, 0L,
                1, 1, 1);
        }
    }

    dim3 g3(ROWS / 64, 512 / 64, 1);
    gemm_f16x3<<<g3, 256, 0, stream>>>(
        combh, combl, 0L,
        wfh, wfl, 0L,
        512, 512, 512,
        gate, 512, 0L,
        gate, 512, 0L,
        (f16*)nullptr, (f16*)nullptr, 0, 0L,
        1, 0, 0);

    fusion_ln2_kernel<<<ROWS, 256, 0, stream>>>(u32, gate, fb, lnw, lnb, (float*)d_out);
}

// Round 8
// 309.032 us; speedup vs baseline: 1.3677x; 1.3242x over previous
//
#include <hip/hip_runtime.h>
#include <cstddef>

#define LSEQ    1024
#define DMODEL  256
#define DINNER  512
#define DSTATE  64
#define NHEADS  8
#define HEADDIM 64
#define CONVDIM 640
#define DINPROJ 1160
#define ROWS    2048   // B * L
#define EPSF    1e-5f
#define NC      32     // chunks per sequence
#define LC      32     // chunk length
#define XBCW    648    // xBC (640) + raw dt (8)
#define HROW    131072 // 32 units * 4096 floats per chunk-row (c-major H)

// weight-pair buffer geometry (element counts)
#define WIN  593920
#define WOUT 262144
#define WF   262144
#define PSI  296960
#define PSO  131072

typedef _Float16 f16;
typedef f16   v8h __attribute__((ext_vector_type(8)));
typedef f16   v4h __attribute__((ext_vector_type(4)));
typedef float v4f __attribute__((ext_vector_type(4)));
#define MFMA16(a, b, c) __builtin_amdgcn_mfma_f32_16x16x32_f16(a, b, c, 0, 0, 0)

__device__ __forceinline__ float sigmoidf_(float x) { return 1.0f / (1.0f + expf(-x)); }
__device__ __forceinline__ float siluf_(float x)    { return x / (1.0f + expf(-x)); }
__device__ __forceinline__ float softplusf_(float x) {
    return x > 0.0f ? x + log1pf(expf(-x)) : log1pf(expf(x));
}
__device__ __forceinline__ void split16(float v, f16& h, f16& l) {
    h = (f16)v;
    l = (f16)((v - (float)h) * 4096.0f);
}

// ---------------------------------------------------------------- embedding -> f16 pairs
__global__ __launch_bounds__(256) void embed_kernel(
    const int* __restrict__ ids, const float* __restrict__ mask,
    const float* __restrict__ tok, const float* __restrict__ pos,
    f16* __restrict__ uh, f16* __restrict__ ul) {
    int row = blockIdx.x;
    int d = threadIdx.x;
    int b = row >> 10, t = row & 1023;
    int id = ids[row];
    float v = tok[(size_t)id * DMODEL + d] + pos[(size_t)t * DMODEL + d];
    v *= mask[row];
    f16 h, l; split16(v, h, l);
    size_t fwd = (size_t)row * DMODEL + d;
    size_t bwd = (size_t)ROWS * DMODEL + ((size_t)(b << 10) + (1023 - t)) * DMODEL + d;
    uh[fwd] = h; ul[fwd] = l;
    uh[bwd] = h; ul[bwd] = l;
}

// ---------------------------------------------------------------- weight fp32 -> f16 pairs (per layer)
__global__ __launch_bounds__(256) void wconv_kernel(
    const float* __restrict__ inw, const float* __restrict__ ow, const float* __restrict__ fw,
    f16* __restrict__ wb, int layer, int total) {
    int idx = (blockIdx.x * 256 + threadIdx.x) * 4;
#pragma unroll
    for (int e = idx; e < idx + 4; ++e) {
        if (e >= total) break;
        float v; f16 *dh, *dl; int off;
        if (e < WIN) {
            int d = e / PSI, r = e - d * PSI;
            v = inw[(size_t)(d * 2 + layer) * PSI + r];
            dh = wb; dl = wb + WIN; off = e;
        } else if (e < WIN + WOUT) {
            int e2 = e - WIN;
            int d = e2 / PSO, r = e2 - d * PSO;
            v = ow[(size_t)(d * 2 + layer) * PSO + r];
            dh = wb + 2 * WIN; dl = dh + WOUT; off = e2;
        } else {
            int e3 = e - WIN - WOUT;
            v = fw[e3];
            dh = wb + 2 * WIN + 2 * WOUT; dl = dh + WF; off = e3;
        }
        f16 h, l; split16(v, h, l);
        dh[off] = h; dl[off] = l;
    }
}

// ---------------------------------------------------------------- f16x3 MFMA GEMM (verified)
__global__ __launch_bounds__(256) void gemm_f16x3(
    const f16* __restrict__ Ah, const f16* __restrict__ Al, long sA,
    const f16* __restrict__ Wh, const f16* __restrict__ Wl, long sW,
    int N, int K, int Nsplit,
    float* __restrict__ O0, int ld0, long sO0,
    float* __restrict__ O1, int ld1, long sO1,
    f16* __restrict__ Ph, f16* __restrict__ Pl, int ldP, long sP,
    int has32, int haspair, int flipcomb) {
    int dir = blockIdx.z;
    Ah += (size_t)dir * sA; Al += (size_t)dir * sA;
    Wh += (size_t)dir * sW; Wl += (size_t)dir * sW;
    if (has32)  { O0 += (size_t)dir * sO0; O1 += (size_t)dir * sO1; }
    if (haspair){ Ph += (size_t)dir * sP;  Pl += (size_t)dir * sP; }

    __shared__ f16 sm[4 * 64 * 72];
    f16* As_h = sm;
    f16* As_l = sm + 64 * 72;
    f16* Ws_h = sm + 2 * 64 * 72;
    f16* Ws_l = sm + 3 * 64 * 72;

    int tid = threadIdx.x;
    int m0 = blockIdx.x * 64, n0 = blockIdx.y * 64;
    int srow = tid >> 2, sseg = tid & 3;
    int lane = tid & 63, w = tid >> 6;
    int wrow = (w >> 1) * 32, wcol = (w & 1) * 32;
    int q = lane >> 4, r16 = lane & 15;
    bool wok = (n0 + srow) < N;

    v4f accM[2][2], accX[2][2];
#pragma unroll
    for (int i = 0; i < 2; ++i)
#pragma unroll
        for (int j = 0; j < 2; ++j) { accM[i][j] = (v4f)0.0f; accX[i][j] = (v4f)0.0f; }

    for (int k0 = 0; k0 < K; k0 += 64) {
        size_t aoff = (size_t)(m0 + srow) * K + k0 + sseg * 16;
        float4 ah0 = *(const float4*)&Ah[aoff];
        float4 ah1 = *(const float4*)&Ah[aoff + 8];
        float4 al0 = *(const float4*)&Al[aoff];
        float4 al1 = *(const float4*)&Al[aoff + 8];
        float4 wh0 = make_float4(0.f,0.f,0.f,0.f), wh1 = wh0, wl0 = wh0, wl1 = wh0;
        if (wok) {
            size_t woff = (size_t)(n0 + srow) * K + k0 + sseg * 16;
            wh0 = *(const float4*)&Wh[woff];
            wh1 = *(const float4*)&Wh[woff + 8];
            wl0 = *(const float4*)&Wl[woff];
            wl1 = *(const float4*)&Wl[woff + 8];
        }
        __syncthreads();
        int d = srow * 72 + sseg * 16;
        *(float4*)&As_h[d] = ah0; *(float4*)&As_h[d + 8] = ah1;
        *(float4*)&As_l[d] = al0; *(float4*)&As_l[d + 8] = al1;
        *(float4*)&Ws_h[d] = wh0; *(float4*)&Ws_h[d + 8] = wh1;
        *(float4*)&Ws_l[d] = wl0; *(float4*)&Ws_l[d + 8] = wl1;
        __syncthreads();

#pragma unroll
        for (int ks = 0; ks < 64; ks += 32) {
            v8h fa_h[2], fa_l[2], fb_h[2], fb_l[2];
#pragma unroll
            for (int i = 0; i < 2; ++i) {
                int ra = (wrow + i * 16 + r16) * 72 + ks + q * 8;
                int rb = (wcol + i * 16 + r16) * 72 + ks + q * 8;
                fa_h[i] = *(const v8h*)&As_h[ra];
                fa_l[i] = *(const v8h*)&As_l[ra];
                fb_h[i] = *(const v8h*)&Ws_h[rb];
                fb_l[i] = *(const v8h*)&Ws_l[rb];
            }
#pragma unroll
            for (int i = 0; i < 2; ++i)
#pragma unroll
                for (int j = 0; j < 2; ++j) {
                    accM[i][j] = MFMA16(fa_h[i], fb_h[j], accM[i][j]);
                    accX[i][j] = MFMA16(fa_h[i], fb_l[j], accX[i][j]);
                    accX[i][j] = MFMA16(fa_l[i], fb_h[j], accX[i][j]);
                }
        }
    }

    const float cs = 1.0f / 4096.0f;
#pragma unroll
    for (int i = 0; i < 2; ++i)
#pragma unroll
        for (int j = 0; j < 2; ++j) {
            int nn = n0 + wcol + j * 16 + r16;
            if (nn < N) {
#pragma unroll
                for (int r = 0; r < 4; ++r) {
                    float v = accM[i][j][r] + accX[i][j][r] * cs;
                    int mm = m0 + wrow + i * 16 + q * 4 + r;
                    if (has32) {
                        if (nn < Nsplit) O0[(size_t)mm * ld0 + nn] = v;
                        else             O1[(size_t)mm * ld1 + (nn - Nsplit)] = v;
                    }
                    if (haspair) {
                        f16 h, l; split16(v, h, l);
                        if (flipcomb) {
                            int bb = mm >> 10, tt_ = mm & 1023;
                            size_t drow = dir == 0 ? (size_t)mm : (size_t)((bb << 10) + (1023 - tt_));
                            size_t dcol = dir == 0 ? (size_t)nn : (size_t)(nn + 256);
                            Ph[drow * 512 + dcol] = h;
                            Pl[drow * 512 + dcol] = l;
                        } else {
                            Ph[(size_t)mm * ldP + nn] = h;
                            Pl[(size_t)mm * ldP + nn] = l;
                        }
                    }
                }
            }
        }
}

// ---------------------------------------------------------------- depthwise causal conv(4) + SiLU + softplus(dt)
__global__ __launch_bounds__(256) void conv_dt_kernel(
    const float* __restrict__ xbc, float* __restrict__ xc, float* __restrict__ dts,
    const float* __restrict__ cw, const float* __restrict__ cb,
    const float* __restrict__ dtb, int layer) {
    int row = blockIdx.x;
    int dir = blockIdx.y;
    int b = row >> 10, t = row & 1023;
    const float* xd = xbc + (size_t)dir * ROWS * XBCW;
    int pi = dir * 2 + layer;
    const float* cwl = cw + (size_t)pi * CONVDIM * 4;
    const float* cbl = cb + (size_t)pi * CONVDIM;
    const float* dtbl = dtb + pi * NHEADS;
    for (int c = threadIdx.x; c < CONVDIM + NHEADS; c += 256) {
        if (c < CONVDIM) {
            float acc = cbl[c];
#pragma unroll
            for (int k = 0; k < 4; ++k) {
                int tt = t - 3 + k;
                if (tt >= 0)
                    acc = fmaf(xd[(size_t)((b << 10) + tt) * XBCW + c], cwl[c * 4 + k], acc);
            }
            xc[((size_t)dir * ROWS + row) * CONVDIM + c] = siluf_(acc);
        } else {
            int hh = c - CONVDIM;
            dts[((size_t)dir * ROWS + row) * NHEADS + hh] =
                softplusf_(xd[(size_t)row * XBCW + CONVDIM + hh] + dtbl[hh]);
        }
    }
}

// ---------------------------------------------------------------- S1: MFMA-SSD chunk scan. 256 threads (4 waves) per (unit,chunk).
// Math identical to round-7 version; work re-partitioned across 4 waves.
__global__ __launch_bounds__(256) void scan_chunk_kernel(
    const float* __restrict__ xc, const float* __restrict__ dts,
    float* __restrict__ y, const float* __restrict__ Alog, const float* __restrict__ Dp,
    float* __restrict__ H, float* __restrict__ cumb, int layer) {
    __shared__ f16 Chs[32 * 72], Cls[32 * 72], Bhs[32 * 72], Bls[32 * 72];   // (t/s, n) row-major
    __shared__ f16 Xth[64 * 40], Xtl[64 * 40];                                // X^T (p, s)
    __shared__ f16 Bvh[64 * 40], Bvl[64 * 40];                                // (B*v*4096)^T (n, s)
    __shared__ f16 Gph[32 * 40], Gpl[32 * 40];                                // G' (t, s)
    __shared__ float sLC[32], sRD[32], sV[32];

    int blk = blockIdx.x;
    int u = blk >> 5, c = blk & 31;
    int dir = u >> 4, b = (u >> 3) & 1, h = u & 7;
    int tid = threadIdx.x;
    int w = tid >> 6, lane = tid & 63;
    int pi = dir * 2 + layer;
    float Av = -expf(Alog[pi * NHEADS + h]);
    float Dv = Dp[pi * NHEADS + h];
    const float* xcd = xc + (size_t)dir * ROWS * CONVDIM;
    const float* dtd = dts + (size_t)dir * ROWS * NHEADS;
    float* yd = y + (size_t)dir * ROWS * DINNER;
    int t0 = c * LC, base = b << 10;
    const float cs = 1.0f / 4096.0f;

    // wave 0: per-step scalars (dt, dA, chunk-local prefix product lc)
    if (w == 0) {
        int tp = lane & 31;
        float dt_l = dtd[(size_t)(base + t0 + tp) * NHEADS + h];
        float dA_l = expf(dt_l * Av);
        float cum_l = dA_l;
#pragma unroll
        for (int off = 1; off < 32; off <<= 1) {
            float o = __shfl_up(cum_l, off);
            if (tp >= off) cum_l *= o;
        }
        float lclast = __shfl(cum_l, 31);
        if (lane < 32) {
            cumb[(u << 10) + t0 + lane] = cum_l;
            float rl = 1.0f / cum_l;
            sLC[lane] = cum_l;
            sRD[lane] = rl * dt_l;
            sV[lane]  = lclast * rl * dt_l * 4096.0f;
        }
    }
    __syncthreads();

    // stage B (cols 512..575) + C (576..639); Bv transposed-scaled. 1024 float4 tasks.
#pragma unroll
    for (int j = 0; j < 4; ++j) {
        int idx = j * 256 + tid;
        int tr = idx >> 5, c4 = idx & 31;
        float4 v = *(const float4*)&xcd[(size_t)(base + t0 + tr) * CONVDIM + DINNER + c4 * 4];
        float vs = sV[tr];
        float e[4] = {v.x, v.y, v.z, v.w};
        f16 hq[4], lq[4];
#pragma unroll
        for (int k = 0; k < 4; ++k) split16(e[k], hq[k], lq[k]);
        int col0 = c4 * 4;
        if (col0 < 64) {
            *(v4h*)&Bhs[tr * 72 + col0] = *(v4h*)hq;
            *(v4h*)&Bls[tr * 72 + col0] = *(v4h*)lq;
#pragma unroll
            for (int k = 0; k < 4; ++k) {
                f16 h2, l2; split16(e[k] * vs, h2, l2);
                Bvh[(col0 + k) * 40 + tr] = h2;
                Bvl[(col0 + k) * 40 + tr] = l2;
            }
        } else {
            *(v4h*)&Chs[tr * 72 + col0 - 64] = *(v4h*)hq;
            *(v4h*)&Cls[tr * 72 + col0 - 64] = *(v4h*)lq;
        }
    }
    // stage X^T (head slice). 512 float4 tasks.
#pragma unroll
    for (int j = 0; j < 2; ++j) {
        int idx = j * 256 + tid;
        int sr = idx >> 4, c4 = idx & 15;
        float4 v = *(const float4*)&xcd[(size_t)(base + t0 + sr) * CONVDIM + h * HEADDIM + c4 * 4];
        float e[4] = {v.x, v.y, v.z, v.w};
#pragma unroll
        for (int k = 0; k < 4; ++k) {
            f16 hh, ll; split16(e[k], hh, ll);
            Xth[(c4 * 4 + k) * 40 + sr] = hh;
            Xtl[(c4 * 4 + k) * 40 + sr] = ll;
        }
    }
    __syncthreads();

    int q = lane >> 4, r16 = lane & 15;

    // ---- G = C.B^T (32x32, k=64): wave w computes tile (ti=w>>1, si=w&1)
    {
        int ti = w >> 1, si = w & 1;
        v4f gM = (v4f)0.0f, gX = (v4f)0.0f;
#pragma unroll
        for (int ks = 0; ks < 64; ks += 32) {
            int ra = (ti * 16 + r16) * 72 + ks + q * 8;
            int rb = (si * 16 + r16) * 72 + ks + q * 8;
            v8h ca  = *(const v8h*)&Chs[ra];
            v8h cl2 = *(const v8h*)&Cls[ra];
            v8h ba  = *(const v8h*)&Bhs[rb];
            v8h bl2 = *(const v8h*)&Bls[rb];
            gM = MFMA16(ca, ba, gM);
            gX = MFMA16(ca, bl2, gX);
            gX = MFMA16(cl2, ba, gX);
        }
#pragma unroll
        for (int r = 0; r < 4; ++r) {
            int t = ti * 16 + q * 4 + r;
            int s = si * 16 + r16;
            float g = gM[r] + gX[r] * cs;
            float wgt = (s <= t) ? sLC[t] * sRD[s] * 4096.0f : 0.0f;
            f16 hh, ll; split16(g * wgt, hh, ll);
            Gph[t * 40 + s] = hh;
            Gpl[t * 40 + s] = ll;
        }
    }
    __syncthreads();

    // ---- Y = G'.X /4096 + Dv*x: wave w does ti = w>>1, pj in {(w&1)*2, (w&1)*2+1}
    {
        int ti = w >> 1;
        int ra = (ti * 16 + r16) * 40 + q * 8;
        v8h ga = *(const v8h*)&Gph[ra];
        v8h gl = *(const v8h*)&Gpl[ra];
#pragma unroll
        for (int jj = 0; jj < 2; ++jj) {
            int pj = (w & 1) * 2 + jj;
            int rb = (pj * 16 + r16) * 40 + q * 8;
            v8h xa = *(const v8h*)&Xth[rb];
            v8h xl = *(const v8h*)&Xtl[rb];
            v4f m = (v4f)0.0f, x2 = (v4f)0.0f;
            m  = MFMA16(ga, xa, m);
            x2 = MFMA16(ga, xl, x2);
            x2 = MFMA16(gl, xa, x2);
#pragma unroll
            for (int r = 0; r < 4; ++r) {
                int t = ti * 16 + q * 4 + r;
                int pp = pj * 16 + r16;
                float xv = (float)Xth[pp * 40 + t] + cs * (float)Xtl[pp * 40 + t];
                float val = (m[r] + x2[r] * cs) * cs + Dv * xv;
                yd[(size_t)(base + t0 + t) * DINNER + h * HEADDIM + pp] = val;
            }
        }
    }

    // ---- h_end^T = Bv.X /4096: wave w does ni = w, pj 0..3
    {
        float* Hb = H + (size_t)c * HROW + (size_t)u * 4096;
        int ni = w;
        int ra = (ni * 16 + r16) * 40 + q * 8;
        v8h ba  = *(const v8h*)&Bvh[ra];
        v8h bl2 = *(const v8h*)&Bvl[ra];
#pragma unroll
        for (int pj = 0; pj < 4; ++pj) {
            int rb = (pj * 16 + r16) * 40 + q * 8;
            v8h xa = *(const v8h*)&Xth[rb];
            v8h xl = *(const v8h*)&Xtl[rb];
            v4f m = (v4f)0.0f, x2 = (v4f)0.0f;
            m  = MFMA16(ba, xa, m);
            x2 = MFMA16(ba, xl, x2);
            x2 = MFMA16(bl2, xa, x2);
#pragma unroll
            for (int r = 0; r < 4; ++r) {
                int n = ni * 16 + q * 4 + r;
                int pp = pj * 16 + r16;
                Hb[pp * 64 + n] = (m[r] + x2[r] * cs) * cs;
            }
        }
    }
}

// ---------------------------------------------------------------- S2: carry chain, thread-per-chain (coalesced, in place)
__global__ __launch_bounds__(256) void carry_kernel(
    float* __restrict__ H, const float* __restrict__ cumb) {
    int blk = blockIdx.x;
    int u = blk >> 4;
    int e = ((blk & 15) << 8) + threadIdx.x;   // 0..4095
    size_t off = (size_t)u * 4096 + e;
    float carry = 0.f;
#pragma unroll 4
    for (int c = 0; c < NC; ++c) {
        float Pc = cumb[(u << 10) + c * LC + (LC - 1)];
        float* p = H + (size_t)c * HROW + off;
        float ev = *p;
        *p = carry;
        carry = fmaf(Pc, carry, ev);
    }
}

// ---------------------------------------------------------------- S3: y[t] += cum[t] * (C_t . h_in). 128 threads (2 waves) per (u,c).
__global__ __launch_bounds__(128) void fix_kernel(
    const float* __restrict__ xc, float* __restrict__ y,
    const float* __restrict__ H, const float* __restrict__ cumb) {
    __shared__ float sC[LC * 64];
    __shared__ float sCum[LC];
    int blk = blockIdx.x;
    int u = blk / (NC - 1);
    int c = blk % (NC - 1) + 1;
    int dir = u >> 4, b = (u >> 3) & 1, h = u & 7;
    int tid = threadIdx.x;
    int w = tid >> 6, p = tid & 63;
    const float* xcd = xc + (size_t)dir * ROWS * CONVDIM;
    float* yd = y + (size_t)dir * ROWS * DINNER;
    int t0 = c * LC, base = b << 10;
    if (tid < LC) sCum[tid] = cumb[(u << 10) + t0 + tid];
#pragma unroll
    for (int j = 0; j < 4; ++j) {
        int f4 = j * 128 + tid;
        int trow = f4 >> 4, col4 = f4 & 15;
        float4 v = *(const float4*)&xcd[(size_t)(base + t0 + trow) * CONVDIM + DINNER + DSTATE + col4 * 4];
        *(float4*)&sC[trow * 64 + col4 * 4] = v;
    }
    const float* Hb = H + (size_t)c * HROW + (size_t)u * 4096 + p * 64;
    float hin[DSTATE];
#pragma unroll
    for (int n = 0; n < DSTATE; n += 4) {
        float4 v = *(const float4*)&Hb[n];
        hin[n] = v.x; hin[n + 1] = v.y; hin[n + 2] = v.z; hin[n + 3] = v.w;
    }
    __syncthreads();
#pragma unroll 2
    for (int tt = w * 16; tt < w * 16 + 16; ++tt) {
        float cumt = sCum[tt];
        const float* Cs = &sC[tt * 64];
        float y0 = 0.f, y1 = 0.f, y2 = 0.f, y3 = 0.f;
#pragma unroll
        for (int n = 0; n < DSTATE; n += 4) {
            y0 = fmaf(hin[n],     Cs[n],     y0);
            y1 = fmaf(hin[n + 1], Cs[n + 1], y1);
            y2 = fmaf(hin[n + 2], Cs[n + 2], y2);
            y3 = fmaf(hin[n + 3], Cs[n + 3], y3);
        }
        size_t yi = (size_t)(base + t0 + tt) * DINNER + h * HEADDIM + p;
        yd[yi] += cumt * ((y0 + y1) + (y2 + y3));
    }
}

// ---------------------------------------------------------------- y*silu(z), RMSNorm*nw -> f16 pairs
__global__ __launch_bounds__(256) void gate_rms_kernel(
    const float* __restrict__ y, const float* __restrict__ zbuf,
    const float* __restrict__ nw, f16* __restrict__ yh, f16* __restrict__ yl, int layer) {
    int row = blockIdx.x;
    int dir = blockIdx.y;
    const float* zrow = zbuf + ((size_t)dir * ROWS + row) * DINNER;
    const float* yrow = y + ((size_t)dir * ROWS + row) * DINNER;
    f16* yhr = yh + ((size_t)dir * ROWS + row) * DINNER;
    f16* ylr = yl + ((size_t)dir * ROWS + row) * DINNER;
    const float* nwl = nw + (dir * 2 + layer) * DINNER;
    int tid = threadIdx.x;
    int i0 = tid, i1 = tid + 256;
    float g0 = yrow[i0] * siluf_(zrow[i0]);
    float g1 = yrow[i1] * siluf_(zrow[i1]);
    __shared__ float red[256];
    red[tid] = fmaf(g0, g0, g1 * g1);
    __syncthreads();
    for (int s = 128; s > 0; s >>= 1) {
        if (tid < s) red[tid] += red[tid + s];
        __syncthreads();
    }
    float scale = 1.0f / sqrtf(red[0] / (float)DINNER + EPSF);
    float v0 = g0 * scale * nwl[i0];
    float v1 = g1 * scale * nwl[i1];
    f16 h, l;
    split16(v0, h, l); yhr[i0] = h; ylr[i0] = l;
    split16(v1, h, l); yhr[i1] = h; ylr[i1] = l;
}

// ---------------------------------------------------------------- fusion gates + LayerNorm
__global__ __launch_bounds__(256) void fusion_ln2_kernel(
    const float* __restrict__ u32, const float* __restrict__ gate,
    const float* __restrict__ fb, const float* __restrict__ lnw,
    const float* __restrict__ lnb, float* __restrict__ out) {
    int row = blockIdx.x;
    int b = row >> 10, t = row & 1023;
    int tid = threadIdx.x;
    float f  = u32[(size_t)row * DMODEL + tid];
    float bw = u32[(size_t)ROWS * DMODEL + ((size_t)(b << 10) + (1023 - t)) * DMODEL + tid];
    float g0 = sigmoidf_(gate[(size_t)row * 512 + tid] + fb[tid]);
    float g1 = sigmoidf_(gate[(size_t)row * 512 + 256 + tid] + fb[256 + tid]);
    float fused = g0 * f + g1 * bw;
    __shared__ float red[256];
    red[tid] = fused;
    __syncthreads();
    for (int s = 128; s > 0; s >>= 1) {
        if (tid < s) red[tid] += red[tid + s];
        __syncthreads();
    }
    float mu = red[0] / (float)DMODEL;
    __syncthreads();
    float d = fused - mu;
    red[tid] = d * d;
    __syncthreads();
    for (int s = 128; s > 0; s >>= 1) {
        if (tid < s) red[tid] += red[tid + s];
        __syncthreads();
    }
    float var = red[0] / (float)DMODEL;
    out[(size_t)row * DMODEL + tid] = d * (1.0f / sqrtf(var + EPSF)) * lnw[tid] + lnb[tid];
}

// ---------------------------------------------------------------- launch
extern "C" void kernel_launch(void* const* d_in, const int* in_sizes, int n_in,
                              void* d_out, int out_size, void* d_ws, size_t ws_size,
                              hipStream_t stream) {
    const int*   ids  = (const int*)d_in[0];
    const float* mask = (const float*)d_in[1];
    const float* tok  = (const float*)d_in[2];
    const float* pos  = (const float*)d_in[3];
    const float* inw  = (const float*)d_in[4];
    const float* cw   = (const float*)d_in[5];
    const float* cb   = (const float*)d_in[6];
    const float* dtb  = (const float*)d_in[7];
    const float* alog = (const float*)d_in[8];
    const float* dpar = (const float*)d_in[9];
    const float* nw   = (const float*)d_in[10];
    const float* ow   = (const float*)d_in[11];
    const float* fw   = (const float*)d_in[12];
    const float* fb   = (const float*)d_in[13];
    const float* lnw  = (const float*)d_in[14];
    const float* lnb  = (const float*)d_in[15];

    float* ws = (float*)d_ws;
    float* zbuf = ws;                      // 2,097,152 f
    float* xbc  = ws + 2097152;            // 2,654,208 f
    float* xc   = ws + 4751360;            // 2,621,440 f (conv out; yh/yl + gate overlays)
    float* dts  = ws + 7372800;            //    32,768 f
    float* ybuf = ws + 7405568;            // 2,097,152 f (scan y; u32 + comb overlays)
    f16*   uh   = (f16*)(ws + 9502720);    // 1,048,576 h
    f16*   ul   = (f16*)(ws + 10027008);   // 1,048,576 h
    f16*   wb   = (f16*)(ws + 10551296);   // 2,236,416 h
    float* H    = ws + 11669504;           // 4,194,304 f (flat, c-major)
    float* cumb = ws + 15863808;           //    32,768 f
    f16*   yh   = (f16*)xc;
    f16*   yl   = (f16*)(xc + 1048576);
    float* gate = xc;
    float* u32  = ybuf;
    f16*   combh = (f16*)(ybuf + 1048576);
    f16*   combl = (f16*)(ybuf + 1572864);
    f16* wih = wb;               f16* wil = wb + WIN;
    f16* woh = wb + 2 * WIN;     f16* wol = wb + 2 * WIN + WOUT;
    f16* wfh = wb + 2 * WIN + 2 * WOUT;
    f16* wfl = wfh + WF;

    embed_kernel<<<ROWS, DMODEL, 0, stream>>>(ids, mask, tok, pos, uh, ul);

    for (int layer = 0; layer < 2; ++layer) {
        int wtot = WIN + WOUT + (layer == 1 ? WF : 0);
        wconv_kernel<<<(wtot + 1023) / 1024, 256, 0, stream>>>(inw, ow, fw, wb, layer, wtot);

        dim3 g1(ROWS / 64, (DINPROJ + 63) / 64, 2);
        gemm_f16x3<<<g1, 256, 0, stream>>>(
            uh, ul, (long)ROWS * DMODEL,
            wih, wil, (long)PSI,
            DINPROJ, DMODEL, DINNER,
            zbuf, DINNER, (long)ROWS * DINNER,
            xbc, XBCW, (long)ROWS * XBCW,
            (f16*)nullptr, (f16*)nullptr, 0, 0L,
            1, 0, 0);

        conv_dt_kernel<<<dim3(ROWS, 2), 256, 0, stream>>>(xbc, xc, dts, cw, cb, dtb, layer);
        scan_chunk_kernel<<<32 * NC, 256, 0, stream>>>(xc, dts, ybuf, alog, dpar, H, cumb, layer);
        carry_kernel<<<32 * 16, 256, 0, stream>>>(H, cumb);
        fix_kernel<<<32 * (NC - 1), 128, 0, stream>>>(xc, ybuf, H, cumb);
        gate_rms_kernel<<<dim3(ROWS, 2), 256, 0, stream>>>(ybuf, zbuf, nw, yh, yl, layer);

        dim3 g2(ROWS / 64, DMODEL / 64, 2);
        if (layer == 0) {
            gemm_f16x3<<<g2, 256, 0, stream>>>(
                yh, yl, (long)ROWS * DINNER,
                woh, wol, (long)PSO,
                DMODEL, DINNER, DMODEL,
                u32, DMODEL, (long)ROWS * DMODEL,
                u32, DMODEL, (long)ROWS * DMODEL,
                uh, ul, DMODEL, (long)ROWS * DMODEL,
                1, 1, 0);
        } else {
            gemm_f16x3<<<g2, 256, 0, stream>>>(
                yh, yl, (long)ROWS * DINNER,
                woh, wol, (long)PSO,
                DMODEL, DINNER, DMODEL,
                u32, DMODEL, (long)ROWS * DMODEL,
                u32, DMODEL, (long)ROWS * DMODEL,
                combh, combl, 512, 0L,
                1, 1, 1);
        }
    }

    dim3 g3(ROWS / 64, 512 / 64, 1);
    gemm_f16x3<<<g3, 256, 0, stream>>>(
        combh, combl, 0L,
        wfh, wfl, 0L,
        512, 512, 512,
        gate, 512, 0L,
        gate, 512, 0L,
        (f16*)nullptr, (f16*)nullptr, 0, 0L,
        1, 0, 0);

    fusion_ln2_kernel<<<ROWS, 256, 0, stream>>>(u32, gate, fb, lnw, lnb, (float*)d_out);
}

// Round 9
// 297.206 us; speedup vs baseline: 1.4221x; 1.0398x over previous
//
#include <hip/hip_runtime.h>
#include <cstddef>

#define LSEQ    1024
#define DMODEL  256
#define DINNER  512
#define DSTATE  64
#define NHEADS  8
#define HEADDIM 64
#define CONVDIM 640
#define DINPROJ 1160
#define ROWS    2048   // B * L
#define EPSF    1e-5f
#define NC      32     // chunks per sequence
#define LC      32     // chunk length
#define XBCW    648    // xBC (640) + raw dt (8)
#define HROW    131072 // 32 units * 4096 floats per chunk-row (c-major H)

// weight-pair buffer geometry (element counts)
#define WIN  593920
#define WOUT 262144
#define WF   262144
#define PSI  296960
#define PSO  131072
#define LSTRIDE 1712128   // halves per layer block in wb: 2*(WIN+WOUT)

typedef _Float16 f16;
typedef f16   v8h __attribute__((ext_vector_type(8)));
typedef f16   v4h __attribute__((ext_vector_type(4)));
typedef float v4f __attribute__((ext_vector_type(4)));
#define MFMA16(a, b, c) __builtin_amdgcn_mfma_f32_16x16x32_f16(a, b, c, 0, 0, 0)

__device__ __forceinline__ float sigmoidf_(float x) { return 1.0f / (1.0f + expf(-x)); }
__device__ __forceinline__ float siluf_(float x)    { return x / (1.0f + expf(-x)); }
__device__ __forceinline__ float softplusf_(float x) {
    return x > 0.0f ? x + log1pf(expf(-x)) : log1pf(expf(x));
}
__device__ __forceinline__ void split16(float v, f16& h, f16& l) {
    h = (f16)v;
    l = (f16)((v - (float)h) * 4096.0f);
}

// 4-channel causal conv(4): identical fma order to the old conv_dt kernel (bias, then taps k=0..3)
__device__ __forceinline__ float4 conv4_(const float* __restrict__ xbcd,
                                         const float* __restrict__ cwl,
                                         const float* __restrict__ cbl,
                                         int base, int tg, int ch0) {
    float4 acc = *(const float4*)&cbl[ch0];
    float4 cw0 = *(const float4*)&cwl[(ch0 + 0) * 4];
    float4 cw1 = *(const float4*)&cwl[(ch0 + 1) * 4];
    float4 cw2 = *(const float4*)&cwl[(ch0 + 2) * 4];
    float4 cw3 = *(const float4*)&cwl[(ch0 + 3) * 4];
    const float* w0 = (const float*)&cw0;
    const float* w1 = (const float*)&cw1;
    const float* w2 = (const float*)&cw2;
    const float* w3 = (const float*)&cw3;
#pragma unroll
    for (int k = 0; k < 4; ++k) {
        int ts = tg - 3 + k;
        if (ts >= 0) {
            float4 xv = *(const float4*)&xbcd[(size_t)(base + ts) * XBCW + ch0];
            acc.x = fmaf(xv.x, w0[k], acc.x);
            acc.y = fmaf(xv.y, w1[k], acc.y);
            acc.z = fmaf(xv.z, w2[k], acc.z);
            acc.w = fmaf(xv.w, w3[k], acc.w);
        }
    }
    return acc;
}

// ---------------------------------------------------------------- embedding -> f16 pairs
__global__ __launch_bounds__(256) void embed_kernel(
    const int* __restrict__ ids, const float* __restrict__ mask,
    const float* __restrict__ tok, const float* __restrict__ pos,
    f16* __restrict__ uh, f16* __restrict__ ul) {
    int row = blockIdx.x;
    int d = threadIdx.x;
    int b = row >> 10, t = row & 1023;
    int id = ids[row];
    float v = tok[(size_t)id * DMODEL + d] + pos[(size_t)t * DMODEL + d];
    v *= mask[row];
    f16 h, l; split16(v, h, l);
    size_t fwd = (size_t)row * DMODEL + d;
    size_t bwd = (size_t)ROWS * DMODEL + ((size_t)(b << 10) + (1023 - t)) * DMODEL + d;
    uh[fwd] = h; ul[fwd] = l;
    uh[bwd] = h; ul[bwd] = l;
}

// ---------------------------------------------------------------- ALL weights fp32 -> f16 pairs (single dispatch)
__global__ __launch_bounds__(256) void wconv_kernel(
    const float* __restrict__ inw, const float* __restrict__ ow, const float* __restrict__ fw,
    f16* __restrict__ wb, int total) {
    int idx = (blockIdx.x * 256 + threadIdx.x) * 4;
#pragma unroll
    for (int e = idx; e < idx + 4; ++e) {
        if (e >= total) break;
        float v; f16 *dh, *dl; int off;
        if (e < 2 * (WIN + WOUT)) {
            int layer = e / (WIN + WOUT);
            int r = e - layer * (WIN + WOUT);
            if (r < WIN) {
                int d = r / PSI, rr = r - d * PSI;
                v = inw[(size_t)(d * 2 + layer) * PSI + rr];
                dh = wb + (size_t)layer * LSTRIDE; dl = dh + WIN; off = r;
            } else {
                int r2 = r - WIN;
                int d = r2 / PSO, rr = r2 - d * PSO;
                v = ow[(size_t)(d * 2 + layer) * PSO + rr];
                dh = wb + (size_t)layer * LSTRIDE + 2 * WIN; dl = dh + WOUT; off = r2;
            }
        } else {
            int e3 = e - 2 * (WIN + WOUT);
            v = fw[e3];
            dh = wb + 2 * (size_t)LSTRIDE; dl = dh + WF; off = e3;
        }
        f16 h, l; split16(v, h, l);
        dh[off] = h; dl[off] = l;
    }
}

// ---------------------------------------------------------------- f16x3 MFMA GEMM (verified)
__global__ __launch_bounds__(256) void gemm_f16x3(
    const f16* __restrict__ Ah, const f16* __restrict__ Al, long sA,
    const f16* __restrict__ Wh, const f16* __restrict__ Wl, long sW,
    int N, int K, int Nsplit,
    float* __restrict__ O0, int ld0, long sO0,
    float* __restrict__ O1, int ld1, long sO1,
    f16* __restrict__ Ph, f16* __restrict__ Pl, int ldP, long sP,
    int has32, int haspair, int flipcomb) {
    int dir = blockIdx.z;
    Ah += (size_t)dir * sA; Al += (size_t)dir * sA;
    Wh += (size_t)dir * sW; Wl += (size_t)dir * sW;
    if (has32)  { O0 += (size_t)dir * sO0; O1 += (size_t)dir * sO1; }
    if (haspair){ Ph += (size_t)dir * sP;  Pl += (size_t)dir * sP; }

    __shared__ f16 sm[4 * 64 * 72];
    f16* As_h = sm;
    f16* As_l = sm + 64 * 72;
    f16* Ws_h = sm + 2 * 64 * 72;
    f16* Ws_l = sm + 3 * 64 * 72;

    int tid = threadIdx.x;
    int m0 = blockIdx.x * 64, n0 = blockIdx.y * 64;
    int srow = tid >> 2, sseg = tid & 3;
    int lane = tid & 63, w = tid >> 6;
    int wrow = (w >> 1) * 32, wcol = (w & 1) * 32;
    int q = lane >> 4, r16 = lane & 15;
    bool wok = (n0 + srow) < N;

    v4f accM[2][2], accX[2][2];
#pragma unroll
    for (int i = 0; i < 2; ++i)
#pragma unroll
        for (int j = 0; j < 2; ++j) { accM[i][j] = (v4f)0.0f; accX[i][j] = (v4f)0.0f; }

    for (int k0 = 0; k0 < K; k0 += 64) {
        size_t aoff = (size_t)(m0 + srow) * K + k0 + sseg * 16;
        float4 ah0 = *(const float4*)&Ah[aoff];
        float4 ah1 = *(const float4*)&Ah[aoff + 8];
        float4 al0 = *(const float4*)&Al[aoff];
        float4 al1 = *(const float4*)&Al[aoff + 8];
        float4 wh0 = make_float4(0.f,0.f,0.f,0.f), wh1 = wh0, wl0 = wh0, wl1 = wh0;
        if (wok) {
            size_t woff = (size_t)(n0 + srow) * K + k0 + sseg * 16;
            wh0 = *(const float4*)&Wh[woff];
            wh1 = *(const float4*)&Wh[woff + 8];
            wl0 = *(const float4*)&Wl[woff];
            wl1 = *(const float4*)&Wl[woff + 8];
        }
        __syncthreads();
        int d = srow * 72 + sseg * 16;
        *(float4*)&As_h[d] = ah0; *(float4*)&As_h[d + 8] = ah1;
        *(float4*)&As_l[d] = al0; *(float4*)&As_l[d + 8] = al1;
        *(float4*)&Ws_h[d] = wh0; *(float4*)&Ws_h[d + 8] = wh1;
        *(float4*)&Ws_l[d] = wl0; *(float4*)&Ws_l[d + 8] = wl1;
        __syncthreads();

#pragma unroll
        for (int ks = 0; ks < 64; ks += 32) {
            v8h fa_h[2], fa_l[2], fb_h[2], fb_l[2];
#pragma unroll
            for (int i = 0; i < 2; ++i) {
                int ra = (wrow + i * 16 + r16) * 72 + ks + q * 8;
                int rb = (wcol + i * 16 + r16) * 72 + ks + q * 8;
                fa_h[i] = *(const v8h*)&As_h[ra];
                fa_l[i] = *(const v8h*)&As_l[ra];
                fb_h[i] = *(const v8h*)&Ws_h[rb];
                fb_l[i] = *(const v8h*)&Ws_l[rb];
            }
#pragma unroll
            for (int i = 0; i < 2; ++i)
#pragma unroll
                for (int j = 0; j < 2; ++j) {
                    accM[i][j] = MFMA16(fa_h[i], fb_h[j], accM[i][j]);
                    accX[i][j] = MFMA16(fa_h[i], fb_l[j], accX[i][j]);
                    accX[i][j] = MFMA16(fa_l[i], fb_h[j], accX[i][j]);
                }
        }
    }

    const float cs = 1.0f / 4096.0f;
#pragma unroll
    for (int i = 0; i < 2; ++i)
#pragma unroll
        for (int j = 0; j < 2; ++j) {
            int nn = n0 + wcol + j * 16 + r16;
            if (nn < N) {
#pragma unroll
                for (int r = 0; r < 4; ++r) {
                    float v = accM[i][j][r] + accX[i][j][r] * cs;
                    int mm = m0 + wrow + i * 16 + q * 4 + r;
                    if (has32) {
                        if (nn < Nsplit) O0[(size_t)mm * ld0 + nn] = v;
                        else             O1[(size_t)mm * ld1 + (nn - Nsplit)] = v;
                    }
                    if (haspair) {
                        f16 h, l; split16(v, h, l);
                        if (flipcomb) {
                            int bb = mm >> 10, tt_ = mm & 1023;
                            size_t drow = dir == 0 ? (size_t)mm : (size_t)((bb << 10) + (1023 - tt_));
                            size_t dcol = dir == 0 ? (size_t)nn : (size_t)(nn + 256);
                            Ph[drow * 512 + dcol] = h;
                            Pl[drow * 512 + dcol] = l;
                        } else {
                            Ph[(size_t)mm * ldP + nn] = h;
                            Pl[(size_t)mm * ldP + nn] = l;
                        }
                    }
                }
            }
        }
}

// ---------------------------------------------------------------- S1: MFMA-SSD chunk scan WITH fused conv+silu+softplus.
// 256 threads (4 waves) per (unit,chunk). Math bitwise-identical to round-8 conv_dt+scan.
__global__ __launch_bounds__(256) void scan_chunk_kernel(
    const float* __restrict__ xbc, const float* __restrict__ cw, const float* __restrict__ cb,
    const float* __restrict__ dtb, float* __restrict__ y,
    const float* __restrict__ Alog, const float* __restrict__ Dp,
    float* __restrict__ H, float* __restrict__ cumb, float* __restrict__ Cbuf, int layer) {
    __shared__ f16 Chs[32 * 72], Cls[32 * 72], Bhs[32 * 72], Bls[32 * 72];   // (t/s, n) row-major
    __shared__ f16 Xth[64 * 40], Xtl[64 * 40];                                // X^T (p, s)
    __shared__ f16 Bvh[64 * 40], Bvl[64 * 40];                                // (B*v*4096)^T (n, s)
    __shared__ f16 Gph[32 * 40], Gpl[32 * 40];                                // G' (t, s)
    __shared__ float sLC[32], sRD[32], sV[32];

    int blk = blockIdx.x;
    int u = blk >> 5, c = blk & 31;
    int dir = u >> 4, b = (u >> 3) & 1, h = u & 7;
    int tid = threadIdx.x;
    int w = tid >> 6, lane = tid & 63;
    int pi = dir * 2 + layer;
    float Av = -expf(Alog[pi * NHEADS + h]);
    float Dv = Dp[pi * NHEADS + h];
    const float* xbcd = xbc + (size_t)dir * ROWS * XBCW;
    const float* cwl = cw + (size_t)pi * CONVDIM * 4;
    const float* cbl = cb + (size_t)pi * CONVDIM;
    float dtbh = dtb[pi * NHEADS + h];
    float* yd = y + (size_t)dir * ROWS * DINNER;
    int t0 = c * LC, base = b << 10;
    const float cs = 1.0f / 4096.0f;

    // wave 0: per-step scalars (softplus dt inline, dA, chunk-local prefix product lc)
    if (w == 0) {
        int tp = lane & 31;
        float dtraw = xbcd[(size_t)(base + t0 + tp) * XBCW + CONVDIM + h];
        float dt_l = softplusf_(dtraw + dtbh);
        float dA_l = expf(dt_l * Av);
        float cum_l = dA_l;
#pragma unroll
        for (int off = 1; off < 32; off <<= 1) {
            float o = __shfl_up(cum_l, off);
            if (tp >= off) cum_l *= o;
        }
        float lclast = __shfl(cum_l, 31);
        if (lane < 32) {
            cumb[(u << 10) + t0 + lane] = cum_l;
            float rl = 1.0f / cum_l;
            sLC[lane] = cum_l;
            sRD[lane] = rl * dt_l;
            sV[lane]  = lclast * rl * dt_l * 4096.0f;
        }
    }
    __syncthreads();

    // stage B (ch 512..575) + C (576..639) with fused conv+silu. 1024 float4 tasks.
#pragma unroll
    for (int j = 0; j < 4; ++j) {
        int idx = j * 256 + tid;
        int tr = idx >> 5, c4 = idx & 31;
        int ch0 = 512 + c4 * 4;
        float4 a = conv4_(xbcd, cwl, cbl, base, t0 + tr, ch0);
        float e[4] = {siluf_(a.x), siluf_(a.y), siluf_(a.z), siluf_(a.w)};
        float vs = sV[tr];
        f16 hq[4], lq[4];
#pragma unroll
        for (int k = 0; k < 4; ++k) split16(e[k], hq[k], lq[k]);
        int col0 = c4 * 4;
        if (col0 < 64) {
            *(v4h*)&Bhs[tr * 72 + col0] = *(v4h*)hq;
            *(v4h*)&Bls[tr * 72 + col0] = *(v4h*)lq;
#pragma unroll
            for (int k = 0; k < 4; ++k) {
                f16 h2, l2; split16(e[k] * vs, h2, l2);
                Bvh[(col0 + k) * 40 + tr] = h2;
                Bvl[(col0 + k) * 40 + tr] = l2;
            }
        } else {
            *(v4h*)&Chs[tr * 72 + col0 - 64] = *(v4h*)hq;
            *(v4h*)&Cls[tr * 72 + col0 - 64] = *(v4h*)lq;
            if (h == 0)   // one writer per row: compact conv'd C for fix_kernel
                *(float4*)&Cbuf[((size_t)dir * ROWS + base + t0 + tr) * 64 + (col0 - 64)] =
                    make_float4(e[0], e[1], e[2], e[3]);
        }
    }
    // stage X^T (head slice) with fused conv+silu. 512 float4 tasks.
#pragma unroll
    for (int j = 0; j < 2; ++j) {
        int idx = j * 256 + tid;
        int sr = idx >> 4, c4 = idx & 15;
        int ch0 = h * HEADDIM + c4 * 4;
        float4 a = conv4_(xbcd, cwl, cbl, base, t0 + sr, ch0);
        float e[4] = {siluf_(a.x), siluf_(a.y), siluf_(a.z), siluf_(a.w)};
#pragma unroll
        for (int k = 0; k < 4; ++k) {
            f16 hh, ll; split16(e[k], hh, ll);
            Xth[(c4 * 4 + k) * 40 + sr] = hh;
            Xtl[(c4 * 4 + k) * 40 + sr] = ll;
        }
    }
    __syncthreads();

    int q = lane >> 4, r16 = lane & 15;

    // ---- G = C.B^T (32x32, k=64): wave w computes tile (ti=w>>1, si=w&1)
    {
        int ti = w >> 1, si = w & 1;
        v4f gM = (v4f)0.0f, gX = (v4f)0.0f;
#pragma unroll
        for (int ks = 0; ks < 64; ks += 32) {
            int ra = (ti * 16 + r16) * 72 + ks + q * 8;
            int rb = (si * 16 + r16) * 72 + ks + q * 8;
            v8h ca  = *(const v8h*)&Chs[ra];
            v8h cl2 = *(const v8h*)&Cls[ra];
            v8h ba  = *(const v8h*)&Bhs[rb];
            v8h bl2 = *(const v8h*)&Bls[rb];
            gM = MFMA16(ca, ba, gM);
            gX = MFMA16(ca, bl2, gX);
            gX = MFMA16(cl2, ba, gX);
        }
#pragma unroll
        for (int r = 0; r < 4; ++r) {
            int t = ti * 16 + q * 4 + r;
            int s = si * 16 + r16;
            float g = gM[r] + gX[r] * cs;
            float wgt = (s <= t) ? sLC[t] * sRD[s] * 4096.0f : 0.0f;
            f16 hh, ll; split16(g * wgt, hh, ll);
            Gph[t * 40 + s] = hh;
            Gpl[t * 40 + s] = ll;
        }
    }
    __syncthreads();

    // ---- Y = G'.X /4096 + Dv*x: wave w does ti = w>>1, pj in {(w&1)*2, (w&1)*2+1}
    {
        int ti = w >> 1;
        int ra = (ti * 16 + r16) * 40 + q * 8;
        v8h ga = *(const v8h*)&Gph[ra];
        v8h gl = *(const v8h*)&Gpl[ra];
#pragma unroll
        for (int jj = 0; jj < 2; ++jj) {
            int pj = (w & 1) * 2 + jj;
            int rb = (pj * 16 + r16) * 40 + q * 8;
            v8h xa = *(const v8h*)&Xth[rb];
            v8h xl = *(const v8h*)&Xtl[rb];
            v4f m = (v4f)0.0f, x2 = (v4f)0.0f;
            m  = MFMA16(ga, xa, m);
            x2 = MFMA16(ga, xl, x2);
            x2 = MFMA16(gl, xa, x2);
#pragma unroll
            for (int r = 0; r < 4; ++r) {
                int t = ti * 16 + q * 4 + r;
                int pp = pj * 16 + r16;
                float xv = (float)Xth[pp * 40 + t] + cs * (float)Xtl[pp * 40 + t];
                float val = (m[r] + x2[r] * cs) * cs + Dv * xv;
                yd[(size_t)(base + t0 + t) * DINNER + h * HEADDIM + pp] = val;
            }
        }
    }

    // ---- h_end^T = Bv.X /4096: wave w does ni = w, pj 0..3
    {
        float* Hb = H + (size_t)c * HROW + (size_t)u * 4096;
        int ni = w;
        int ra = (ni * 16 + r16) * 40 + q * 8;
        v8h ba  = *(const v8h*)&Bvh[ra];
        v8h bl2 = *(const v8h*)&Bvl[ra];
#pragma unroll
        for (int pj = 0; pj < 4; ++pj) {
            int rb = (pj * 16 + r16) * 40 + q * 8;
            v8h xa = *(const v8h*)&Xth[rb];
            v8h xl = *(const v8h*)&Xtl[rb];
            v4f m = (v4f)0.0f, x2 = (v4f)0.0f;
            m  = MFMA16(ba, xa, m);
            x2 = MFMA16(ba, xl, x2);
            x2 = MFMA16(bl2, xa, x2);
#pragma unroll
            for (int r = 0; r < 4; ++r) {
                int n = ni * 16 + q * 4 + r;
                int pp = pj * 16 + r16;
                Hb[pp * 64 + n] = (m[r] + x2[r] * cs) * cs;
            }
        }
    }
}

// ---------------------------------------------------------------- S2: carry chain, thread-per-chain (coalesced, in place)
__global__ __launch_bounds__(256) void carry_kernel(
    float* __restrict__ H, const float* __restrict__ cumb) {
    int blk = blockIdx.x;
    int u = blk >> 4;
    int e = ((blk & 15) << 8) + threadIdx.x;   // 0..4095
    size_t off = (size_t)u * 4096 + e;
    float carry = 0.f;
#pragma unroll 4
    for (int c = 0; c < NC; ++c) {
        float Pc = cumb[(u << 10) + c * LC + (LC - 1)];
        float* p = H + (size_t)c * HROW + off;
        float ev = *p;
        *p = carry;
        carry = fmaf(Pc, carry, ev);
    }
}

// ---------------------------------------------------------------- S3: y[t] += cum[t] * (C_t . h_in). 128 threads (2 waves).
__global__ __launch_bounds__(128) void fix_kernel(
    const float* __restrict__ Cbuf, float* __restrict__ y,
    const float* __restrict__ H, const float* __restrict__ cumb) {
    __shared__ float sC[LC * 64];
    __shared__ float sCum[LC];
    int blk = blockIdx.x;
    int u = blk / (NC - 1);
    int c = blk % (NC - 1) + 1;
    int dir = u >> 4, b = (u >> 3) & 1, h = u & 7;
    int tid = threadIdx.x;
    int w = tid >> 6, p = tid & 63;
    const float* Cb = Cbuf + (size_t)dir * ROWS * 64;
    float* yd = y + (size_t)dir * ROWS * DINNER;
    int t0 = c * LC, base = b << 10;
    if (tid < LC) sCum[tid] = cumb[(u << 10) + t0 + tid];
#pragma unroll
    for (int j = 0; j < 4; ++j) {
        int f4 = j * 128 + tid;
        int trow = f4 >> 4, col4 = f4 & 15;
        float4 v = *(const float4*)&Cb[(size_t)(base + t0 + trow) * 64 + col4 * 4];
        *(float4*)&sC[trow * 64 + col4 * 4] = v;
    }
    const float* Hb = H + (size_t)c * HROW + (size_t)u * 4096 + p * 64;
    float hin[DSTATE];
#pragma unroll
    for (int n = 0; n < DSTATE; n += 4) {
        float4 v = *(const float4*)&Hb[n];
        hin[n] = v.x; hin[n + 1] = v.y; hin[n + 2] = v.z; hin[n + 3] = v.w;
    }
    __syncthreads();
#pragma unroll 2
    for (int tt = w * 16; tt < w * 16 + 16; ++tt) {
        float cumt = sCum[tt];
        const float* Cs = &sC[tt * 64];
        float y0 = 0.f, y1 = 0.f, y2 = 0.f, y3 = 0.f;
#pragma unroll
        for (int n = 0; n < DSTATE; n += 4) {
            y0 = fmaf(hin[n],     Cs[n],     y0);
            y1 = fmaf(hin[n + 1], Cs[n + 1], y1);
            y2 = fmaf(hin[n + 2], Cs[n + 2], y2);
            y3 = fmaf(hin[n + 3], Cs[n + 3], y3);
        }
        size_t yi = (size_t)(base + t0 + tt) * DINNER + h * HEADDIM + p;
        yd[yi] += cumt * ((y0 + y1) + (y2 + y3));
    }
}

// ---------------------------------------------------------------- y*silu(z), RMSNorm*nw -> f16 pairs
__global__ __launch_bounds__(256) void gate_rms_kernel(
    const float* __restrict__ y, const float* __restrict__ zbuf,
    const float* __restrict__ nw, f16* __restrict__ yh, f16* __restrict__ yl, int layer) {
    int row = blockIdx.x;
    int dir = blockIdx.y;
    const float* zrow = zbuf + ((size_t)dir * ROWS + row) * DINNER;
    const float* yrow = y + ((size_t)dir * ROWS + row) * DINNER;
    f16* yhr = yh + ((size_t)dir * ROWS + row) * DINNER;
    f16* ylr = yl + ((size_t)dir * ROWS + row) * DINNER;
    const float* nwl = nw + (dir * 2 + layer) * DINNER;
    int tid = threadIdx.x;
    int i0 = tid, i1 = tid + 256;
    float g0 = yrow[i0] * siluf_(zrow[i0]);
    float g1 = yrow[i1] * siluf_(zrow[i1]);
    __shared__ float red[256];
    red[tid] = fmaf(g0, g0, g1 * g1);
    __syncthreads();
    for (int s = 128; s > 0; s >>= 1) {
        if (tid < s) red[tid] += red[tid + s];
        __syncthreads();
    }
    float scale = 1.0f / sqrtf(red[0] / (float)DINNER + EPSF);
    float v0 = g0 * scale * nwl[i0];
    float v1 = g1 * scale * nwl[i1];
    f16 h, l;
    split16(v0, h, l); yhr[i0] = h; ylr[i0] = l;
    split16(v1, h, l); yhr[i1] = h; ylr[i1] = l;
}

// ---------------------------------------------------------------- fusion gates + LayerNorm
__global__ __launch_bounds__(256) void fusion_ln2_kernel(
    const float* __restrict__ u32, const float* __restrict__ gate,
    const float* __restrict__ fb, const float* __restrict__ lnw,
    const float* __restrict__ lnb, float* __restrict__ out) {
    int row = blockIdx.x;
    int b = row >> 10, t = row & 1023;
    int tid = threadIdx.x;
    float f  = u32[(size_t)row * DMODEL + tid];
    float bw = u32[(size_t)ROWS * DMODEL + ((size_t)(b << 10) + (1023 - t)) * DMODEL + tid];
    float g0 = sigmoidf_(gate[(size_t)row * 512 + tid] + fb[tid]);
    float g1 = sigmoidf_(gate[(size_t)row * 512 + 256 + tid] + fb[256 + tid]);
    float fused = g0 * f + g1 * bw;
    __shared__ float red[256];
    red[tid] = fused;
    __syncthreads();
    for (int s = 128; s > 0; s >>= 1) {
        if (tid < s) red[tid] += red[tid + s];
        __syncthreads();
    }
    float mu = red[0] / (float)DMODEL;
    __syncthreads();
    float d = fused - mu;
    red[tid] = d * d;
    __syncthreads();
    for (int s = 128; s > 0; s >>= 1) {
        if (tid < s) red[tid] += red[tid + s];
        __syncthreads();
    }
    float var = red[0] / (float)DMODEL;
    out[(size_t)row * DMODEL + tid] = d * (1.0f / sqrtf(var + EPSF)) * lnw[tid] + lnb[tid];
}

// ---------------------------------------------------------------- launch
extern "C" void kernel_launch(void* const* d_in, const int* in_sizes, int n_in,
                              void* d_out, int out_size, void* d_ws, size_t ws_size,
                              hipStream_t stream) {
    const int*   ids  = (const int*)d_in[0];
    const float* mask = (const float*)d_in[1];
    const float* tok  = (const float*)d_in[2];
    const float* pos  = (const float*)d_in[3];
    const float* inw  = (const float*)d_in[4];
    const float* cw   = (const float*)d_in[5];
    const float* cb   = (const float*)d_in[6];
    const float* dtb  = (const float*)d_in[7];
    const float* alog = (const float*)d_in[8];
    const float* dpar = (const float*)d_in[9];
    const float* nw   = (const float*)d_in[10];
    const float* ow   = (const float*)d_in[11];
    const float* fw   = (const float*)d_in[12];
    const float* fb   = (const float*)d_in[13];
    const float* lnw  = (const float*)d_in[14];
    const float* lnb  = (const float*)d_in[15];

    float* ws = (float*)d_ws;
    float* zbuf = ws;                      //  2,097,152 f
    float* xbc  = ws +  2097152;           //  2,654,208 f (in_proj raw out; live through scan)
    float* ybuf = ws +  4751360;           //  2,097,152 f (scan y; u32 + comb overlays after gate_rms)
    f16*   yh   = (f16*)(ws +  6848512);   //  2,097,152 h
    f16*   yl   = (f16*)(ws +  7897088);   //  2,097,152 h
    float* gate = ws +  8945664;           //  1,048,576 f
    f16*   uh   = (f16*)(ws +  9994240);   //  2,097,152 h
    f16*   ul   = (f16*)(ws + 11042816);   //  2,097,152 h
    f16*   wb   = (f16*)(ws + 12091392);   //  3,948,544 h (all weight pairs)
    float* H    = ws + 14065664;           //  4,194,304 f (flat, c-major)
    float* cumb = ws + 18259968;           //     32,768 f
    float* Cbuf = ws + 18292736;           //    262,144 f (conv'd C for fix)
    float* u32  = ybuf;
    f16*   combh = (f16*)(ybuf + 1048576);
    f16*   combl = (f16*)(ybuf + 1572864);
    f16*   wfh = wb + 2 * (size_t)LSTRIDE;
    f16*   wfl = wfh + WF;

    int wtotal = 2 * (WIN + WOUT) + WF;
    wconv_kernel<<<(wtotal + 1023) / 1024, 256, 0, stream>>>(inw, ow, fw, wb, wtotal);
    embed_kernel<<<ROWS, DMODEL, 0, stream>>>(ids, mask, tok, pos, uh, ul);

    for (int layer = 0; layer < 2; ++layer) {
        f16* wih = wb + (size_t)layer * LSTRIDE;
        f16* wil = wih + WIN;
        f16* woh = wb + (size_t)layer * LSTRIDE + 2 * WIN;
        f16* wol = woh + WOUT;

        dim3 g1(ROWS / 64, (DINPROJ + 63) / 64, 2);
        gemm_f16x3<<<g1, 256, 0, stream>>>(
            uh, ul, (long)ROWS * DMODEL,
            wih, wil, (long)PSI,
            DINPROJ, DMODEL, DINNER,
            zbuf, DINNER, (long)ROWS * DINNER,
            xbc, XBCW, (long)ROWS * XBCW,
            (f16*)nullptr, (f16*)nullptr, 0, 0L,
            1, 0, 0);

        scan_chunk_kernel<<<32 * NC, 256, 0, stream>>>(
            xbc, cw, cb, dtb, ybuf, alog, dpar, H, cumb, Cbuf, layer);
        carry_kernel<<<32 * 16, 256, 0, stream>>>(H, cumb);
        fix_kernel<<<32 * (NC - 1), 128, 0, stream>>>(Cbuf, ybuf, H, cumb);
        gate_rms_kernel<<<dim3(ROWS, 2), 256, 0, stream>>>(ybuf, zbuf, nw, yh, yl, layer);

        dim3 g2(ROWS / 64, DMODEL / 64, 2);
        if (layer == 0) {
            gemm_f16x3<<<g2, 256, 0, stream>>>(
                yh, yl, (long)ROWS * DINNER,
                woh, wol, (long)PSO,
                DMODEL, DINNER, DMODEL,
                u32, DMODEL, (long)ROWS * DMODEL,
                u32, DMODEL, (long)ROWS * DMODEL,
                uh, ul, DMODEL, (long)ROWS * DMODEL,
                1, 1, 0);
        } else {
            gemm_f16x3<<<g2, 256, 0, stream>>>(
                yh, yl, (long)ROWS * DINNER,
                woh, wol, (long)PSO,
                DMODEL, DINNER, DMODEL,
                u32, DMODEL, (long)ROWS * DMODEL,
                u32, DMODEL, (long)ROWS * DMODEL,
                combh, combl, 512, 0L,
                1, 1, 1);
        }
    }

    dim3 g3(ROWS / 64, 512 / 64, 1);
    gemm_f16x3<<<g3, 256, 0, stream>>>(
        combh, combl, 0L,
        wfh, wfl, 0L,
        512, 512, 512,
        gate, 512, 0L,
        gate, 512, 0L,
        (f16*)nullptr, (f16*)nullptr, 0, 0L,
        1, 0, 0);

    fusion_ln2_kernel<<<ROWS, 256, 0, stream>>>(u32, gate, fb, lnw, lnb, (float*)d_out);
}

// Round 10
// 287.361 us; speedup vs baseline: 1.4708x; 1.0343x over previous
//
#include <hip/hip_runtime.h>
#include <cstddef>

#define LSEQ    1024
#define DMODEL  256
#define DINNER  512
#define DSTATE  64
#define NHEADS  8
#define HEADDIM 64
#define CONVDIM 640
#define DINPROJ 1160
#define ROWS    2048   // B * L
#define EPSF    1e-5f
#define NC      32     // chunks per sequence
#define LC      32     // chunk length
#define XBCW    648    // xBC (640) + raw dt (8)
#define HROW    131072 // 32 units * 4096 floats per chunk-row (c-major H)

// weight-pair buffer geometry (element counts)
#define WIN  593920
#define WOUT 262144
#define WF   262144
#define PSI  296960
#define PSO  131072
#define LSTRIDE 1712128   // halves per layer block in wb: 2*(WIN+WOUT)
#define WTOTAL  1974272   // 2*(WIN+WOUT)+WF
#define WBLOCKS 1928      // WTOTAL/1024

typedef _Float16 f16;
typedef f16   v8h __attribute__((ext_vector_type(8)));
typedef f16   v4h __attribute__((ext_vector_type(4)));
typedef float v4f __attribute__((ext_vector_type(4)));
#define MFMA16(a, b, c) __builtin_amdgcn_mfma_f32_16x16x32_f16(a, b, c, 0, 0, 0)

__device__ __forceinline__ float sigmoidf_(float x) { return 1.0f / (1.0f + expf(-x)); }
__device__ __forceinline__ float siluf_(float x)    { return x / (1.0f + expf(-x)); }
__device__ __forceinline__ float softplusf_(float x) {
    return x > 0.0f ? x + log1pf(expf(-x)) : log1pf(expf(x));
}
__device__ __forceinline__ void split16(float v, f16& h, f16& l) {
    h = (f16)v;
    l = (f16)((v - (float)h) * 4096.0f);
}

// 4-channel causal conv(4): identical fma order to the reference conv
__device__ __forceinline__ float4 conv4_(const float* __restrict__ xbcd,
                                         const float* __restrict__ cwl,
                                         const float* __restrict__ cbl,
                                         int base, int tg, int ch0) {
    float4 acc = *(const float4*)&cbl[ch0];
    float4 cw0 = *(const float4*)&cwl[(ch0 + 0) * 4];
    float4 cw1 = *(const float4*)&cwl[(ch0 + 1) * 4];
    float4 cw2 = *(const float4*)&cwl[(ch0 + 2) * 4];
    float4 cw3 = *(const float4*)&cwl[(ch0 + 3) * 4];
    const float* w0 = (const float*)&cw0;
    const float* w1 = (const float*)&cw1;
    const float* w2 = (const float*)&cw2;
    const float* w3 = (const float*)&cw3;
#pragma unroll
    for (int k = 0; k < 4; ++k) {
        int ts = tg - 3 + k;
        if (ts >= 0) {
            float4 xv = *(const float4*)&xbcd[(size_t)(base + ts) * XBCW + ch0];
            acc.x = fmaf(xv.x, w0[k], acc.x);
            acc.y = fmaf(xv.y, w1[k], acc.y);
            acc.z = fmaf(xv.z, w2[k], acc.z);
            acc.w = fmaf(xv.w, w3[k], acc.w);
        }
    }
    return acc;
}

// ---------------------------------------------------------------- merged: embed (blocks 0..2047) + weight conversion (rest)
__global__ __launch_bounds__(256) void prep_kernel(
    const int* __restrict__ ids, const float* __restrict__ mask,
    const float* __restrict__ tok, const float* __restrict__ pos,
    f16* __restrict__ uh, f16* __restrict__ ul,
    const float* __restrict__ inw, const float* __restrict__ ow, const float* __restrict__ fw,
    f16* __restrict__ wb) {
    int blk = blockIdx.x;
    if (blk < ROWS) {
        int row = blk;
        int d = threadIdx.x;
        int b = row >> 10, t = row & 1023;
        int id = ids[row];
        float v = tok[(size_t)id * DMODEL + d] + pos[(size_t)t * DMODEL + d];
        v *= mask[row];
        f16 h, l; split16(v, h, l);
        size_t fwd = (size_t)row * DMODEL + d;
        size_t bwd = (size_t)ROWS * DMODEL + ((size_t)(b << 10) + (1023 - t)) * DMODEL + d;
        uh[fwd] = h; ul[fwd] = l;
        uh[bwd] = h; ul[bwd] = l;
    } else {
        int idx = ((blk - ROWS) * 256 + threadIdx.x) * 4;
#pragma unroll
        for (int e = idx; e < idx + 4; ++e) {
            if (e >= WTOTAL) break;
            float v; f16 *dh, *dl; int off;
            if (e < 2 * (WIN + WOUT)) {
                int layer = e / (WIN + WOUT);
                int r = e - layer * (WIN + WOUT);
                if (r < WIN) {
                    int d = r / PSI, rr = r - d * PSI;
                    v = inw[(size_t)(d * 2 + layer) * PSI + rr];
                    dh = wb + (size_t)layer * LSTRIDE; dl = dh + WIN; off = r;
                } else {
                    int r2 = r - WIN;
                    int d = r2 / PSO, rr = r2 - d * PSO;
                    v = ow[(size_t)(d * 2 + layer) * PSO + rr];
                    dh = wb + (size_t)layer * LSTRIDE + 2 * WIN; dl = dh + WOUT; off = r2;
                }
            } else {
                int e3 = e - 2 * (WIN + WOUT);
                v = fw[e3];
                dh = wb + 2 * (size_t)LSTRIDE; dl = dh + WF; off = e3;
            }
            f16 h, l; split16(v, h, l);
            dh[off] = h; dl[off] = l;
        }
    }
}

// ---------------------------------------------------------------- f16x3 MFMA GEMM with register-prefetch pipeline
__global__ __launch_bounds__(256) void gemm_f16x3(
    const f16* __restrict__ Ah, const f16* __restrict__ Al, long sA,
    const f16* __restrict__ Wh, const f16* __restrict__ Wl, long sW,
    int N, int K, int Nsplit,
    float* __restrict__ O0, int ld0, long sO0,
    float* __restrict__ O1, int ld1, long sO1,
    f16* __restrict__ Ph, f16* __restrict__ Pl, int ldP, long sP,
    int has32, int haspair, int flipcomb) {
    int dir = blockIdx.z;
    Ah += (size_t)dir * sA; Al += (size_t)dir * sA;
    Wh += (size_t)dir * sW; Wl += (size_t)dir * sW;
    if (has32)  { O0 += (size_t)dir * sO0; O1 += (size_t)dir * sO1; }
    if (haspair){ Ph += (size_t)dir * sP;  Pl += (size_t)dir * sP; }

    __shared__ f16 sm[4 * 64 * 72];
    f16* As_h = sm;
    f16* As_l = sm + 64 * 72;
    f16* Ws_h = sm + 2 * 64 * 72;
    f16* Ws_l = sm + 3 * 64 * 72;

    int tid = threadIdx.x;
    int m0 = blockIdx.x * 64, n0 = blockIdx.y * 64;
    int srow = tid >> 2, sseg = tid & 3;
    int lane = tid & 63, w = tid >> 6;
    int wrow = (w >> 1) * 32, wcol = (w & 1) * 32;
    int q = lane >> 4, r16 = lane & 15;
    bool wok = (n0 + srow) < N;

    v4f accM[2][2], accX[2][2];
#pragma unroll
    for (int i = 0; i < 2; ++i)
#pragma unroll
        for (int j = 0; j < 2; ++j) { accM[i][j] = (v4f)0.0f; accX[i][j] = (v4f)0.0f; }

    // prefetch registers (current tile)
    float4 ah0, ah1, al0, al1, wh0, wh1, wl0, wl1;
    {
        size_t aoff = (size_t)(m0 + srow) * K + sseg * 16;
        ah0 = *(const float4*)&Ah[aoff];
        ah1 = *(const float4*)&Ah[aoff + 8];
        al0 = *(const float4*)&Al[aoff];
        al1 = *(const float4*)&Al[aoff + 8];
        wh0 = make_float4(0.f,0.f,0.f,0.f); wh1 = wh0; wl0 = wh0; wl1 = wh0;
        if (wok) {
            size_t woff = (size_t)(n0 + srow) * K + sseg * 16;
            wh0 = *(const float4*)&Wh[woff];
            wh1 = *(const float4*)&Wh[woff + 8];
            wl0 = *(const float4*)&Wl[woff];
            wl1 = *(const float4*)&Wl[woff + 8];
        }
    }

    for (int k0 = 0; k0 < K; k0 += 64) {
        __syncthreads();                 // prev iteration's LDS reads done
        int d = srow * 72 + sseg * 16;
        *(float4*)&As_h[d] = ah0; *(float4*)&As_h[d + 8] = ah1;
        *(float4*)&As_l[d] = al0; *(float4*)&As_l[d + 8] = al1;
        *(float4*)&Ws_h[d] = wh0; *(float4*)&Ws_h[d + 8] = wh1;
        *(float4*)&Ws_l[d] = wl0; *(float4*)&Ws_l[d + 8] = wl1;
        __syncthreads();

        // issue next tile's global loads BEFORE the MFMA section (latency overlaps compute)
        if (k0 + 64 < K) {
            size_t aoff = (size_t)(m0 + srow) * K + (k0 + 64) + sseg * 16;
            ah0 = *(const float4*)&Ah[aoff];
            ah1 = *(const float4*)&Ah[aoff + 8];
            al0 = *(const float4*)&Al[aoff];
            al1 = *(const float4*)&Al[aoff + 8];
            if (wok) {
                size_t woff = (size_t)(n0 + srow) * K + (k0 + 64) + sseg * 16;
                wh0 = *(const float4*)&Wh[woff];
                wh1 = *(const float4*)&Wh[woff + 8];
                wl0 = *(const float4*)&Wl[woff];
                wl1 = *(const float4*)&Wl[woff + 8];
            }
        }

#pragma unroll
        for (int ks = 0; ks < 64; ks += 32) {
            v8h fa_h[2], fa_l[2], fb_h[2], fb_l[2];
#pragma unroll
            for (int i = 0; i < 2; ++i) {
                int ra = (wrow + i * 16 + r16) * 72 + ks + q * 8;
                int rb = (wcol + i * 16 + r16) * 72 + ks + q * 8;
                fa_h[i] = *(const v8h*)&As_h[ra];
                fa_l[i] = *(const v8h*)&As_l[ra];
                fb_h[i] = *(const v8h*)&Ws_h[rb];
                fb_l[i] = *(const v8h*)&Ws_l[rb];
            }
#pragma unroll
            for (int i = 0; i < 2; ++i)
#pragma unroll
                for (int j = 0; j < 2; ++j) {
                    accM[i][j] = MFMA16(fa_h[i], fb_h[j], accM[i][j]);
                    accX[i][j] = MFMA16(fa_h[i], fb_l[j], accX[i][j]);
                    accX[i][j] = MFMA16(fa_l[i], fb_h[j], accX[i][j]);
                }
        }
    }

    const float cs = 1.0f / 4096.0f;
#pragma unroll
    for (int i = 0; i < 2; ++i)
#pragma unroll
        for (int j = 0; j < 2; ++j) {
            int nn = n0 + wcol + j * 16 + r16;
            if (nn < N) {
#pragma unroll
                for (int r = 0; r < 4; ++r) {
                    float v = accM[i][j][r] + accX[i][j][r] * cs;
                    int mm = m0 + wrow + i * 16 + q * 4 + r;
                    if (has32) {
                        if (nn < Nsplit) O0[(size_t)mm * ld0 + nn] = v;
                        else             O1[(size_t)mm * ld1 + (nn - Nsplit)] = v;
                    }
                    if (haspair) {
                        f16 h, l; split16(v, h, l);
                        if (flipcomb) {
                            int bb = mm >> 10, tt_ = mm & 1023;
                            size_t drow = dir == 0 ? (size_t)mm : (size_t)((bb << 10) + (1023 - tt_));
                            size_t dcol = dir == 0 ? (size_t)nn : (size_t)(nn + 256);
                            Ph[drow * 512 + dcol] = h;
                            Pl[drow * 512 + dcol] = l;
                        } else {
                            Ph[(size_t)mm * ldP + nn] = h;
                            Pl[(size_t)mm * ldP + nn] = l;
                        }
                    }
                }
            }
        }
}

// ---------------------------------------------------------------- S1: MFMA-SSD chunk scan with fused conv+silu+softplus
__global__ __launch_bounds__(256) void scan_chunk_kernel(
    const float* __restrict__ xbc, const float* __restrict__ cw, const float* __restrict__ cb,
    const float* __restrict__ dtb, float* __restrict__ y,
    const float* __restrict__ Alog, const float* __restrict__ Dp,
    float* __restrict__ H, float* __restrict__ cumb, float* __restrict__ Cbuf, int layer) {
    __shared__ f16 Chs[32 * 72], Cls[32 * 72], Bhs[32 * 72], Bls[32 * 72];
    __shared__ f16 Xth[64 * 40], Xtl[64 * 40];
    __shared__ f16 Bvh[64 * 40], Bvl[64 * 40];
    __shared__ f16 Gph[32 * 40], Gpl[32 * 40];
    __shared__ float sLC[32], sRD[32], sV[32];

    int blk = blockIdx.x;
    int u = blk >> 5, c = blk & 31;
    int dir = u >> 4, b = (u >> 3) & 1, h = u & 7;
    int tid = threadIdx.x;
    int w = tid >> 6, lane = tid & 63;
    int pi = dir * 2 + layer;
    float Av = -expf(Alog[pi * NHEADS + h]);
    float Dv = Dp[pi * NHEADS + h];
    const float* xbcd = xbc + (size_t)dir * ROWS * XBCW;
    const float* cwl = cw + (size_t)pi * CONVDIM * 4;
    const float* cbl = cb + (size_t)pi * CONVDIM;
    float dtbh = dtb[pi * NHEADS + h];
    float* yd = y + (size_t)dir * ROWS * DINNER;
    int t0 = c * LC, base = b << 10;
    const float cs = 1.0f / 4096.0f;

    if (w == 0) {
        int tp = lane & 31;
        float dtraw = xbcd[(size_t)(base + t0 + tp) * XBCW + CONVDIM + h];
        float dt_l = softplusf_(dtraw + dtbh);
        float dA_l = expf(dt_l * Av);
        float cum_l = dA_l;
#pragma unroll
        for (int off = 1; off < 32; off <<= 1) {
            float o = __shfl_up(cum_l, off);
            if (tp >= off) cum_l *= o;
        }
        float lclast = __shfl(cum_l, 31);
        if (lane < 32) {
            cumb[(u << 10) + t0 + lane] = cum_l;
            float rl = 1.0f / cum_l;
            sLC[lane] = cum_l;
            sRD[lane] = rl * dt_l;
            sV[lane]  = lclast * rl * dt_l * 4096.0f;
        }
    }
    __syncthreads();

#pragma unroll
    for (int j = 0; j < 4; ++j) {
        int idx = j * 256 + tid;
        int tr = idx >> 5, c4 = idx & 31;
        int ch0 = 512 + c4 * 4;
        float4 a = conv4_(xbcd, cwl, cbl, base, t0 + tr, ch0);
        float e[4] = {siluf_(a.x), siluf_(a.y), siluf_(a.z), siluf_(a.w)};
        float vs = sV[tr];
        f16 hq[4], lq[4];
#pragma unroll
        for (int k = 0; k < 4; ++k) split16(e[k], hq[k], lq[k]);
        int col0 = c4 * 4;
        if (col0 < 64) {
            *(v4h*)&Bhs[tr * 72 + col0] = *(v4h*)hq;
            *(v4h*)&Bls[tr * 72 + col0] = *(v4h*)lq;
#pragma unroll
            for (int k = 0; k < 4; ++k) {
                f16 h2, l2; split16(e[k] * vs, h2, l2);
                Bvh[(col0 + k) * 40 + tr] = h2;
                Bvl[(col0 + k) * 40 + tr] = l2;
            }
        } else {
            *(v4h*)&Chs[tr * 72 + col0 - 64] = *(v4h*)hq;
            *(v4h*)&Cls[tr * 72 + col0 - 64] = *(v4h*)lq;
            if (h == 0)
                *(float4*)&Cbuf[((size_t)dir * ROWS + base + t0 + tr) * 64 + (col0 - 64)] =
                    make_float4(e[0], e[1], e[2], e[3]);
        }
    }
#pragma unroll
    for (int j = 0; j < 2; ++j) {
        int idx = j * 256 + tid;
        int sr = idx >> 4, c4 = idx & 15;
        int ch0 = h * HEADDIM + c4 * 4;
        float4 a = conv4_(xbcd, cwl, cbl, base, t0 + sr, ch0);
        float e[4] = {siluf_(a.x), siluf_(a.y), siluf_(a.z), siluf_(a.w)};
#pragma unroll
        for (int k = 0; k < 4; ++k) {
            f16 hh, ll; split16(e[k], hh, ll);
            Xth[(c4 * 4 + k) * 40 + sr] = hh;
            Xtl[(c4 * 4 + k) * 40 + sr] = ll;
        }
    }
    __syncthreads();

    int q = lane >> 4, r16 = lane & 15;

    {
        int ti = w >> 1, si = w & 1;
        v4f gM = (v4f)0.0f, gX = (v4f)0.0f;
#pragma unroll
        for (int ks = 0; ks < 64; ks += 32) {
            int ra = (ti * 16 + r16) * 72 + ks + q * 8;
            int rb = (si * 16 + r16) * 72 + ks + q * 8;
            v8h ca  = *(const v8h*)&Chs[ra];
            v8h cl2 = *(const v8h*)&Cls[ra];
            v8h ba  = *(const v8h*)&Bhs[rb];
            v8h bl2 = *(const v8h*)&Bls[rb];
            gM = MFMA16(ca, ba, gM);
            gX = MFMA16(ca, bl2, gX);
            gX = MFMA16(cl2, ba, gX);
        }
#pragma unroll
        for (int r = 0; r < 4; ++r) {
            int t = ti * 16 + q * 4 + r;
            int s = si * 16 + r16;
            float g = gM[r] + gX[r] * cs;
            float wgt = (s <= t) ? sLC[t] * sRD[s] * 4096.0f : 0.0f;
            f16 hh, ll; split16(g * wgt, hh, ll);
            Gph[t * 40 + s] = hh;
            Gpl[t * 40 + s] = ll;
        }
    }
    __syncthreads();

    {
        int ti = w >> 1;
        int ra = (ti * 16 + r16) * 40 + q * 8;
        v8h ga = *(const v8h*)&Gph[ra];
        v8h gl = *(const v8h*)&Gpl[ra];
#pragma unroll
        for (int jj = 0; jj < 2; ++jj) {
            int pj = (w & 1) * 2 + jj;
            int rb = (pj * 16 + r16) * 40 + q * 8;
            v8h xa = *(const v8h*)&Xth[rb];
            v8h xl = *(const v8h*)&Xtl[rb];
            v4f m = (v4f)0.0f, x2 = (v4f)0.0f;
            m  = MFMA16(ga, xa, m);
            x2 = MFMA16(ga, xl, x2);
            x2 = MFMA16(gl, xa, x2);
#pragma unroll
            for (int r = 0; r < 4; ++r) {
                int t = ti * 16 + q * 4 + r;
                int pp = pj * 16 + r16;
                float xv = (float)Xth[pp * 40 + t] + cs * (float)Xtl[pp * 40 + t];
                float val = (m[r] + x2[r] * cs) * cs + Dv * xv;
                yd[(size_t)(base + t0 + t) * DINNER + h * HEADDIM + pp] = val;
            }
        }
    }

    {
        float* Hb = H + (size_t)c * HROW + (size_t)u * 4096;
        int ni = w;
        int ra = (ni * 16 + r16) * 40 + q * 8;
        v8h ba  = *(const v8h*)&Bvh[ra];
        v8h bl2 = *(const v8h*)&Bvl[ra];
#pragma unroll
        for (int pj = 0; pj < 4; ++pj) {
            int rb = (pj * 16 + r16) * 40 + q * 8;
            v8h xa = *(const v8h*)&Xth[rb];
            v8h xl = *(const v8h*)&Xtl[rb];
            v4f m = (v4f)0.0f, x2 = (v4f)0.0f;
            m  = MFMA16(ba, xa, m);
            x2 = MFMA16(ba, xl, x2);
            x2 = MFMA16(bl2, xa, x2);
#pragma unroll
            for (int r = 0; r < 4; ++r) {
                int n = ni * 16 + q * 4 + r;
                int pp = pj * 16 + r16;
                Hb[pp * 64 + n] = (m[r] + x2[r] * cs) * cs;
            }
        }
    }
}

// ---------------------------------------------------------------- S2: carry chain, thread-per-chain
__global__ __launch_bounds__(256) void carry_kernel(
    float* __restrict__ H, const float* __restrict__ cumb) {
    int blk = blockIdx.x;
    int u = blk >> 4;
    int e = ((blk & 15) << 8) + threadIdx.x;
    size_t off = (size_t)u * 4096 + e;
    float carry = 0.f;
#pragma unroll 4
    for (int c = 0; c < NC; ++c) {
        float Pc = cumb[(u << 10) + c * LC + (LC - 1)];
        float* p = H + (size_t)c * HROW + off;
        float ev = *p;
        *p = carry;
        carry = fmaf(Pc, carry, ev);
    }
}

// ---------------------------------------------------------------- S3: y[t] += cum[t] * (C_t . h_in)
__global__ __launch_bounds__(128) void fix_kernel(
    const float* __restrict__ Cbuf, float* __restrict__ y,
    const float* __restrict__ H, const float* __restrict__ cumb) {
    __shared__ float sC[LC * 64];
    __shared__ float sCum[LC];
    int blk = blockIdx.x;
    int u = blk / (NC - 1);
    int c = blk % (NC - 1) + 1;
    int dir = u >> 4, b = (u >> 3) & 1, h = u & 7;
    int tid = threadIdx.x;
    int w = tid >> 6, p = tid & 63;
    const float* Cb = Cbuf + (size_t)dir * ROWS * 64;
    float* yd = y + (size_t)dir * ROWS * DINNER;
    int t0 = c * LC, base = b << 10;
    if (tid < LC) sCum[tid] = cumb[(u << 10) + t0 + tid];
#pragma unroll
    for (int j = 0; j < 4; ++j) {
        int f4 = j * 128 + tid;
        int trow = f4 >> 4, col4 = f4 & 15;
        float4 v = *(const float4*)&Cb[(size_t)(base + t0 + trow) * 64 + col4 * 4];
        *(float4*)&sC[trow * 64 + col4 * 4] = v;
    }
    const float* Hb = H + (size_t)c * HROW + (size_t)u * 4096 + p * 64;
    float hin[DSTATE];
#pragma unroll
    for (int n = 0; n < DSTATE; n += 4) {
        float4 v = *(const float4*)&Hb[n];
        hin[n] = v.x; hin[n + 1] = v.y; hin[n + 2] = v.z; hin[n + 3] = v.w;
    }
    __syncthreads();
#pragma unroll 2
    for (int tt = w * 16; tt < w * 16 + 16; ++tt) {
        float cumt = sCum[tt];
        const float* Cs = &sC[tt * 64];
        float y0 = 0.f, y1 = 0.f, y2 = 0.f, y3 = 0.f;
#pragma unroll
        for (int n = 0; n < DSTATE; n += 4) {
            y0 = fmaf(hin[n],     Cs[n],     y0);
            y1 = fmaf(hin[n + 1], Cs[n + 1], y1);
            y2 = fmaf(hin[n + 2], Cs[n + 2], y2);
            y3 = fmaf(hin[n + 3], Cs[n + 3], y3);
        }
        size_t yi = (size_t)(base + t0 + tt) * DINNER + h * HEADDIM + p;
        yd[yi] += cumt * ((y0 + y1) + (y2 + y3));
    }
}

// ---------------------------------------------------------------- y*silu(z), RMSNorm*nw -> f16 pairs
__global__ __launch_bounds__(256) void gate_rms_kernel(
    const float* __restrict__ y, const float* __restrict__ zbuf,
    const float* __restrict__ nw, f16* __restrict__ yh, f16* __restrict__ yl, int layer) {
    int row = blockIdx.x;
    int dir = blockIdx.y;
    const float* zrow = zbuf + ((size_t)dir * ROWS + row) * DINNER;
    const float* yrow = y + ((size_t)dir * ROWS + row) * DINNER;
    f16* yhr = yh + ((size_t)dir * ROWS + row) * DINNER;
    f16* ylr = yl + ((size_t)dir * ROWS + row) * DINNER;
    const float* nwl = nw + (dir * 2 + layer) * DINNER;
    int tid = threadIdx.x;
    int i0 = tid, i1 = tid + 256;
    float g0 = yrow[i0] * siluf_(zrow[i0]);
    float g1 = yrow[i1] * siluf_(zrow[i1]);
    __shared__ float red[256];
    red[tid] = fmaf(g0, g0, g1 * g1);
    __syncthreads();
    for (int s = 128; s > 0; s >>= 1) {
        if (tid < s) red[tid] += red[tid + s];
        __syncthreads();
    }
    float scale = 1.0f / sqrtf(red[0] / (float)DINNER + EPSF);
    float v0 = g0 * scale * nwl[i0];
    float v1 = g1 * scale * nwl[i1];
    f16 h, l;
    split16(v0, h, l); yhr[i0] = h; ylr[i0] = l;
    split16(v1, h, l); yhr[i1] = h; ylr[i1] = l;
}

// ---------------------------------------------------------------- fusion gates + LayerNorm
__global__ __launch_bounds__(256) void fusion_ln2_kernel(
    const float* __restrict__ u32, const float* __restrict__ gate,
    const float* __restrict__ fb, const float* __restrict__ lnw,
    const float* __restrict__ lnb, float* __restrict__ out) {
    int row = blockIdx.x;
    int b = row >> 10, t = row & 1023;
    int tid = threadIdx.x;
    float f  = u32[(size_t)row * DMODEL + tid];
    float bw = u32[(size_t)ROWS * DMODEL + ((size_t)(b << 10) + (1023 - t)) * DMODEL + tid];
    float g0 = sigmoidf_(gate[(size_t)row * 512 + tid] + fb[tid]);
    float g1 = sigmoidf_(gate[(size_t)row * 512 + 256 + tid] + fb[256 + tid]);
    float fused = g0 * f + g1 * bw;
    __shared__ float red[256];
    red[tid] = fused;
    __syncthreads();
    for (int s = 128; s > 0; s >>= 1) {
        if (tid < s) red[tid] += red[tid + s];
        __syncthreads();
    }
    float mu = red[0] / (float)DMODEL;
    __syncthreads();
    float d = fused - mu;
    red[tid] = d * d;
    __syncthreads();
    for (int s = 128; s > 0; s >>= 1) {
        if (tid < s) red[tid] += red[tid + s];
        __syncthreads();
    }
    float var = red[0] / (float)DMODEL;
    out[(size_t)row * DMODEL + tid] = d * (1.0f / sqrtf(var + EPSF)) * lnw[tid] + lnb[tid];
}

// ---------------------------------------------------------------- launch
extern "C" void kernel_launch(void* const* d_in, const int* in_sizes, int n_in,
                              void* d_out, int out_size, void* d_ws, size_t ws_size,
                              hipStream_t stream) {
    const int*   ids  = (const int*)d_in[0];
    const float* mask = (const float*)d_in[1];
    const float* tok  = (const float*)d_in[2];
    const float* pos  = (const float*)d_in[3];
    const float* inw  = (const float*)d_in[4];
    const float* cw   = (const float*)d_in[5];
    const float* cb   = (const float*)d_in[6];
    const float* dtb  = (const float*)d_in[7];
    const float* alog = (const float*)d_in[8];
    const float* dpar = (const float*)d_in[9];
    const float* nw   = (const float*)d_in[10];
    const float* ow   = (const float*)d_in[11];
    const float* fw   = (const float*)d_in[12];
    const float* fb   = (const float*)d_in[13];
    const float* lnw  = (const float*)d_in[14];
    const float* lnb  = (const float*)d_in[15];

    float* ws = (float*)d_ws;
    float* zbuf = ws;                      //  2,097,152 f
    float* xbc  = ws +  2097152;           //  2,654,208 f
    float* ybuf = ws +  4751360;           //  2,097,152 f
    f16*   yh   = (f16*)(ws +  6848512);   //  2,097,152 h
    f16*   yl   = (f16*)(ws +  7897088);   //  2,097,152 h
    float* gate = ws +  8945664;           //  1,048,576 f
    f16*   uh   = (f16*)(ws +  9994240);   //  2,097,152 h
    f16*   ul   = (f16*)(ws + 11042816);   //  2,097,152 h
    f16*   wb   = (f16*)(ws + 12091392);   //  3,948,544 h
    float* H    = ws + 14065664;           //  4,194,304 f
    float* cumb = ws + 18259968;           //     32,768 f
    float* Cbuf = ws + 18292736;           //    262,144 f
    float* u32  = ybuf;
    f16*   combh = (f16*)(ybuf + 1048576);
    f16*   combl = (f16*)(ybuf + 1572864);
    f16*   wfh = wb + 2 * (size_t)LSTRIDE;
    f16*   wfl = wfh + WF;

    prep_kernel<<<ROWS + WBLOCKS, 256, 0, stream>>>(ids, mask, tok, pos, uh, ul, inw, ow, fw, wb);

    for (int layer = 0; layer < 2; ++layer) {
        f16* wih = wb + (size_t)layer * LSTRIDE;
        f16* wil = wih + WIN;
        f16* woh = wb + (size_t)layer * LSTRIDE + 2 * WIN;
        f16* wol = woh + WOUT;

        dim3 g1(ROWS / 64, (DINPROJ + 63) / 64, 2);
        gemm_f16x3<<<g1, 256, 0, stream>>>(
            uh, ul, (long)ROWS * DMODEL,
            wih, wil, (long)PSI,
            DINPROJ, DMODEL, DINNER,
            zbuf, DINNER, (long)ROWS * DINNER,
            xbc, XBCW, (long)ROWS * XBCW,
            (f16*)nullptr, (f16*)nullptr, 0, 0L,
            1, 0, 0);

        scan_chunk_kernel<<<32 * NC, 256, 0, stream>>>(
            xbc, cw, cb, dtb, ybuf, alog, dpar, H, cumb, Cbuf, layer);
        carry_kernel<<<32 * 16, 256, 0, stream>>>(H, cumb);
        fix_kernel<<<32 * (NC - 1), 128, 0, stream>>>(Cbuf, ybuf, H, cumb);
        gate_rms_kernel<<<dim3(ROWS, 2), 256, 0, stream>>>(ybuf, zbuf, nw, yh, yl, layer);

        dim3 g2(ROWS / 64, DMODEL / 64, 2);
        if (layer == 0) {
            gemm_f16x3<<<g2, 256, 0, stream>>>(
                yh, yl, (long)ROWS * DINNER,
                woh, wol, (long)PSO,
                DMODEL, DINNER, DMODEL,
                u32, DMODEL, (long)ROWS * DMODEL,
                u32, DMODEL, (long)ROWS * DMODEL,
                uh, ul, DMODEL, (long)ROWS * DMODEL,
                1, 1, 0);
        } else {
            gemm_f16x3<<<g2, 256, 0, stream>>>(
                yh, yl, (long)ROWS * DINNER,
                woh, wol, (long)PSO,
                DMODEL, DINNER, DMODEL,
                u32, DMODEL, (long)ROWS * DMODEL,
                u32, DMODEL, (long)ROWS * DMODEL,
                combh, combl, 512, 0L,
                1, 1, 1);
        }
    }

    dim3 g3(ROWS / 64, 512 / 64, 1);
    gemm_f16x3<<<g3, 256, 0, stream>>>(
        combh, combl, 0L,
        wfh, wfl, 0L,
        512, 512, 512,
        gate, 512, 0L,
        gate, 512, 0L,
        (f16*)nullptr, (f16*)nullptr, 0, 0L,
        1, 0, 0);

    fusion_ln2_kernel<<<ROWS, 256, 0, stream>>>(u32, gate, fb, lnw, lnb, (float*)d_out);
}

// Round 11
// 285.869 us; speedup vs baseline: 1.4785x; 1.0052x over previous
//
#include <hip/hip_runtime.h>
#include <cstddef>

#define LSEQ    1024
#define DMODEL  256
#define DINNER  512
#define DSTATE  64
#define NHEADS  8
#define HEADDIM 64
#define CONVDIM 640
#define DINPROJ 1160
#define ROWS    2048   // B * L
#define EPSF    1e-5f
#define NC      32     // chunks per sequence
#define LC      32     // chunk length
#define XBCW    648    // xBC (640) + raw dt (8)
#define HROW    131072 // 32 units * 4096 floats per chunk-row (c-major H)

// weight-pair buffer geometry (element counts)
#define WIN  593920
#define WOUT 262144
#define WF   262144
#define PSI  296960
#define PSO  131072
#define LSTRIDE 1712128   // halves per layer block in wb: 2*(WIN+WOUT)
#define WTOTAL  1974272   // 2*(WIN+WOUT)+WF
#define WBLOCKS 1928      // WTOTAL/1024

typedef _Float16 f16;
typedef f16   v8h __attribute__((ext_vector_type(8)));
typedef f16   v4h __attribute__((ext_vector_type(4)));
typedef float v4f __attribute__((ext_vector_type(4)));
#define MFMA16(a, b, c) __builtin_amdgcn_mfma_f32_16x16x32_f16(a, b, c, 0, 0, 0)

__device__ __forceinline__ float sigmoidf_(float x) { return 1.0f / (1.0f + expf(-x)); }
__device__ __forceinline__ float siluf_(float x)    { return x / (1.0f + expf(-x)); }
__device__ __forceinline__ float softplusf_(float x) {
    return x > 0.0f ? x + log1pf(expf(-x)) : log1pf(expf(x));
}
__device__ __forceinline__ void split16(float v, f16& h, f16& l) {
    h = (f16)v;
    l = (f16)((v - (float)h) * 4096.0f);
}

// 4-channel causal conv(4): identical fma order to the reference conv
__device__ __forceinline__ float4 conv4_(const float* __restrict__ xbcd,
                                         const float* __restrict__ cwl,
                                         const float* __restrict__ cbl,
                                         int base, int tg, int ch0) {
    float4 acc = *(const float4*)&cbl[ch0];
    float4 cw0 = *(const float4*)&cwl[(ch0 + 0) * 4];
    float4 cw1 = *(const float4*)&cwl[(ch0 + 1) * 4];
    float4 cw2 = *(const float4*)&cwl[(ch0 + 2) * 4];
    float4 cw3 = *(const float4*)&cwl[(ch0 + 3) * 4];
    const float* w0 = (const float*)&cw0;
    const float* w1 = (const float*)&cw1;
    const float* w2 = (const float*)&cw2;
    const float* w3 = (const float*)&cw3;
#pragma unroll
    for (int k = 0; k < 4; ++k) {
        int ts = tg - 3 + k;
        if (ts >= 0) {
            float4 xv = *(const float4*)&xbcd[(size_t)(base + ts) * XBCW + ch0];
            acc.x = fmaf(xv.x, w0[k], acc.x);
            acc.y = fmaf(xv.y, w1[k], acc.y);
            acc.z = fmaf(xv.z, w2[k], acc.z);
            acc.w = fmaf(xv.w, w3[k], acc.w);
        }
    }
    return acc;
}

// ---------------------------------------------------------------- merged: embed (blocks 0..2047) + weight conversion (rest)
__global__ __launch_bounds__(256) void prep_kernel(
    const int* __restrict__ ids, const float* __restrict__ mask,
    const float* __restrict__ tok, const float* __restrict__ pos,
    f16* __restrict__ uh, f16* __restrict__ ul,
    const float* __restrict__ inw, const float* __restrict__ ow, const float* __restrict__ fw,
    f16* __restrict__ wb) {
    int blk = blockIdx.x;
    if (blk < ROWS) {
        int row = blk;
        int d = threadIdx.x;
        int b = row >> 10, t = row & 1023;
        int id = ids[row];
        float v = tok[(size_t)id * DMODEL + d] + pos[(size_t)t * DMODEL + d];
        v *= mask[row];
        f16 h, l; split16(v, h, l);
        size_t fwd = (size_t)row * DMODEL + d;
        size_t bwd = (size_t)ROWS * DMODEL + ((size_t)(b << 10) + (1023 - t)) * DMODEL + d;
        uh[fwd] = h; ul[fwd] = l;
        uh[bwd] = h; ul[bwd] = l;
    } else {
        int idx = ((blk - ROWS) * 256 + threadIdx.x) * 4;
#pragma unroll
        for (int e = idx; e < idx + 4; ++e) {
            if (e >= WTOTAL) break;
            float v; f16 *dh, *dl; int off;
            if (e < 2 * (WIN + WOUT)) {
                int layer = e / (WIN + WOUT);
                int r = e - layer * (WIN + WOUT);
                if (r < WIN) {
                    int d = r / PSI, rr = r - d * PSI;
                    v = inw[(size_t)(d * 2 + layer) * PSI + rr];
                    dh = wb + (size_t)layer * LSTRIDE; dl = dh + WIN; off = r;
                } else {
                    int r2 = r - WIN;
                    int d = r2 / PSO, rr = r2 - d * PSO;
                    v = ow[(size_t)(d * 2 + layer) * PSO + rr];
                    dh = wb + (size_t)layer * LSTRIDE + 2 * WIN; dl = dh + WOUT; off = r2;
                }
            } else {
                int e3 = e - 2 * (WIN + WOUT);
                v = fw[e3];
                dh = wb + 2 * (size_t)LSTRIDE; dl = dh + WF; off = e3;
            }
            f16 h, l; split16(v, h, l);
            dh[off] = h; dl[off] = l;
        }
    }
}

// ---------------------------------------------------------------- conv+SiLU for B/C cols (512..639), once per (dir,row)
__global__ __launch_bounds__(256) void conv_bc_kernel(
    const float* __restrict__ xbc, const float* __restrict__ cw, const float* __restrict__ cb,
    float* __restrict__ BCbuf, int layer) {
    int idx = blockIdx.x * 256 + threadIdx.x;   // 2 dirs * 2048 rows * 32 c4 = 131072
    int c4 = idx & 31;
    int row = (idx >> 5) & 2047;
    int dir = idx >> 16;
    int b = row >> 10, t = row & 1023;
    const float* xbcd = xbc + (size_t)dir * ROWS * XBCW;
    int pi = dir * 2 + layer;
    const float* cwl = cw + (size_t)pi * CONVDIM * 4;
    const float* cbl = cb + (size_t)pi * CONVDIM;
    float4 a = conv4_(xbcd, cwl, cbl, b << 10, t, 512 + c4 * 4);
    float4 e = make_float4(siluf_(a.x), siluf_(a.y), siluf_(a.z), siluf_(a.w));
    *(float4*)&BCbuf[((size_t)dir * ROWS + row) * 128 + c4 * 4] = e;
}

// ---------------------------------------------------------------- f16x3 MFMA GEMM with register-prefetch pipeline
__global__ __launch_bounds__(256) void gemm_f16x3(
    const f16* __restrict__ Ah, const f16* __restrict__ Al, long sA,
    const f16* __restrict__ Wh, const f16* __restrict__ Wl, long sW,
    int N, int K, int Nsplit,
    float* __restrict__ O0, int ld0, long sO0,
    float* __restrict__ O1, int ld1, long sO1,
    f16* __restrict__ Ph, f16* __restrict__ Pl, int ldP, long sP,
    int has32, int haspair, int flipcomb) {
    int dir = blockIdx.z;
    Ah += (size_t)dir * sA; Al += (size_t)dir * sA;
    Wh += (size_t)dir * sW; Wl += (size_t)dir * sW;
    if (has32)  { O0 += (size_t)dir * sO0; O1 += (size_t)dir * sO1; }
    if (haspair){ Ph += (size_t)dir * sP;  Pl += (size_t)dir * sP; }

    __shared__ f16 sm[4 * 64 * 72];
    f16* As_h = sm;
    f16* As_l = sm + 64 * 72;
    f16* Ws_h = sm + 2 * 64 * 72;
    f16* Ws_l = sm + 3 * 64 * 72;

    int tid = threadIdx.x;
    int m0 = blockIdx.x * 64, n0 = blockIdx.y * 64;
    int srow = tid >> 2, sseg = tid & 3;
    int lane = tid & 63, w = tid >> 6;
    int wrow = (w >> 1) * 32, wcol = (w & 1) * 32;
    int q = lane >> 4, r16 = lane & 15;
    bool wok = (n0 + srow) < N;

    v4f accM[2][2], accX[2][2];
#pragma unroll
    for (int i = 0; i < 2; ++i)
#pragma unroll
        for (int j = 0; j < 2; ++j) { accM[i][j] = (v4f)0.0f; accX[i][j] = (v4f)0.0f; }

    float4 ah0, ah1, al0, al1, wh0, wh1, wl0, wl1;
    {
        size_t aoff = (size_t)(m0 + srow) * K + sseg * 16;
        ah0 = *(const float4*)&Ah[aoff];
        ah1 = *(const float4*)&Ah[aoff + 8];
        al0 = *(const float4*)&Al[aoff];
        al1 = *(const float4*)&Al[aoff + 8];
        wh0 = make_float4(0.f,0.f,0.f,0.f); wh1 = wh0; wl0 = wh0; wl1 = wh0;
        if (wok) {
            size_t woff = (size_t)(n0 + srow) * K + sseg * 16;
            wh0 = *(const float4*)&Wh[woff];
            wh1 = *(const float4*)&Wh[woff + 8];
            wl0 = *(const float4*)&Wl[woff];
            wl1 = *(const float4*)&Wl[woff + 8];
        }
    }

    for (int k0 = 0; k0 < K; k0 += 64) {
        __syncthreads();
        int d = srow * 72 + sseg * 16;
        *(float4*)&As_h[d] = ah0; *(float4*)&As_h[d + 8] = ah1;
        *(float4*)&As_l[d] = al0; *(float4*)&As_l[d + 8] = al1;
        *(float4*)&Ws_h[d] = wh0; *(float4*)&Ws_h[d + 8] = wh1;
        *(float4*)&Ws_l[d] = wl0; *(float4*)&Ws_l[d + 8] = wl1;
        __syncthreads();

        if (k0 + 64 < K) {
            size_t aoff = (size_t)(m0 + srow) * K + (k0 + 64) + sseg * 16;
            ah0 = *(const float4*)&Ah[aoff];
            ah1 = *(const float4*)&Ah[aoff + 8];
            al0 = *(const float4*)&Al[aoff];
            al1 = *(const float4*)&Al[aoff + 8];
            if (wok) {
                size_t woff = (size_t)(n0 + srow) * K + (k0 + 64) + sseg * 16;
                wh0 = *(const float4*)&Wh[woff];
                wh1 = *(const float4*)&Wh[woff + 8];
                wl0 = *(const float4*)&Wl[woff];
                wl1 = *(const float4*)&Wl[woff + 8];
            }
        }

#pragma unroll
        for (int ks = 0; ks < 64; ks += 32) {
            v8h fa_h[2], fa_l[2], fb_h[2], fb_l[2];
#pragma unroll
            for (int i = 0; i < 2; ++i) {
                int ra = (wrow + i * 16 + r16) * 72 + ks + q * 8;
                int rb = (wcol + i * 16 + r16) * 72 + ks + q * 8;
                fa_h[i] = *(const v8h*)&As_h[ra];
                fa_l[i] = *(const v8h*)&As_l[ra];
                fb_h[i] = *(const v8h*)&Ws_h[rb];
                fb_l[i] = *(const v8h*)&Ws_l[rb];
            }
#pragma unroll
            for (int i = 0; i < 2; ++i)
#pragma unroll
                for (int j = 0; j < 2; ++j) {
                    accM[i][j] = MFMA16(fa_h[i], fb_h[j], accM[i][j]);
                    accX[i][j] = MFMA16(fa_h[i], fb_l[j], accX[i][j]);
                    accX[i][j] = MFMA16(fa_l[i], fb_h[j], accX[i][j]);
                }
        }
    }

    const float cs = 1.0f / 4096.0f;
#pragma unroll
    for (int i = 0; i < 2; ++i)
#pragma unroll
        for (int j = 0; j < 2; ++j) {
            int nn = n0 + wcol + j * 16 + r16;
            if (nn < N) {
#pragma unroll
                for (int r = 0; r < 4; ++r) {
                    float v = accM[i][j][r] + accX[i][j][r] * cs;
                    int mm = m0 + wrow + i * 16 + q * 4 + r;
                    if (has32) {
                        if (nn < Nsplit) O0[(size_t)mm * ld0 + nn] = v;
                        else             O1[(size_t)mm * ld1 + (nn - Nsplit)] = v;
                    }
                    if (haspair) {
                        f16 h, l; split16(v, h, l);
                        if (flipcomb) {
                            int bb = mm >> 10, tt_ = mm & 1023;
                            size_t drow = dir == 0 ? (size_t)mm : (size_t)((bb << 10) + (1023 - tt_));
                            size_t dcol = dir == 0 ? (size_t)nn : (size_t)(nn + 256);
                            Ph[drow * 512 + dcol] = h;
                            Pl[drow * 512 + dcol] = l;
                        } else {
                            Ph[(size_t)mm * ldP + nn] = h;
                            Pl[(size_t)mm * ldP + nn] = l;
                        }
                    }
                }
            }
        }
}

// ---------------------------------------------------------------- S1: MFMA-SSD chunk scan; B/C from BCbuf, X-conv fused
__global__ __launch_bounds__(256) void scan_chunk_kernel(
    const float* __restrict__ xbc, const float* __restrict__ BCbuf,
    const float* __restrict__ cw, const float* __restrict__ cb,
    const float* __restrict__ dtb, float* __restrict__ y,
    const float* __restrict__ Alog, const float* __restrict__ Dp,
    float* __restrict__ H, float* __restrict__ cumb, int layer) {
    __shared__ f16 Chs[32 * 72], Cls[32 * 72], Bhs[32 * 72], Bls[32 * 72];
    __shared__ f16 Xth[64 * 40], Xtl[64 * 40];
    __shared__ f16 Bvh[64 * 40], Bvl[64 * 40];
    __shared__ f16 Gph[32 * 40], Gpl[32 * 40];
    __shared__ float sLC[32], sRD[32], sV[32];

    int blk = blockIdx.x;
    int u = blk >> 5, c = blk & 31;
    int dir = u >> 4, b = (u >> 3) & 1, h = u & 7;
    int tid = threadIdx.x;
    int w = tid >> 6, lane = tid & 63;
    int pi = dir * 2 + layer;
    float Av = -expf(Alog[pi * NHEADS + h]);
    float Dv = Dp[pi * NHEADS + h];
    const float* xbcd = xbc + (size_t)dir * ROWS * XBCW;
    const float* BCb = BCbuf + (size_t)dir * ROWS * 128;
    const float* cwl = cw + (size_t)pi * CONVDIM * 4;
    const float* cbl = cb + (size_t)pi * CONVDIM;
    float dtbh = dtb[pi * NHEADS + h];
    float* yd = y + (size_t)dir * ROWS * DINNER;
    int t0 = c * LC, base = b << 10;
    const float cs = 1.0f / 4096.0f;

    if (w == 0) {
        int tp = lane & 31;
        float dtraw = xbcd[(size_t)(base + t0 + tp) * XBCW + CONVDIM + h];
        float dt_l = softplusf_(dtraw + dtbh);
        float dA_l = expf(dt_l * Av);
        float cum_l = dA_l;
#pragma unroll
        for (int off = 1; off < 32; off <<= 1) {
            float o = __shfl_up(cum_l, off);
            if (tp >= off) cum_l *= o;
        }
        float lclast = __shfl(cum_l, 31);
        if (lane < 32) {
            cumb[(u << 10) + t0 + lane] = cum_l;
            float rl = 1.0f / cum_l;
            sLC[lane] = cum_l;
            sRD[lane] = rl * dt_l;
            sV[lane]  = lclast * rl * dt_l * 4096.0f;
        }
    }
    __syncthreads();

    // stage B/C from precomputed BCbuf (values bitwise-identical to fused conv)
#pragma unroll
    for (int j = 0; j < 4; ++j) {
        int idx = j * 256 + tid;
        int tr = idx >> 5, c4 = idx & 31;
        float4 v = *(const float4*)&BCb[(size_t)(base + t0 + tr) * 128 + c4 * 4];
        float e[4] = {v.x, v.y, v.z, v.w};
        float vs = sV[tr];
        f16 hq[4], lq[4];
#pragma unroll
        for (int k = 0; k < 4; ++k) split16(e[k], hq[k], lq[k]);
        int col0 = c4 * 4;
        if (col0 < 64) {
            *(v4h*)&Bhs[tr * 72 + col0] = *(v4h*)hq;
            *(v4h*)&Bls[tr * 72 + col0] = *(v4h*)lq;
#pragma unroll
            for (int k = 0; k < 4; ++k) {
                f16 h2, l2; split16(e[k] * vs, h2, l2);
                Bvh[(col0 + k) * 40 + tr] = h2;
                Bvl[(col0 + k) * 40 + tr] = l2;
            }
        } else {
            *(v4h*)&Chs[tr * 72 + col0 - 64] = *(v4h*)hq;
            *(v4h*)&Cls[tr * 72 + col0 - 64] = *(v4h*)lq;
        }
    }
    // stage X^T (head slice) with fused conv+silu (per-head unique)
#pragma unroll
    for (int j = 0; j < 2; ++j) {
        int idx = j * 256 + tid;
        int sr = idx >> 4, c4 = idx & 15;
        int ch0 = h * HEADDIM + c4 * 4;
        float4 a = conv4_(xbcd, cwl, cbl, base, t0 + sr, ch0);
        float e[4] = {siluf_(a.x), siluf_(a.y), siluf_(a.z), siluf_(a.w)};
#pragma unroll
        for (int k = 0; k < 4; ++k) {
            f16 hh, ll; split16(e[k], hh, ll);
            Xth[(c4 * 4 + k) * 40 + sr] = hh;
            Xtl[(c4 * 4 + k) * 40 + sr] = ll;
        }
    }
    __syncthreads();

    int q = lane >> 4, r16 = lane & 15;

    {
        int ti = w >> 1, si = w & 1;
        v4f gM = (v4f)0.0f, gX = (v4f)0.0f;
#pragma unroll
        for (int ks = 0; ks < 64; ks += 32) {
            int ra = (ti * 16 + r16) * 72 + ks + q * 8;
            int rb = (si * 16 + r16) * 72 + ks + q * 8;
            v8h ca  = *(const v8h*)&Chs[ra];
            v8h cl2 = *(const v8h*)&Cls[ra];
            v8h ba  = *(const v8h*)&Bhs[rb];
            v8h bl2 = *(const v8h*)&Bls[rb];
            gM = MFMA16(ca, ba, gM);
            gX = MFMA16(ca, bl2, gX);
            gX = MFMA16(cl2, ba, gX);
        }
#pragma unroll
        for (int r = 0; r < 4; ++r) {
            int t = ti * 16 + q * 4 + r;
            int s = si * 16 + r16;
            float g = gM[r] + gX[r] * cs;
            float wgt = (s <= t) ? sLC[t] * sRD[s] * 4096.0f : 0.0f;
            f16 hh, ll; split16(g * wgt, hh, ll);
            Gph[t * 40 + s] = hh;
            Gpl[t * 40 + s] = ll;
        }
    }
    __syncthreads();

    {
        int ti = w >> 1;
        int ra = (ti * 16 + r16) * 40 + q * 8;
        v8h ga = *(const v8h*)&Gph[ra];
        v8h gl = *(const v8h*)&Gpl[ra];
#pragma unroll
        for (int jj = 0; jj < 2; ++jj) {
            int pj = (w & 1) * 2 + jj;
            int rb = (pj * 16 + r16) * 40 + q * 8;
            v8h xa = *(const v8h*)&Xth[rb];
            v8h xl = *(const v8h*)&Xtl[rb];
            v4f m = (v4f)0.0f, x2 = (v4f)0.0f;
            m  = MFMA16(ga, xa, m);
            x2 = MFMA16(ga, xl, x2);
            x2 = MFMA16(gl, xa, x2);
#pragma unroll
            for (int r = 0; r < 4; ++r) {
                int t = ti * 16 + q * 4 + r;
                int pp = pj * 16 + r16;
                float xv = (float)Xth[pp * 40 + t] + cs * (float)Xtl[pp * 40 + t];
                float val = (m[r] + x2[r] * cs) * cs + Dv * xv;
                yd[(size_t)(base + t0 + t) * DINNER + h * HEADDIM + pp] = val;
            }
        }
    }

    {
        float* Hb = H + (size_t)c * HROW + (size_t)u * 4096;
        int ni = w;
        int ra = (ni * 16 + r16) * 40 + q * 8;
        v8h ba  = *(const v8h*)&Bvh[ra];
        v8h bl2 = *(const v8h*)&Bvl[ra];
#pragma unroll
        for (int pj = 0; pj < 4; ++pj) {
            int rb = (pj * 16 + r16) * 40 + q * 8;
            v8h xa = *(const v8h*)&Xth[rb];
            v8h xl = *(const v8h*)&Xtl[rb];
            v4f m = (v4f)0.0f, x2 = (v4f)0.0f;
            m  = MFMA16(ba, xa, m);
            x2 = MFMA16(ba, xl, x2);
            x2 = MFMA16(bl2, xa, x2);
#pragma unroll
            for (int r = 0; r < 4; ++r) {
                int n = ni * 16 + q * 4 + r;
                int pp = pj * 16 + r16;
                Hb[pp * 64 + n] = (m[r] + x2[r] * cs) * cs;
            }
        }
    }
}

// ---------------------------------------------------------------- S2: carry chain, thread-per-chain
__global__ __launch_bounds__(256) void carry_kernel(
    float* __restrict__ H, const float* __restrict__ cumb) {
    int blk = blockIdx.x;
    int u = blk >> 4;
    int e = ((blk & 15) << 8) + threadIdx.x;
    size_t off = (size_t)u * 4096 + e;
    float carry = 0.f;
#pragma unroll 4
    for (int c = 0; c < NC; ++c) {
        float Pc = cumb[(u << 10) + c * LC + (LC - 1)];
        float* p = H + (size_t)c * HROW + off;
        float ev = *p;
        *p = carry;
        carry = fmaf(Pc, carry, ev);
    }
}

// ---------------------------------------------------------------- S3: y[t] += cum[t] * (C_t . h_in)
__global__ __launch_bounds__(128) void fix_kernel(
    const float* __restrict__ BCbuf, float* __restrict__ y,
    const float* __restrict__ H, const float* __restrict__ cumb) {
    __shared__ float sC[LC * 64];
    __shared__ float sCum[LC];
    int blk = blockIdx.x;
    int u = blk / (NC - 1);
    int c = blk % (NC - 1) + 1;
    int dir = u >> 4, b = (u >> 3) & 1, h = u & 7;
    int tid = threadIdx.x;
    int w = tid >> 6, p = tid & 63;
    const float* Cb = BCbuf + (size_t)dir * ROWS * 128;
    float* yd = y + (size_t)dir * ROWS * DINNER;
    int t0 = c * LC, base = b << 10;
    if (tid < LC) sCum[tid] = cumb[(u << 10) + t0 + tid];
#pragma unroll
    for (int j = 0; j < 4; ++j) {
        int f4 = j * 128 + tid;
        int trow = f4 >> 4, col4 = f4 & 15;
        float4 v = *(const float4*)&Cb[(size_t)(base + t0 + trow) * 128 + 64 + col4 * 4];
        *(float4*)&sC[trow * 64 + col4 * 4] = v;
    }
    const float* Hb = H + (size_t)c * HROW + (size_t)u * 4096 + p * 64;
    float hin[DSTATE];
#pragma unroll
    for (int n = 0; n < DSTATE; n += 4) {
        float4 v = *(const float4*)&Hb[n];
        hin[n] = v.x; hin[n + 1] = v.y; hin[n + 2] = v.z; hin[n + 3] = v.w;
    }
    __syncthreads();
#pragma unroll 2
    for (int tt = w * 16; tt < w * 16 + 16; ++tt) {
        float cumt = sCum[tt];
        const float* Cs = &sC[tt * 64];
        float y0 = 0.f, y1 = 0.f, y2 = 0.f, y3 = 0.f;
#pragma unroll
        for (int n = 0; n < DSTATE; n += 4) {
            y0 = fmaf(hin[n],     Cs[n],     y0);
            y1 = fmaf(hin[n + 1], Cs[n + 1], y1);
            y2 = fmaf(hin[n + 2], Cs[n + 2], y2);
            y3 = fmaf(hin[n + 3], Cs[n + 3], y3);
        }
        size_t yi = (size_t)(base + t0 + tt) * DINNER + h * HEADDIM + p;
        yd[yi] += cumt * ((y0 + y1) + (y2 + y3));
    }
}

// ---------------------------------------------------------------- y*silu(z), RMSNorm*nw -> f16 pairs (shuffle reduce)
__global__ __launch_bounds__(256) void gate_rms_kernel(
    const float* __restrict__ y, const float* __restrict__ zbuf,
    const float* __restrict__ nw, f16* __restrict__ yh, f16* __restrict__ yl, int layer) {
    int row = blockIdx.x;
    int dir = blockIdx.y;
    const float* zrow = zbuf + ((size_t)dir * ROWS + row) * DINNER;
    const float* yrow = y + ((size_t)dir * ROWS + row) * DINNER;
    f16* yhr = yh + ((size_t)dir * ROWS + row) * DINNER;
    f16* ylr = yl + ((size_t)dir * ROWS + row) * DINNER;
    const float* nwl = nw + (dir * 2 + layer) * DINNER;
    int tid = threadIdx.x;
    int i0 = tid, i1 = tid + 256;
    float g0 = yrow[i0] * siluf_(zrow[i0]);
    float g1 = yrow[i1] * siluf_(zrow[i1]);
    float s = fmaf(g0, g0, g1 * g1);
#pragma unroll
    for (int off = 32; off >= 1; off >>= 1) s += __shfl_down(s, off);
    __shared__ float ws4[4];
    if ((tid & 63) == 0) ws4[tid >> 6] = s;
    __syncthreads();
    float tot = (ws4[0] + ws4[1]) + (ws4[2] + ws4[3]);
    float scale = 1.0f / sqrtf(tot / (float)DINNER + EPSF);
    float v0 = g0 * scale * nwl[i0];
    float v1 = g1 * scale * nwl[i1];
    f16 h, l;
    split16(v0, h, l); yhr[i0] = h; ylr[i0] = l;
    split16(v1, h, l); yhr[i1] = h; ylr[i1] = l;
}

// ---------------------------------------------------------------- fusion gates + LayerNorm (shuffle reduce)
__global__ __launch_bounds__(256) void fusion_ln2_kernel(
    const float* __restrict__ u32, const float* __restrict__ gate,
    const float* __restrict__ fb, const float* __restrict__ lnw,
    const float* __restrict__ lnb, float* __restrict__ out) {
    int row = blockIdx.x;
    int b = row >> 10, t = row & 1023;
    int tid = threadIdx.x;
    float f  = u32[(size_t)row * DMODEL + tid];
    float bw = u32[(size_t)ROWS * DMODEL + ((size_t)(b << 10) + (1023 - t)) * DMODEL + tid];
    float g0 = sigmoidf_(gate[(size_t)row * 512 + tid] + fb[tid]);
    float g1 = sigmoidf_(gate[(size_t)row * 512 + 256 + tid] + fb[256 + tid]);
    float fused = g0 * f + g1 * bw;
    __shared__ float ws4[4];
    float s = fused;
#pragma unroll
    for (int off = 32; off >= 1; off >>= 1) s += __shfl_down(s, off);
    if ((tid & 63) == 0) ws4[tid >> 6] = s;
    __syncthreads();
    float mu = ((ws4[0] + ws4[1]) + (ws4[2] + ws4[3])) / (float)DMODEL;
    float d = fused - mu;
    float s2 = d * d;
#pragma unroll
    for (int off = 32; off >= 1; off >>= 1) s2 += __shfl_down(s2, off);
    __syncthreads();
    if ((tid & 63) == 0) ws4[tid >> 6] = s2;
    __syncthreads();
    float var = ((ws4[0] + ws4[1]) + (ws4[2] + ws4[3])) / (float)DMODEL;
    out[(size_t)row * DMODEL + tid] = d * (1.0f / sqrtf(var + EPSF)) * lnw[tid] + lnb[tid];
}

// ---------------------------------------------------------------- launch
extern "C" void kernel_launch(void* const* d_in, const int* in_sizes, int n_in,
                              void* d_out, int out_size, void* d_ws, size_t ws_size,
                              hipStream_t stream) {
    const int*   ids  = (const int*)d_in[0];
    const float* mask = (const float*)d_in[1];
    const float* tok  = (const float*)d_in[2];
    const float* pos  = (const float*)d_in[3];
    const float* inw  = (const float*)d_in[4];
    const float* cw   = (const float*)d_in[5];
    const float* cb   = (const float*)d_in[6];
    const float* dtb  = (const float*)d_in[7];
    const float* alog = (const float*)d_in[8];
    const float* dpar = (const float*)d_in[9];
    const float* nw   = (const float*)d_in[10];
    const float* ow   = (const float*)d_in[11];
    const float* fw   = (const float*)d_in[12];
    const float* fb   = (const float*)d_in[13];
    const float* lnw  = (const float*)d_in[14];
    const float* lnb  = (const float*)d_in[15];

    float* ws = (float*)d_ws;
    float* zbuf = ws;                      //  2,097,152 f
    float* xbc  = ws +  2097152;           //  2,654,208 f
    float* ybuf = ws +  4751360;           //  2,097,152 f
    f16*   yh   = (f16*)(ws +  6848512);   //  2,097,152 h
    f16*   yl   = (f16*)(ws +  7897088);   //  2,097,152 h
    float* gate = ws +  8945664;           //  1,048,576 f
    f16*   uh   = (f16*)(ws +  9994240);   //  2,097,152 h
    f16*   ul   = (f16*)(ws + 11042816);   //  2,097,152 h
    f16*   wb   = (f16*)(ws + 12091392);   //  3,948,544 h
    float* H    = ws + 14065664;           //  4,194,304 f
    float* cumb = ws + 18259968;           //     32,768 f
    float* BCbuf= ws + 18292736;           //    524,288 f (conv'd B|C, 128/row)
    float* u32  = ybuf;
    f16*   combh = (f16*)(ybuf + 1048576);
    f16*   combl = (f16*)(ybuf + 1572864);
    f16*   wfh = wb + 2 * (size_t)LSTRIDE;
    f16*   wfl = wfh + WF;

    prep_kernel<<<ROWS + WBLOCKS, 256, 0, stream>>>(ids, mask, tok, pos, uh, ul, inw, ow, fw, wb);

    for (int layer = 0; layer < 2; ++layer) {
        f16* wih = wb + (size_t)layer * LSTRIDE;
        f16* wil = wih + WIN;
        f16* woh = wb + (size_t)layer * LSTRIDE + 2 * WIN;
        f16* wol = woh + WOUT;

        dim3 g1(ROWS / 64, (DINPROJ + 63) / 64, 2);
        gemm_f16x3<<<g1, 256, 0, stream>>>(
            uh, ul, (long)ROWS * DMODEL,
            wih, wil, (long)PSI,
            DINPROJ, DMODEL, DINNER,
            zbuf, DINNER, (long)ROWS * DINNER,
            xbc, XBCW, (long)ROWS * XBCW,
            (f16*)nullptr, (f16*)nullptr, 0, 0L,
            1, 0, 0);

        conv_bc_kernel<<<512, 256, 0, stream>>>(xbc, cw, cb, BCbuf, layer);
        scan_chunk_kernel<<<32 * NC, 256, 0, stream>>>(
            xbc, BCbuf, cw, cb, dtb, ybuf, alog, dpar, H, cumb, layer);
        carry_kernel<<<32 * 16, 256, 0, stream>>>(H, cumb);
        fix_kernel<<<32 * (NC - 1), 128, 0, stream>>>(BCbuf, ybuf, H, cumb);
        gate_rms_kernel<<<dim3(ROWS, 2), 256, 0, stream>>>(ybuf, zbuf, nw, yh, yl, layer);

        dim3 g2(ROWS / 64, DMODEL / 64, 2);
        if (layer == 0) {
            gemm_f16x3<<<g2, 256, 0, stream>>>(
                yh, yl, (long)ROWS * DINNER,
                woh, wol, (long)PSO,
                DMODEL, DINNER, DMODEL,
                u32, DMODEL, (long)ROWS * DMODEL,
                u32, DMODEL, (long)ROWS * DMODEL,
                uh, ul, DMODEL, (long)ROWS * DMODEL,
                1, 1, 0);
        } else {
            gemm_f16x3<<<g2, 256, 0, stream>>>(
                yh, yl, (long)ROWS * DINNER,
                woh, wol, (long)PSO,
                DMODEL, DINNER, DMODEL,
                u32, DMODEL, (long)ROWS * DMODEL,
                u32, DMODEL, (long)ROWS * DMODEL,
                combh, combl, 512, 0L,
                1, 1, 1);
        }
    }

    dim3 g3(ROWS / 64, 512 / 64, 1);
    gemm_f16x3<<<g3, 256, 0, stream>>>(
        combh, combl, 0L,
        wfh, wfl, 0L,
        512, 512, 512,
        gate, 512, 0L,
        gate, 512, 0L,
        (f16*)nullptr, (f16*)nullptr, 0, 0L,
        1, 0, 0);

    fusion_ln2_kernel<<<ROWS, 256, 0, stream>>>(u32, gate, fb, lnw, lnb, (float*)d_out);
}